// Round 1
// baseline (3225.546 us; speedup 1.0000x reference)
//
#include <hip/hip_runtime.h>
#include <hip/hip_bf16.h>
#include <math.h>

// Problem constants
#define BB 4
#define SS 2048
#define DM 1024
#define NH 8
#define DH 128
#define NE 8
#define NTOK (BB*SS)          // 8192
#define SCALE_SQRT 0.29730177875068026f

typedef unsigned short u16;
typedef short s8v __attribute__((ext_vector_type(8)));
typedef float f4v __attribute__((ext_vector_type(4)));
#define MFMA16(a,b,c) __builtin_amdgcn_mfma_f32_16x16x32_bf16((a),(b),(c),0,0,0)

// Round-to-nearest-even fp32 -> bf16 split: x ~= hi + lo (each bf16).
__device__ inline void bfsplit(float x, u16& h, u16& l) {
    unsigned u = __float_as_uint(x);
    unsigned hr = (u + 0x7FFFu + ((u >> 16) & 1u)) >> 16;
    h = (u16)hr;
    float hf = __uint_as_float(hr << 16);
    unsigned u2 = __float_as_uint(x - hf);
    l = (u16)((u2 + 0x7FFFu + ((u2 >> 16) & 1u)) >> 16);
}
__device__ inline u16 bf16rne(float x) {
    unsigned u = __float_as_uint(x);
    return (u16)((u + 0x7FFFu + ((u >> 16) & 1u)) >> 16);
}

// ---------------------------------------------------------------------------
// Projection GEMM (fp32 accumulate): emits bf16 hi/lo directly.
// ---------------------------------------------------------------------------
__global__ void proj_kernel(const float* __restrict__ A,
                            const float* __restrict__ W,
                            u16* __restrict__ out_h, u16* __restrict__ out_l,
                            float scale) {
    __shared__ float As[16][65];
    __shared__ float Ws[16][65];
    const int t  = threadIdx.x;
    const int tx = t & 15, ty = t >> 4;
    const int m0 = blockIdx.x * 64, n0 = blockIdx.y * 64;
    float acc[4][4] = {};
    for (int kt = 0; kt < DM; kt += 16) {
#pragma unroll
        for (int i = 0; i < 4; ++i) {
            int idx = t + i * 256;
            int m = idx >> 4, kk = idx & 15;
            As[kk][m] = A[(size_t)(m0 + m) * DM + kt + kk];
            Ws[kk][m] = W[(size_t)(n0 + m) * DM + kt + kk];
        }
        __syncthreads();
#pragma unroll
        for (int kk = 0; kk < 16; ++kk) {
            float a[4], b[4];
#pragma unroll
            for (int i = 0; i < 4; ++i) a[i] = As[kk][ty * 4 + i];
#pragma unroll
            for (int j = 0; j < 4; ++j) b[j] = Ws[kk][tx * 4 + j];
#pragma unroll
            for (int i = 0; i < 4; ++i)
#pragma unroll
                for (int j = 0; j < 4; ++j) acc[i][j] += a[i] * b[j];
        }
        __syncthreads();
    }
#pragma unroll
    for (int ii = 0; ii < 4; ++ii)
#pragma unroll
        for (int jj = 0; jj < 4; ++jj) {
            int i = m0 + ty * 4 + ii;
            int j = n0 + tx * 4 + jj;
            int b = i >> 11, s = i & 2047, h = j >> 7, f = j & 127;
            u16 hh, ll;
            bfsplit(acc[ii][jj] * scale, hh, ll);
            size_t o = ((((size_t)(b * NH + h)) * SS + s) << 7) + f;
            out_h[o] = hh; out_l[o] = ll;
        }
}

// ---------------------------------------------------------------------------
// Zero helper for bucket counters.
// ---------------------------------------------------------------------------
__global__ void zero_kernel(int* __restrict__ p, int n) {
    int i = blockIdx.x * 128 + threadIdx.x;
    if (i < n) p[i] = 0;
}

// ---------------------------------------------------------------------------
// Gate: dense sparse-valued gate g[token][h][e] + bucket build.
// Buckets: bucket (h*7+e) collects tokens whose routed top-1 (over e=0..6)
// is e, with the sigmoid gate value. Bucket order is arbitrary (atomicAdd),
// but every token's GEMM row is independent -> deterministic results.
// ---------------------------------------------------------------------------
__global__ void gate_kernel(const float* __restrict__ x,
                            const float* __restrict__ sel,
                            float* __restrict__ gdense,
                            int* __restrict__ bcnt,
                            int* __restrict__ bidx,
                            float* __restrict__ bgv) {
    __shared__ float xs[DM];
    __shared__ float logits[64];
    __shared__ int   sbest[NH];
    __shared__ float sg1[NH], sg2[NH];
    const int token = blockIdx.x;
    const int t = threadIdx.x;  // 0..63
    const float* xp = x + (size_t)token * DM;
    for (int i = t; i < DM; i += 64) xs[i] = xp[i];
    __syncthreads();
    const float* sp = sel + (size_t)t * DM;
    float acc = 0.f;
    for (int d = 0; d < DM; ++d) acc += xs[d] * sp[d];
    logits[t] = acc;
    __syncthreads();
    if (t < NH) {
        const float* lp = logits + t * NE;
        int best = 0; float bv = lp[0];
#pragma unroll
        for (int e = 1; e < NE - 1; ++e)
            if (lp[e] > bv) { bv = lp[e]; best = e; }   // strict > == lowest idx tie
        float g1 = 1.f / (1.f + expf(-bv));
        sbest[t] = best;
        sg1[t] = g1;
        sg2[t] = 1.f / (1.f + expf(-lp[NE - 1]));
        int bk = t * 7 + best;
        int slot = atomicAdd(&bcnt[bk], 1);
        bidx[(size_t)bk * NTOK + slot] = token;
        bgv [(size_t)bk * NTOK + slot] = g1;
    }
    __syncthreads();
    const int h = t >> 3, e = t & 7;
    float val = (e == sbest[h]) ? sg1[h] : ((e == NE - 1) ? sg2[h] : 0.f);
    gdense[(size_t)token * 64 + t] = val;
}

// ---------------------------------------------------------------------------
// Preprocess: split fp32 -> bf16 hi/lo (no transpose). n divisible by 1024.
// ---------------------------------------------------------------------------
__global__ void split_kernel(const float* __restrict__ src,
                             u16* __restrict__ dh, u16* __restrict__ dl) {
    int i = (blockIdx.x * 256 + threadIdx.x) * 4;
    float4 v = *(const float4*)(src + i);
    u16 h[4], l[4];
    bfsplit(v.x, h[0], l[0]); bfsplit(v.y, h[1], l[1]);
    bfsplit(v.z, h[2], l[2]); bfsplit(v.w, h[3], l[3]);
    uint2 ph = { (unsigned)h[0] | ((unsigned)h[1] << 16),
                 (unsigned)h[2] | ((unsigned)h[3] << 16) };
    uint2 pl = { (unsigned)l[0] | ((unsigned)l[1] << 16),
                 (unsigned)l[2] | ((unsigned)l[3] << 16) };
    *(uint2*)&dh[i] = ph;
    *(uint2*)&dl[i] = pl;
}

// ---------------------------------------------------------------------------
// Preprocess: per-matrix transpose + split. src[mat][R][C] -> dst[mat][C][R].
// ---------------------------------------------------------------------------
__global__ void tsplit_kernel(const float* __restrict__ src,
                              u16* __restrict__ dh, u16* __restrict__ dl,
                              int R, int C) {
    __shared__ float tile[32][33];
    const int mat = blockIdx.x;
    const int r0 = blockIdx.y * 32, c0 = blockIdx.z * 32;
    const size_t base = (size_t)mat * R * C;
    const int tr = threadIdx.x >> 5, tc = threadIdx.x & 31;
#pragma unroll
    for (int p = 0; p < 4; ++p)
        tile[tr + p * 8][tc] = src[base + (size_t)(r0 + tr + p * 8) * C + c0 + tc];
    __syncthreads();
#pragma unroll
    for (int p = 0; p < 4; ++p) {
        int cc = tr + p * 8, rr = tc;
        float x = tile[rr][cc];
        u16 hh, ll; bfsplit(x, hh, ll);
        size_t o = base + (size_t)(c0 + cc) * R + r0 + rr;
        dh[o] = hh; dl[o] = ll;
    }
}

// ---------------------------------------------------------------------------
// Value CVMM, SHARED expert only (e = 7), dense over tokens. Writes wv.
// ---------------------------------------------------------------------------
__global__ __launch_bounds__(256, 2) void v_shared_kernel(
        const u16* __restrict__ Ah_g, const u16* __restrict__ Al_g,
        const u16* __restrict__ Bh_g, const u16* __restrict__ Bl_g,
        const float* __restrict__ gdense,
        float* __restrict__ wv) {
    const int i0 = blockIdx.x * 128;
    const int h  = blockIdx.y;
    __shared__ u16 Ah[128 * 72], Al[128 * 72], Bh[128 * 72], Bl[128 * 72];
    __shared__ float gl[128];
    const int t = threadIdx.x;
    const int lane = t & 63, wave = t >> 6;
    const int wm = wave >> 1, wn = wave & 1;
    const int ln = lane & 15, qd = lane >> 4;
    const f4v z4 = {0.f, 0.f, 0.f, 0.f};

    if (t < 128) gl[t] = gdense[(size_t)(i0 + t) * 64 + h * 8 + 7];

    f4v C[4][4];
#pragma unroll
    for (int fm = 0; fm < 4; ++fm)
#pragma unroll
        for (int fn = 0; fn < 4; ++fn) C[fm][fn] = z4;

    const size_t bbase = (size_t)(h * 8 + 7) * DH * 1024;
    for (int kb = 0; kb < 16; ++kb) {
        __syncthreads();
        const int kbase = kb * 64;
#pragma unroll
        for (int p = 0; p < 4; ++p) {
            int chunk = p * 256 + t;
            int row = chunk >> 3, off = (chunk & 7) * 8;
            size_t ga = (size_t)(i0 + row) * 1024 + kbase + off;
            *(uint4*)&Ah[row * 72 + off] = *(const uint4*)&Ah_g[ga];
            *(uint4*)&Al[row * 72 + off] = *(const uint4*)&Al_g[ga];
            size_t gb = bbase + (size_t)row * 1024 + kbase + off;
            *(uint4*)&Bh[row * 72 + off] = *(const uint4*)&Bh_g[gb];
            *(uint4*)&Bl[row * 72 + off] = *(const uint4*)&Bl_g[gb];
        }
        __syncthreads();
#pragma unroll
        for (int ks = 0; ks < 2; ++ks) {
            s8v ah[4], alv[4], bh[4], blv[4];
#pragma unroll
            for (int fm = 0; fm < 4; ++fm) {
                int o = (wm * 64 + fm * 16 + ln) * 72 + ks * 32 + qd * 8;
                ah[fm]  = *(const s8v*)&Ah[o];
                alv[fm] = *(const s8v*)&Al[o];
            }
#pragma unroll
            for (int fn = 0; fn < 4; ++fn) {
                int o = (wn * 64 + fn * 16 + ln) * 72 + ks * 32 + qd * 8;
                bh[fn]  = *(const s8v*)&Bh[o];
                blv[fn] = *(const s8v*)&Bl[o];
            }
#pragma unroll
            for (int fm = 0; fm < 4; ++fm)
#pragma unroll
                for (int fn = 0; fn < 4; ++fn) {
                    C[fm][fn] = MFMA16(ah[fm],  bh[fn],  C[fm][fn]);
                    C[fm][fn] = MFMA16(ah[fm],  blv[fn], C[fm][fn]);
                    C[fm][fn] = MFMA16(alv[fm], bh[fn],  C[fm][fn]);
                }
        }
    }
#pragma unroll
    for (int fm = 0; fm < 4; ++fm)
#pragma unroll
        for (int fn = 0; fn < 4; ++fn)
#pragma unroll
            for (int r = 0; r < 4; ++r) {
                int row = wm * 64 + fm * 16 + qd * 4 + r;
                int token = i0 + row;
                int f = wn * 64 + fn * 16 + ln;
                int b = token >> 11, s = token & 2047;
                wv[(((size_t)(b * NH + h) * SS + s) << 7) + f] = gl[row] * C[fm][fn][r];
            }
}

// ---------------------------------------------------------------------------
// Value CVMM, ROUTED experts via token buckets. wv += g * (v_src @ V[h,e]).
// grid (64 tiles, 56 buckets). Race-free: each (token,h) in exactly 1 bucket.
// ---------------------------------------------------------------------------
__global__ __launch_bounds__(256, 2) void v_routed_kernel(
        const u16* __restrict__ Ah_g, const u16* __restrict__ Al_g,
        const u16* __restrict__ Bh_g, const u16* __restrict__ Bl_g,
        const int* __restrict__ bcnt, const int* __restrict__ bidx,
        const float* __restrict__ bgv,
        float* __restrict__ wv) {
    const int bucket = blockIdx.y;           // h*7 + e
    const int cnt = bcnt[bucket];
    const int tile0 = blockIdx.x * 128;
    if (tile0 >= cnt) return;
    const int h = bucket / 7, e = bucket % 7;
    const int rows = min(128, cnt - tile0);
    __shared__ u16 Ah[128 * 72], Al[128 * 72], Bh[128 * 72], Bl[128 * 72];
    __shared__ int   toks[128];
    __shared__ float gvals[128];
    const int t = threadIdx.x;
    const int lane = t & 63, wave = t >> 6;
    const int wm = wave >> 1, wn = wave & 1;
    const int ln = lane & 15, qd = lane >> 4;
    const f4v z4 = {0.f, 0.f, 0.f, 0.f};

    if (t < 128) {
        int slot = tile0 + min(t, rows - 1);   // clamp: padding rows duplicate
        toks[t]  = bidx[(size_t)bucket * NTOK + slot];
        gvals[t] = bgv [(size_t)bucket * NTOK + slot];
    }

    f4v C[4][4];
#pragma unroll
    for (int fm = 0; fm < 4; ++fm)
#pragma unroll
        for (int fn = 0; fn < 4; ++fn) C[fm][fn] = z4;

    const size_t bbase = (size_t)(h * 8 + e) * DH * 1024;
    for (int kb = 0; kb < 16; ++kb) {
        __syncthreads();                       // also covers toks[] staging
        const int kbase = kb * 64;
#pragma unroll
        for (int p = 0; p < 4; ++p) {
            int chunk = p * 256 + t;
            int row = chunk >> 3, off = (chunk & 7) * 8;
            size_t ga = (size_t)toks[row] * 1024 + kbase + off;
            *(uint4*)&Ah[row * 72 + off] = *(const uint4*)&Ah_g[ga];
            *(uint4*)&Al[row * 72 + off] = *(const uint4*)&Al_g[ga];
            size_t gb = bbase + (size_t)row * 1024 + kbase + off;
            *(uint4*)&Bh[row * 72 + off] = *(const uint4*)&Bh_g[gb];
            *(uint4*)&Bl[row * 72 + off] = *(const uint4*)&Bl_g[gb];
        }
        __syncthreads();
#pragma unroll
        for (int ks = 0; ks < 2; ++ks) {
            s8v ah[4], alv[4], bh[4], blv[4];
#pragma unroll
            for (int fm = 0; fm < 4; ++fm) {
                int o = (wm * 64 + fm * 16 + ln) * 72 + ks * 32 + qd * 8;
                ah[fm]  = *(const s8v*)&Ah[o];
                alv[fm] = *(const s8v*)&Al[o];
            }
#pragma unroll
            for (int fn = 0; fn < 4; ++fn) {
                int o = (wn * 64 + fn * 16 + ln) * 72 + ks * 32 + qd * 8;
                bh[fn]  = *(const s8v*)&Bh[o];
                blv[fn] = *(const s8v*)&Bl[o];
            }
#pragma unroll
            for (int fm = 0; fm < 4; ++fm)
#pragma unroll
                for (int fn = 0; fn < 4; ++fn) {
                    C[fm][fn] = MFMA16(ah[fm],  bh[fn],  C[fm][fn]);
                    C[fm][fn] = MFMA16(ah[fm],  blv[fn], C[fm][fn]);
                    C[fm][fn] = MFMA16(alv[fm], bh[fn],  C[fm][fn]);
                }
        }
    }
#pragma unroll
    for (int fm = 0; fm < 4; ++fm)
#pragma unroll
        for (int fn = 0; fn < 4; ++fn)
#pragma unroll
            for (int r = 0; r < 4; ++r) {
                int row = wm * 64 + fm * 16 + qd * 4 + r;
                if (row >= rows) continue;     // guard padding rows
                int token = toks[row];
                int f = wn * 64 + fn * 16 + ln;
                int b = token >> 11, s = token & 2047;
                wv[(((size_t)(b * NH + h) * SS + s) << 7) + f] += gvals[row] * C[fm][fn][r];
            }
}

// ---------------------------------------------------------------------------
// Output CVMM, SHARED expert only (e = 7), sums over h. Writes out.
// ---------------------------------------------------------------------------
__global__ __launch_bounds__(256, 2) void out_shared_kernel(
        const u16* __restrict__ Ah_g, const u16* __restrict__ Al_g,
        const u16* __restrict__ Bh_g, const u16* __restrict__ Bl_g,
        const float* __restrict__ gdense,
        float* __restrict__ out) {
    const int n0 = blockIdx.x * 128;
    const int i0 = blockIdx.y * 128;
    __shared__ u16 Ah[128 * 72], Al[128 * 72], Bh[128 * 72], Bl[128 * 72];
    __shared__ float gl[128];
    const int t = threadIdx.x;
    const int lane = t & 63, wave = t >> 6;
    const int wm = wave >> 1, wn = wave & 1;
    const int ln = lane & 15, qd = lane >> 4;
    const f4v z4 = {0.f, 0.f, 0.f, 0.f};

    f4v C[4][4];
#pragma unroll
    for (int fm = 0; fm < 4; ++fm)
#pragma unroll
        for (int fn = 0; fn < 4; ++fn) C[fm][fn] = z4;

    for (int h = 0; h < 8; ++h) {
        __syncthreads();                       // protect gl overwrite
        if (t < 128) gl[t] = gdense[(size_t)(i0 + t) * 64 + h * 8 + 7];
        f4v T[4][4];
#pragma unroll
        for (int fm = 0; fm < 4; ++fm)
#pragma unroll
            for (int fn = 0; fn < 4; ++fn) T[fm][fn] = z4;
        const size_t bbase = ((size_t)(h * 8 + 7) * 1024 + n0) * DH;
#pragma unroll
        for (int kb = 0; kb < 2; ++kb) {
            __syncthreads();
            const int ka = h * 128 + kb * 64;
            const int kbb = kb * 64;
#pragma unroll
            for (int p = 0; p < 4; ++p) {
                int chunk = p * 256 + t;
                int row = chunk >> 3, off = (chunk & 7) * 8;
                size_t ga = (size_t)(i0 + row) * 1024 + ka + off;
                *(uint4*)&Ah[row * 72 + off] = *(const uint4*)&Ah_g[ga];
                *(uint4*)&Al[row * 72 + off] = *(const uint4*)&Al_g[ga];
                size_t gb = bbase + (size_t)row * DH + kbb + off;
                *(uint4*)&Bh[row * 72 + off] = *(const uint4*)&Bh_g[gb];
                *(uint4*)&Bl[row * 72 + off] = *(const uint4*)&Bl_g[gb];
            }
            __syncthreads();
#pragma unroll
            for (int ks = 0; ks < 2; ++ks) {
                s8v ah[4], alv[4], bh[4], blv[4];
#pragma unroll
                for (int fm = 0; fm < 4; ++fm) {
                    int o = (wm * 64 + fm * 16 + ln) * 72 + ks * 32 + qd * 8;
                    ah[fm]  = *(const s8v*)&Ah[o];
                    alv[fm] = *(const s8v*)&Al[o];
                }
#pragma unroll
                for (int fn = 0; fn < 4; ++fn) {
                    int o = (wn * 64 + fn * 16 + ln) * 72 + ks * 32 + qd * 8;
                    bh[fn]  = *(const s8v*)&Bh[o];
                    blv[fn] = *(const s8v*)&Bl[o];
                }
#pragma unroll
                for (int fm = 0; fm < 4; ++fm)
#pragma unroll
                    for (int fn = 0; fn < 4; ++fn) {
                        T[fm][fn] = MFMA16(ah[fm],  bh[fn],  T[fm][fn]);
                        T[fm][fn] = MFMA16(ah[fm],  blv[fn], T[fm][fn]);
                        T[fm][fn] = MFMA16(alv[fm], bh[fn],  T[fm][fn]);
                    }
            }
        }
#pragma unroll
        for (int fm = 0; fm < 4; ++fm)
#pragma unroll
            for (int r = 0; r < 4; ++r) {
                float g = gl[wm * 64 + fm * 16 + qd * 4 + r];
#pragma unroll
                for (int fn = 0; fn < 4; ++fn)
                    C[fm][fn][r] += g * T[fm][fn][r];
            }
    }
#pragma unroll
    for (int fm = 0; fm < 4; ++fm)
#pragma unroll
        for (int fn = 0; fn < 4; ++fn)
#pragma unroll
            for (int r = 0; r < 4; ++r) {
                int token = i0 + wm * 64 + fm * 16 + qd * 4 + r;
                int d = n0 + wn * 64 + fn * 16 + ln;
                out[(size_t)token * DM + d] = C[fm][fn][r];
            }
}

// ---------------------------------------------------------------------------
// Output CVMM, ROUTED experts for ONE head h (passed as arg; 8 sequential
// launches avoid cross-h races on out). out += g * (res[:,h] @ O[h,e]).
// grid (64 tiles, 7 experts, 8 d-tiles).
// ---------------------------------------------------------------------------
__global__ __launch_bounds__(256, 2) void out_routed_kernel(
        const u16* __restrict__ Ah_g, const u16* __restrict__ Al_g,
        const u16* __restrict__ Bh_g, const u16* __restrict__ Bl_g,
        const int* __restrict__ bcnt, const int* __restrict__ bidx,
        const float* __restrict__ bgv,
        float* __restrict__ out, int h) {
    const int e = blockIdx.y;
    const int bucket = h * 7 + e;
    const int cnt = bcnt[bucket];
    const int tile0 = blockIdx.x * 128;
    if (tile0 >= cnt) return;
    const int rows = min(128, cnt - tile0);
    const int n0 = blockIdx.z * 128;
    __shared__ u16 Ah[128 * 72], Al[128 * 72], Bh[128 * 72], Bl[128 * 72];
    __shared__ int   toks[128];
    __shared__ float gvals[128];
    const int t = threadIdx.x;
    const int lane = t & 63, wave = t >> 6;
    const int wm = wave >> 1, wn = wave & 1;
    const int ln = lane & 15, qd = lane >> 4;
    const f4v z4 = {0.f, 0.f, 0.f, 0.f};

    if (t < 128) {
        int slot = tile0 + min(t, rows - 1);
        toks[t]  = bidx[(size_t)bucket * NTOK + slot];
        gvals[t] = bgv [(size_t)bucket * NTOK + slot];
    }

    f4v C[4][4];
#pragma unroll
    for (int fm = 0; fm < 4; ++fm)
#pragma unroll
        for (int fn = 0; fn < 4; ++fn) C[fm][fn] = z4;

    const size_t bbase = ((size_t)(h * 8 + e) * 1024 + n0) * DH;
#pragma unroll
    for (int kb = 0; kb < 2; ++kb) {
        __syncthreads();                       // also covers toks[] staging
        const int kbb = kb * 64;
#pragma unroll
        for (int p = 0; p < 4; ++p) {
            int chunk = p * 256 + t;
            int row = chunk >> 3, off = (chunk & 7) * 8;
            size_t ga = (size_t)toks[row] * DM + h * DH + kbb + off;
            *(uint4*)&Ah[row * 72 + off] = *(const uint4*)&Ah_g[ga];
            *(uint4*)&Al[row * 72 + off] = *(const uint4*)&Al_g[ga];
            size_t gb = bbase + (size_t)row * DH + kbb + off;
            *(uint4*)&Bh[row * 72 + off] = *(const uint4*)&Bh_g[gb];
            *(uint4*)&Bl[row * 72 + off] = *(const uint4*)&Bl_g[gb];
        }
        __syncthreads();
#pragma unroll
        for (int ks = 0; ks < 2; ++ks) {
            s8v ah[4], alv[4], bh[4], blv[4];
#pragma unroll
            for (int fm = 0; fm < 4; ++fm) {
                int o = (wm * 64 + fm * 16 + ln) * 72 + ks * 32 + qd * 8;
                ah[fm]  = *(const s8v*)&Ah[o];
                alv[fm] = *(const s8v*)&Al[o];
            }
#pragma unroll
            for (int fn = 0; fn < 4; ++fn) {
                int o = (wn * 64 + fn * 16 + ln) * 72 + ks * 32 + qd * 8;
                bh[fn]  = *(const s8v*)&Bh[o];
                blv[fn] = *(const s8v*)&Bl[o];
            }
#pragma unroll
            for (int fm = 0; fm < 4; ++fm)
#pragma unroll
                for (int fn = 0; fn < 4; ++fn) {
                    C[fm][fn] = MFMA16(ah[fm],  bh[fn],  C[fm][fn]);
                    C[fm][fn] = MFMA16(ah[fm],  blv[fn], C[fm][fn]);
                    C[fm][fn] = MFMA16(alv[fm], bh[fn],  C[fm][fn]);
                }
        }
    }
#pragma unroll
    for (int fm = 0; fm < 4; ++fm)
#pragma unroll
        for (int fn = 0; fn < 4; ++fn)
#pragma unroll
            for (int r = 0; r < 4; ++r) {
                int row = wm * 64 + fm * 16 + qd * 4 + r;
                if (row >= rows) continue;     // guard padding rows
                int token = toks[row];
                int d = n0 + wn * 64 + fn * 16 + ln;
                out[(size_t)token * DM + d] += gvals[row] * C[fm][fn][r];
            }
}

// ---------------------------------------------------------------------------
// MFMA flash attention (unchanged).
// ---------------------------------------------------------------------------
__global__ void attn_mfma_kernel(
        const u16* __restrict__ qh, const u16* __restrict__ ql,
        const u16* __restrict__ kh, const u16* __restrict__ kl,
        const u16* __restrict__ vth, const u16* __restrict__ vtl,
        u16* __restrict__ res_hi, u16* __restrict__ res_lo) {
    const int bid = blockIdx.x;          // bh*32 + qtile
    const int bh = bid >> 5;
    const int q0 = (bid & 31) * 64;

    __shared__ u16 Ksh[64 * 136];
    __shared__ u16 Ksl[64 * 136];
    __shared__ u16 Vsh[128 * 72];
    __shared__ u16 Vsl[128 * 72];
    __shared__ u16 Ps[4][16 * 72];

    const int t = threadIdx.x;
    const int lane = t & 63, w = t >> 6;
    const int ln = lane & 15, qd = lane >> 4;

    s8v Qh[4], Qlv[4];
    {
        const size_t qoff = ((size_t)bh * SS + q0 + w * 16 + ln) * DH;
        const u16* qhp = qh + qoff;
        const u16* qlp = ql + qoff;
#pragma unroll
        for (int ks = 0; ks < 4; ++ks) {
            Qh[ks]  = *(const s8v*)(qhp + ks * 32 + qd * 8);
            Qlv[ks] = *(const s8v*)(qlp + ks * 32 + qd * 8);
        }
    }

    f4v Of[8];
    const f4v z4 = {0.f, 0.f, 0.f, 0.f};
#pragma unroll
    for (int fn = 0; fn < 8; ++fn) Of[fn] = z4;
    float mrow[4], lrow[4];
#pragma unroll
    for (int r = 0; r < 4; ++r) { mrow[r] = -INFINITY; lrow[r] = 0.f; }

    const u16* kbh = kh + (size_t)bh * SS * DH;
    const u16* kbl = kl + (size_t)bh * SS * DH;
    const u16* vbh = vth + (size_t)bh * DH * SS;   // [f][s]
    const u16* vbl = vtl + (size_t)bh * DH * SS;

    for (int kt = 0; kt < SS / 64; ++kt) {
        __syncthreads();
#pragma unroll
        for (int p = 0; p < 4; ++p) {
            int chunk = p * 256 + t;
            int krow = chunk >> 4, kc = chunk & 15;
            size_t g = (size_t)(kt * 64 + krow) * DH + kc * 8;
            *(uint4*)&Ksh[krow * 136 + kc * 8] = *(const uint4*)&kbh[g];
            *(uint4*)&Ksl[krow * 136 + kc * 8] = *(const uint4*)&kbl[g];
            int vrow = chunk >> 3, vc = chunk & 7;
            size_t gv = (size_t)vrow * SS + kt * 64 + vc * 8;
            *(uint4*)&Vsh[vrow * 72 + vc * 8] = *(const uint4*)&vbh[gv];
            *(uint4*)&Vsl[vrow * 72 + vc * 8] = *(const uint4*)&vbl[gv];
        }
        __syncthreads();

        f4v S[4];
#pragma unroll
        for (int nt = 0; nt < 4; ++nt) S[nt] = z4;
#pragma unroll
        for (int ks = 0; ks < 4; ++ks) {
#pragma unroll
            for (int nt = 0; nt < 4; ++nt) {
                int o = (nt * 16 + ln) * 136 + ks * 32 + qd * 8;
                s8v kbhf = *(const s8v*)&Ksh[o];
                s8v kblf = *(const s8v*)&Ksl[o];
                S[nt] = MFMA16(Qh[ks],  kbhf, S[nt]);
                S[nt] = MFMA16(Qh[ks],  kblf, S[nt]);
                S[nt] = MFMA16(Qlv[ks], kbhf, S[nt]);
            }
        }

        float mt[4];
#pragma unroll
        for (int r = 0; r < 4; ++r) {
            mt[r] = fmaxf(fmaxf(S[0][r], S[1][r]), fmaxf(S[2][r], S[3][r]));
        }
#pragma unroll
        for (int mask = 1; mask < 16; mask <<= 1)
#pragma unroll
            for (int r = 0; r < 4; ++r)
                mt[r] = fmaxf(mt[r], __shfl_xor(mt[r], mask, 64));
        float alpha[4];
#pragma unroll
        for (int r = 0; r < 4; ++r) {
            float mn = fmaxf(mrow[r], mt[r]);
            alpha[r] = __expf(mrow[r] - mn);
            mrow[r] = mn;
        }
        float pv[4][4], lt[4] = {0.f, 0.f, 0.f, 0.f};
#pragma unroll
        for (int nt = 0; nt < 4; ++nt)
#pragma unroll
            for (int r = 0; r < 4; ++r) {
                float p = __expf(S[nt][r] - mrow[r]);
                pv[nt][r] = p;
                lt[r] += p;
            }
#pragma unroll
        for (int mask = 1; mask < 16; mask <<= 1)
#pragma unroll
            for (int r = 0; r < 4; ++r)
                lt[r] += __shfl_xor(lt[r], mask, 64);
#pragma unroll
        for (int r = 0; r < 4; ++r) lrow[r] = alpha[r] * lrow[r] + lt[r];
#pragma unroll
        for (int fn = 0; fn < 8; ++fn)
#pragma unroll
            for (int r = 0; r < 4; ++r) Of[fn][r] *= alpha[r];

#pragma unroll
        for (int nt = 0; nt < 4; ++nt)
#pragma unroll
            for (int r = 0; r < 4; ++r)
                Ps[w][(qd * 4 + r) * 72 + nt * 16 + ln] = bf16rne(pv[nt][r]);

#pragma unroll
        for (int ks2 = 0; ks2 < 2; ++ks2) {
            s8v pf = *(const s8v*)&Ps[w][ln * 72 + ks2 * 32 + qd * 8];
#pragma unroll
            for (int fn = 0; fn < 8; ++fn) {
                int o = (fn * 16 + ln) * 72 + ks2 * 32 + qd * 8;
                s8v vbhf = *(const s8v*)&Vsh[o];
                s8v vblf = *(const s8v*)&Vsl[o];
                Of[fn] = MFMA16(pf, vbhf, Of[fn]);
                Of[fn] = MFMA16(pf, vblf, Of[fn]);
            }
        }
    }

    const int b = bh >> 3, h = bh & 7;
#pragma unroll
    for (int r = 0; r < 4; ++r) {
        float linv = 1.f / lrow[r];
        int qi = q0 + w * 16 + qd * 4 + r;
        size_t off = (size_t)(b * SS + qi) * DM + h * DH + ln;
#pragma unroll
        for (int fn = 0; fn < 8; ++fn) {
            u16 hh, ll;
            bfsplit(Of[fn][r] * linv, hh, ll);
            res_hi[off + fn * 16] = hh;
            res_lo[off + fn * 16] = ll;
        }
    }
}

// ---------------------------------------------------------------------------
extern "C" void kernel_launch(void* const* d_in, const int* in_sizes, int n_in,
                              void* d_out, int out_size, void* d_ws, size_t ws_size,
                              hipStream_t stream) {
    (void)in_sizes; (void)n_in; (void)out_size; (void)ws_size;
    const float* q_src = (const float*)d_in[0];
    const float* k_src = (const float*)d_in[1];
    const float* v_src = (const float*)d_in[2];
    const float* Wq    = (const float*)d_in[3];
    const float* Wk    = (const float*)d_in[4];
    const float* V     = (const float*)d_in[5];
    const float* O     = (const float*)d_in[6];
    const float* sel_v = (const float*)d_in[7];
    const float* sel_o = (const float*)d_in[8];
    float* out = (float*)d_out;

    // workspace layout
    const size_t NELT = (size_t)NTOK * DM;   // 8388608
    u16* wq_h = (u16*)d_ws;                  // q hi/lo [bh][s][f]
    u16* wq_l = wq_h + NELT;
    u16* wk_h = wq_l + NELT;                 // k hi/lo
    u16* wk_l = wk_h + NELT;
    float* wv = (float*)(wk_l + NELT);       // v fp32 [bh][s][f]
    u16* res_hi = (u16*)(wv + NELT);         // attention result hi/lo
    u16* res_lo = res_hi + NELT;
    u16* vs_hi  = res_lo + NELT;             // vsrc split (later: Ot)
    u16* vs_lo  = vs_hi + NELT;
    u16* Vt_hi  = vs_lo + NELT;              // V transposed (later: vT)
    u16* Vt_lo  = Vt_hi + NELT;
    float* gv = (float*)(Vt_lo + NELT);      // dense gates [8192][64]
    float* go = gv + (size_t)NTOK * 64;
    int* bcnt_v = (int*)(go + (size_t)NTOK * 64);   // 56 counters (v-gate)
    int* bcnt_o = bcnt_v + 56;                      // 56 counters (o-gate)
    int* bidx_v = bcnt_o + 56;                      // 56*NTOK token ids
    float* bgv_v = (float*)(bidx_v + (size_t)56 * NTOK);
    int* bidx_o = (int*)(bgv_v + (size_t)56 * NTOK);
    float* bgv_o = (float*)(bidx_o + (size_t)56 * NTOK);
    u16* Ot_hi = vs_hi;                      // alias (dead after v CVMM)
    u16* Ot_lo = vs_lo;
    u16* vth   = Vt_hi;                      // alias (dead after v CVMM)
    u16* vtl   = Vt_lo;

    // preprocess
    split_kernel<<<NELT / 1024, 256, 0, stream>>>(v_src, vs_hi, vs_lo);
    tsplit_kernel<<<dim3(64, 32, 4), 256, 0, stream>>>(V, Vt_hi, Vt_lo, 1024, 128);

    // gates + expert buckets
    zero_kernel<<<1, 128, 0, stream>>>(bcnt_v, 112);   // zeros bcnt_v AND bcnt_o
    gate_kernel<<<NTOK, 64, 0, stream>>>(k_src, sel_v, gv, bcnt_v, bidx_v, bgv_v);
    gate_kernel<<<NTOK, 64, 0, stream>>>(q_src, sel_o, go, bcnt_o, bidx_o, bgv_o);

    // q/k projections (emit bf16 hi/lo)
    dim3 pgrid(NTOK / 64, (NH * DH) / 64);
    proj_kernel<<<pgrid, 256, 0, stream>>>(q_src, Wq, wq_h, wq_l, SCALE_SQRT);
    proj_kernel<<<pgrid, 256, 0, stream>>>(k_src, Wk, wk_h, wk_l, SCALE_SQRT);

    // value CVMM: shared expert (dense, writes) + routed experts (bucketed, +=)
    v_shared_kernel<<<dim3(64, 8), 256, 0, stream>>>(vs_hi, vs_lo, Vt_hi, Vt_lo, gv, wv);
    v_routed_kernel<<<dim3(64, 56), 256, 0, stream>>>(vs_hi, vs_lo, Vt_hi, Vt_lo,
                                                      bcnt_v, bidx_v, bgv_v, wv);

    // transpose+split O into dead vsrc buffers
    tsplit_kernel<<<dim3(64, 4, 32), 256, 0, stream>>>(O, Ot_hi, Ot_lo, 128, 1024);

    // transpose+split v into dead Vt buffers: vT[bh][f][s]
    tsplit_kernel<<<dim3(32, 64, 4), 256, 0, stream>>>(wv, vth, vtl, 2048, 128);

    // attention (MFMA flash)
    attn_mfma_kernel<<<BB * NH * (SS / 64), 256, 0, stream>>>(
        wq_h, wq_l, wk_h, wk_l, vth, vtl, res_hi, res_lo);

    // output CVMM: shared expert (dense over h, writes out) + routed experts
    // (one launch per head -> no cross-h races on out)
    out_shared_kernel<<<dim3(8, 64), 256, 0, stream>>>(res_hi, res_lo, Ot_hi, Ot_lo, go, out);
    for (int h = 0; h < 8; ++h)
        out_routed_kernel<<<dim3(64, 7, 8), 256, 0, stream>>>(
            res_hi, res_lo, Ot_hi, Ot_lo, bcnt_o, bidx_o, bgv_o, out, h);
}

// Round 2
// 2155.775 us; speedup vs baseline: 1.4962x; 1.4962x over previous
//
#include <hip/hip_runtime.h>
#include <hip/hip_bf16.h>
#include <math.h>

// Problem constants
#define BB 4
#define SS 2048
#define DM 1024
#define NH 8
#define DH 128
#define NE 8
#define NTOK (BB*SS)          // 8192
#define SCALE_SQRT 0.29730177875068026f

typedef unsigned short u16;
typedef short s8v __attribute__((ext_vector_type(8)));
typedef float f4v __attribute__((ext_vector_type(4)));
#define MFMA16(a,b,c) __builtin_amdgcn_mfma_f32_16x16x32_bf16((a),(b),(c),0,0,0)

// Round-to-nearest-even fp32 -> bf16 split: x ~= hi + lo (each bf16).
__device__ inline void bfsplit(float x, u16& h, u16& l) {
    unsigned u = __float_as_uint(x);
    unsigned hr = (u + 0x7FFFu + ((u >> 16) & 1u)) >> 16;
    h = (u16)hr;
    float hf = __uint_as_float(hr << 16);
    unsigned u2 = __float_as_uint(x - hf);
    l = (u16)((u2 + 0x7FFFu + ((u2 >> 16) & 1u)) >> 16);
}
__device__ inline u16 bf16rne(float x) {
    unsigned u = __float_as_uint(x);
    return (u16)((u + 0x7FFFu + ((u >> 16) & 1u)) >> 16);
}

// ---------------------------------------------------------------------------
// Projection GEMM via split-bf16 MFMA (3-term): out = scale * (x @ W^T).
// A = x split [8192][1024]; B = W split [1024][1024] (row n, k contiguous).
// Emits bf16 hi/lo at [bh][s][f] layout. grid (64 token-tiles, 8 n-tiles).
// ---------------------------------------------------------------------------
__global__ __launch_bounds__(256, 2) void proj_mfma_kernel(
        const u16* __restrict__ Ah_g, const u16* __restrict__ Al_g,
        const u16* __restrict__ Bh_g, const u16* __restrict__ Bl_g,
        u16* __restrict__ out_h, u16* __restrict__ out_l, float scale) {
    const int i0 = blockIdx.x * 128;
    const int n0 = blockIdx.y * 128;
    __shared__ u16 Ah[128 * 72], Al[128 * 72], Bh[128 * 72], Bl[128 * 72];
    const int t = threadIdx.x;
    const int lane = t & 63, wave = t >> 6;
    const int wm = wave >> 1, wn = wave & 1;
    const int ln = lane & 15, qd = lane >> 4;
    const f4v z4 = {0.f, 0.f, 0.f, 0.f};

    f4v C[4][4];
#pragma unroll
    for (int fm = 0; fm < 4; ++fm)
#pragma unroll
        for (int fn = 0; fn < 4; ++fn) C[fm][fn] = z4;

    for (int kb = 0; kb < 16; ++kb) {
        __syncthreads();
        const int kbase = kb * 64;
#pragma unroll
        for (int p = 0; p < 4; ++p) {
            int chunk = p * 256 + t;
            int row = chunk >> 3, off = (chunk & 7) * 8;
            size_t ga = (size_t)(i0 + row) * 1024 + kbase + off;
            *(uint4*)&Ah[row * 72 + off] = *(const uint4*)&Ah_g[ga];
            *(uint4*)&Al[row * 72 + off] = *(const uint4*)&Al_g[ga];
            size_t gb = (size_t)(n0 + row) * 1024 + kbase + off;
            *(uint4*)&Bh[row * 72 + off] = *(const uint4*)&Bh_g[gb];
            *(uint4*)&Bl[row * 72 + off] = *(const uint4*)&Bl_g[gb];
        }
        __syncthreads();
#pragma unroll
        for (int ks = 0; ks < 2; ++ks) {
            s8v ah[4], alv[4], bh[4], blv[4];
#pragma unroll
            for (int fm = 0; fm < 4; ++fm) {
                int o = (wm * 64 + fm * 16 + ln) * 72 + ks * 32 + qd * 8;
                ah[fm]  = *(const s8v*)&Ah[o];
                alv[fm] = *(const s8v*)&Al[o];
            }
#pragma unroll
            for (int fn = 0; fn < 4; ++fn) {
                int o = (wn * 64 + fn * 16 + ln) * 72 + ks * 32 + qd * 8;
                bh[fn]  = *(const s8v*)&Bh[o];
                blv[fn] = *(const s8v*)&Bl[o];
            }
#pragma unroll
            for (int fm = 0; fm < 4; ++fm)
#pragma unroll
                for (int fn = 0; fn < 4; ++fn) {
                    C[fm][fn] = MFMA16(ah[fm],  bh[fn],  C[fm][fn]);
                    C[fm][fn] = MFMA16(ah[fm],  blv[fn], C[fm][fn]);
                    C[fm][fn] = MFMA16(alv[fm], bh[fn],  C[fm][fn]);
                }
        }
    }
    const int h = n0 >> 7;
#pragma unroll
    for (int fm = 0; fm < 4; ++fm)
#pragma unroll
        for (int fn = 0; fn < 4; ++fn)
#pragma unroll
            for (int r = 0; r < 4; ++r) {
                int token = i0 + wm * 64 + fm * 16 + qd * 4 + r;
                int f = wn * 64 + fn * 16 + ln;
                int b = token >> 11, s = token & 2047;
                u16 hh, ll;
                bfsplit(C[fm][fn][r] * scale, hh, ll);
                size_t o = ((((size_t)(b * NH + h)) * SS + s) << 7) + f;
                out_h[o] = hh; out_l[o] = ll;
            }
}

// ---------------------------------------------------------------------------
// Gate: dense sparse-valued gate g[token][h][e]
// ---------------------------------------------------------------------------
__global__ void gate_kernel(const float* __restrict__ x,
                            const float* __restrict__ sel,
                            float* __restrict__ gdense) {
    __shared__ float xs[DM];
    __shared__ float logits[64];
    __shared__ int   sbest[NH];
    __shared__ float sg1[NH], sg2[NH];
    const int token = blockIdx.x;
    const int t = threadIdx.x;  // 0..63
    const float* xp = x + (size_t)token * DM;
    for (int i = t; i < DM; i += 64) xs[i] = xp[i];
    __syncthreads();
    const float* sp = sel + (size_t)t * DM;
    float acc = 0.f;
    for (int d = 0; d < DM; ++d) acc += xs[d] * sp[d];
    logits[t] = acc;
    __syncthreads();
    if (t < NH) {
        const float* lp = logits + t * NE;
        int best = 0; float bv = lp[0];
#pragma unroll
        for (int e = 1; e < NE - 1; ++e)
            if (lp[e] > bv) { bv = lp[e]; best = e; }   // strict > == lowest idx tie
        sbest[t] = best;
        sg1[t] = 1.f / (1.f + expf(-bv));
        sg2[t] = 1.f / (1.f + expf(-lp[NE - 1]));
    }
    __syncthreads();
    const int h = t >> 3, e = t & 7;
    float val = (e == sbest[h]) ? sg1[h] : ((e == NE - 1) ? sg2[h] : 0.f);
    gdense[(size_t)token * 64 + t] = val;
}

// ---------------------------------------------------------------------------
// Preprocess: split fp32 -> bf16 hi/lo (no transpose). n divisible by 1024.
// ---------------------------------------------------------------------------
__global__ void split_kernel(const float* __restrict__ src,
                             u16* __restrict__ dh, u16* __restrict__ dl) {
    int i = (blockIdx.x * 256 + threadIdx.x) * 4;
    float4 v = *(const float4*)(src + i);
    u16 h[4], l[4];
    bfsplit(v.x, h[0], l[0]); bfsplit(v.y, h[1], l[1]);
    bfsplit(v.z, h[2], l[2]); bfsplit(v.w, h[3], l[3]);
    uint2 ph = { (unsigned)h[0] | ((unsigned)h[1] << 16),
                 (unsigned)h[2] | ((unsigned)h[3] << 16) };
    uint2 pl = { (unsigned)l[0] | ((unsigned)l[1] << 16),
                 (unsigned)l[2] | ((unsigned)l[3] << 16) };
    *(uint2*)&dh[i] = ph;
    *(uint2*)&dl[i] = pl;
}

// ---------------------------------------------------------------------------
// Preprocess: per-matrix transpose + split. src[mat][R][C] -> dst[mat][C][R].
// ---------------------------------------------------------------------------
__global__ void tsplit_kernel(const float* __restrict__ src,
                              u16* __restrict__ dh, u16* __restrict__ dl,
                              int R, int C) {
    __shared__ float tile[32][33];
    const int mat = blockIdx.x;
    const int r0 = blockIdx.y * 32, c0 = blockIdx.z * 32;
    const size_t base = (size_t)mat * R * C;
    const int tr = threadIdx.x >> 5, tc = threadIdx.x & 31;
#pragma unroll
    for (int p = 0; p < 4; ++p)
        tile[tr + p * 8][tc] = src[base + (size_t)(r0 + tr + p * 8) * C + c0 + tc];
    __syncthreads();
#pragma unroll
    for (int p = 0; p < 4; ++p) {
        int cc = tr + p * 8, rr = tc;
        float x = tile[rr][cc];
        u16 hh, ll; bfsplit(x, hh, ll);
        size_t o = base + (size_t)(c0 + cc) * R + r0 + rr;
        dh[o] = hh; dl[o] = ll;
    }
}

// ---------------------------------------------------------------------------
// Value CVMM, split-bf16 MFMA, dense over experts.
// ---------------------------------------------------------------------------
__global__ __launch_bounds__(256, 2) void v_mfma_kernel(
        const u16* __restrict__ Ah_g, const u16* __restrict__ Al_g,
        const u16* __restrict__ Bh_g, const u16* __restrict__ Bl_g,
        const float* __restrict__ gdense,
        float* __restrict__ wv) {
    const int i0 = blockIdx.x * 128;
    const int h  = blockIdx.y;
    __shared__ u16 Ah[128 * 72], Al[128 * 72], Bh[128 * 72], Bl[128 * 72];
    __shared__ float gl[128 * 8];
    const int t = threadIdx.x;
    const int lane = t & 63, wave = t >> 6;
    const int wm = wave >> 1, wn = wave & 1;
    const int ln = lane & 15, qd = lane >> 4;
    const f4v z4 = {0.f, 0.f, 0.f, 0.f};

#pragma unroll
    for (int p = 0; p < 4; ++p) {
        int idx = p * 256 + t;
        gl[idx] = gdense[(size_t)(i0 + (idx >> 3)) * 64 + h * 8 + (idx & 7)];
    }

    f4v C[4][4];
#pragma unroll
    for (int fm = 0; fm < 4; ++fm)
#pragma unroll
        for (int fn = 0; fn < 4; ++fn) C[fm][fn] = z4;

    for (int e = 0; e < 8; ++e) {
        f4v T[4][4];
#pragma unroll
        for (int fm = 0; fm < 4; ++fm)
#pragma unroll
            for (int fn = 0; fn < 4; ++fn) T[fm][fn] = z4;
        const size_t bbase = (size_t)(h * 8 + e) * DH * 1024;
        for (int kb = 0; kb < 16; ++kb) {
            __syncthreads();
            const int kbase = kb * 64;
#pragma unroll
            for (int p = 0; p < 4; ++p) {
                int chunk = p * 256 + t;
                int row = chunk >> 3, off = (chunk & 7) * 8;
                size_t ga = (size_t)(i0 + row) * 1024 + kbase + off;
                *(uint4*)&Ah[row * 72 + off] = *(const uint4*)&Ah_g[ga];
                *(uint4*)&Al[row * 72 + off] = *(const uint4*)&Al_g[ga];
                size_t gb = bbase + (size_t)row * 1024 + kbase + off;
                *(uint4*)&Bh[row * 72 + off] = *(const uint4*)&Bh_g[gb];
                *(uint4*)&Bl[row * 72 + off] = *(const uint4*)&Bl_g[gb];
            }
            __syncthreads();
#pragma unroll
            for (int ks = 0; ks < 2; ++ks) {
                s8v ah[4], alv[4], bh[4], blv[4];
#pragma unroll
                for (int fm = 0; fm < 4; ++fm) {
                    int o = (wm * 64 + fm * 16 + ln) * 72 + ks * 32 + qd * 8;
                    ah[fm]  = *(const s8v*)&Ah[o];
                    alv[fm] = *(const s8v*)&Al[o];
                }
#pragma unroll
                for (int fn = 0; fn < 4; ++fn) {
                    int o = (wn * 64 + fn * 16 + ln) * 72 + ks * 32 + qd * 8;
                    bh[fn]  = *(const s8v*)&Bh[o];
                    blv[fn] = *(const s8v*)&Bl[o];
                }
#pragma unroll
                for (int fm = 0; fm < 4; ++fm)
#pragma unroll
                    for (int fn = 0; fn < 4; ++fn) {
                        T[fm][fn] = MFMA16(ah[fm],  bh[fn],  T[fm][fn]);
                        T[fm][fn] = MFMA16(ah[fm],  blv[fn], T[fm][fn]);
                        T[fm][fn] = MFMA16(alv[fm], bh[fn],  T[fm][fn]);
                    }
            }
        }
#pragma unroll
        for (int fm = 0; fm < 4; ++fm)
#pragma unroll
            for (int r = 0; r < 4; ++r) {
                float g = gl[(wm * 64 + fm * 16 + qd * 4 + r) * 8 + e];
#pragma unroll
                for (int fn = 0; fn < 4; ++fn)
                    C[fm][fn][r] += g * T[fm][fn][r];
            }
    }
#pragma unroll
    for (int fm = 0; fm < 4; ++fm)
#pragma unroll
        for (int fn = 0; fn < 4; ++fn)
#pragma unroll
            for (int r = 0; r < 4; ++r) {
                int token = i0 + wm * 64 + fm * 16 + qd * 4 + r;
                int f = wn * 64 + fn * 16 + ln;
                int b = token >> 11, s = token & 2047;
                wv[(((size_t)(b * NH + h) * SS + s) << 7) + f] = C[fm][fn][r];
            }
}

// ---------------------------------------------------------------------------
// Output CVMM, split-bf16 MFMA, dense over (h,e).
// ---------------------------------------------------------------------------
__global__ __launch_bounds__(256, 2) void out_mfma_kernel(
        const u16* __restrict__ Ah_g, const u16* __restrict__ Al_g,
        const u16* __restrict__ Bh_g, const u16* __restrict__ Bl_g,
        const float* __restrict__ gdense,
        float* __restrict__ out) {
    const int n0 = blockIdx.x * 128;
    const int i0 = blockIdx.y * 128;
    __shared__ u16 Ah[128 * 72], Al[128 * 72], Bh[128 * 72], Bl[128 * 72];
    __shared__ float gl[128 * 8];
    const int t = threadIdx.x;
    const int lane = t & 63, wave = t >> 6;
    const int wm = wave >> 1, wn = wave & 1;
    const int ln = lane & 15, qd = lane >> 4;
    const f4v z4 = {0.f, 0.f, 0.f, 0.f};

    f4v C[4][4];
#pragma unroll
    for (int fm = 0; fm < 4; ++fm)
#pragma unroll
        for (int fn = 0; fn < 4; ++fn) C[fm][fn] = z4;

    for (int h = 0; h < 8; ++h) {
        __syncthreads();
#pragma unroll
        for (int p = 0; p < 4; ++p) {
            int idx = p * 256 + t;
            gl[idx] = gdense[(size_t)(i0 + (idx >> 3)) * 64 + h * 8 + (idx & 7)];
        }
        for (int e = 0; e < 8; ++e) {
            f4v T[4][4];
#pragma unroll
            for (int fm = 0; fm < 4; ++fm)
#pragma unroll
                for (int fn = 0; fn < 4; ++fn) T[fm][fn] = z4;
            const size_t bbase = ((size_t)(h * 8 + e) * 1024 + n0) * DH;
#pragma unroll
            for (int kb = 0; kb < 2; ++kb) {
                __syncthreads();
                const int ka = h * 128 + kb * 64;
                const int kbb = kb * 64;
#pragma unroll
                for (int p = 0; p < 4; ++p) {
                    int chunk = p * 256 + t;
                    int row = chunk >> 3, off = (chunk & 7) * 8;
                    size_t ga = (size_t)(i0 + row) * 1024 + ka + off;
                    *(uint4*)&Ah[row * 72 + off] = *(const uint4*)&Ah_g[ga];
                    *(uint4*)&Al[row * 72 + off] = *(const uint4*)&Al_g[ga];
                    size_t gb = bbase + (size_t)row * DH + kbb + off;
                    *(uint4*)&Bh[row * 72 + off] = *(const uint4*)&Bh_g[gb];
                    *(uint4*)&Bl[row * 72 + off] = *(const uint4*)&Bl_g[gb];
                }
                __syncthreads();
#pragma unroll
                for (int ks = 0; ks < 2; ++ks) {
                    s8v ah[4], alv[4], bh[4], blv[4];
#pragma unroll
                    for (int fm = 0; fm < 4; ++fm) {
                        int o = (wm * 64 + fm * 16 + ln) * 72 + ks * 32 + qd * 8;
                        ah[fm]  = *(const s8v*)&Ah[o];
                        alv[fm] = *(const s8v*)&Al[o];
                    }
#pragma unroll
                    for (int fn = 0; fn < 4; ++fn) {
                        int o = (wn * 64 + fn * 16 + ln) * 72 + ks * 32 + qd * 8;
                        bh[fn]  = *(const s8v*)&Bh[o];
                        blv[fn] = *(const s8v*)&Bl[o];
                    }
#pragma unroll
                    for (int fm = 0; fm < 4; ++fm)
#pragma unroll
                        for (int fn = 0; fn < 4; ++fn) {
                            T[fm][fn] = MFMA16(ah[fm],  bh[fn],  T[fm][fn]);
                            T[fm][fn] = MFMA16(ah[fm],  blv[fn], T[fm][fn]);
                            T[fm][fn] = MFMA16(alv[fm], bh[fn],  T[fm][fn]);
                        }
                }
            }
#pragma unroll
            for (int fm = 0; fm < 4; ++fm)
#pragma unroll
                for (int r = 0; r < 4; ++r) {
                    float g = gl[(wm * 64 + fm * 16 + qd * 4 + r) * 8 + e];
#pragma unroll
                    for (int fn = 0; fn < 4; ++fn)
                        C[fm][fn][r] += g * T[fm][fn][r];
                }
        }
    }
#pragma unroll
    for (int fm = 0; fm < 4; ++fm)
#pragma unroll
        for (int fn = 0; fn < 4; ++fn)
#pragma unroll
            for (int r = 0; r < 4; ++r) {
                int token = i0 + wm * 64 + fm * 16 + qd * 4 + r;
                int d = n0 + wn * 64 + fn * 16 + ln;
                out[(size_t)token * DM + d] = C[fm][fn][r];
            }
}

// ---------------------------------------------------------------------------
// MFMA flash attention. Block = (b,h) x 64 queries; 4 waves, 16 q-rows each.
// KVBLK = 32 (was 64): LDS 43008 B -> 3 blocks/CU (was 80896 B -> 2).
// Online softmax in registers; per-tile MFMA/col unchanged, tiles doubled.
// ---------------------------------------------------------------------------
__global__ void attn_mfma_kernel(
        const u16* __restrict__ qh, const u16* __restrict__ ql,
        const u16* __restrict__ kh, const u16* __restrict__ kl,
        const u16* __restrict__ vth, const u16* __restrict__ vtl,
        u16* __restrict__ res_hi, u16* __restrict__ res_lo) {
    const int bid = blockIdx.x;          // bh*32 + qtile
    const int bh = bid >> 5;
    const int q0 = (bid & 31) * 64;

    __shared__ u16 Ksh[32 * 136];        // 8704 B
    __shared__ u16 Ksl[32 * 136];
    __shared__ u16 Vsh[128 * 40];        // 10240 B
    __shared__ u16 Vsl[128 * 40];
    __shared__ u16 Ps[4][16 * 40];       // 5120 B   -> total 43008 B

    const int t = threadIdx.x;
    const int lane = t & 63, w = t >> 6;
    const int ln = lane & 15, qd = lane >> 4;

    // Q A-fragments in registers (m = ln, k = ks*32 + qd*8 + 0..7)
    s8v Qh[4], Qlv[4];
    {
        const size_t qoff = ((size_t)bh * SS + q0 + w * 16 + ln) * DH;
        const u16* qhp = qh + qoff;
        const u16* qlp = ql + qoff;
#pragma unroll
        for (int ks = 0; ks < 4; ++ks) {
            Qh[ks]  = *(const s8v*)(qhp + ks * 32 + qd * 8);
            Qlv[ks] = *(const s8v*)(qlp + ks * 32 + qd * 8);
        }
    }

    f4v Of[8];
    const f4v z4 = {0.f, 0.f, 0.f, 0.f};
#pragma unroll
    for (int fn = 0; fn < 8; ++fn) Of[fn] = z4;
    float mrow[4], lrow[4];
#pragma unroll
    for (int r = 0; r < 4; ++r) { mrow[r] = -INFINITY; lrow[r] = 0.f; }

    const u16* kbh = kh + (size_t)bh * SS * DH;
    const u16* kbl = kl + (size_t)bh * SS * DH;
    const u16* vbh = vth + (size_t)bh * DH * SS;   // [f][s]
    const u16* vbl = vtl + (size_t)bh * DH * SS;

    for (int kt = 0; kt < SS / 32; ++kt) {
        __syncthreads();   // all waves done with previous K/V tiles
        // ---- stage K [32 x 128] and V [128 x 32] hi/lo (512 chunks) ----
#pragma unroll
        for (int p = 0; p < 2; ++p) {
            int chunk = p * 256 + t;
            int krow = chunk >> 4, kc = chunk & 15;
            size_t g = (size_t)(kt * 32 + krow) * DH + kc * 8;
            *(uint4*)&Ksh[krow * 136 + kc * 8] = *(const uint4*)&kbh[g];
            *(uint4*)&Ksl[krow * 136 + kc * 8] = *(const uint4*)&kbl[g];
            int vrow = chunk >> 2, vc = chunk & 3;
            size_t gvo = (size_t)vrow * SS + kt * 32 + vc * 8;
            *(uint4*)&Vsh[vrow * 40 + vc * 8] = *(const uint4*)&vbh[gvo];
            *(uint4*)&Vsl[vrow * 40 + vc * 8] = *(const uint4*)&vbl[gvo];
        }
        __syncthreads();

        // ---- QK^T: S[nt] covers cols nt*16+ln (32 cols), rows qd*4+r ----
        f4v S[2];
#pragma unroll
        for (int nt = 0; nt < 2; ++nt) S[nt] = z4;
#pragma unroll
        for (int ks = 0; ks < 4; ++ks) {
#pragma unroll
            for (int nt = 0; nt < 2; ++nt) {
                int o = (nt * 16 + ln) * 136 + ks * 32 + qd * 8;
                s8v kbhf = *(const s8v*)&Ksh[o];
                s8v kblf = *(const s8v*)&Ksl[o];
                S[nt] = MFMA16(Qh[ks],  kbhf, S[nt]);
                S[nt] = MFMA16(Qh[ks],  kblf, S[nt]);
                S[nt] = MFMA16(Qlv[ks], kbhf, S[nt]);
            }
        }

        // ---- online softmax in registers ----
        float mt[4];
#pragma unroll
        for (int r = 0; r < 4; ++r) mt[r] = fmaxf(S[0][r], S[1][r]);
#pragma unroll
        for (int mask = 1; mask < 16; mask <<= 1)
#pragma unroll
            for (int r = 0; r < 4; ++r)
                mt[r] = fmaxf(mt[r], __shfl_xor(mt[r], mask, 64));
        float alpha[4];
#pragma unroll
        for (int r = 0; r < 4; ++r) {
            float mn = fmaxf(mrow[r], mt[r]);
            alpha[r] = __expf(mrow[r] - mn);
            mrow[r] = mn;
        }
        float pv[2][4], lt[4] = {0.f, 0.f, 0.f, 0.f};
#pragma unroll
        for (int nt = 0; nt < 2; ++nt)
#pragma unroll
            for (int r = 0; r < 4; ++r) {
                float p = __expf(S[nt][r] - mrow[r]);
                pv[nt][r] = p;
                lt[r] += p;
            }
#pragma unroll
        for (int mask = 1; mask < 16; mask <<= 1)
#pragma unroll
            for (int r = 0; r < 4; ++r)
                lt[r] += __shfl_xor(lt[r], mask, 64);
#pragma unroll
        for (int r = 0; r < 4; ++r) lrow[r] = alpha[r] * lrow[r] + lt[r];
#pragma unroll
        for (int fn = 0; fn < 8; ++fn)
#pragma unroll
            for (int r = 0; r < 4; ++r) Of[fn][r] *= alpha[r];

        // ---- P (C-layout) -> per-wave LDS (A-layout source) ----
#pragma unroll
        for (int nt = 0; nt < 2; ++nt)
#pragma unroll
            for (int r = 0; r < 4; ++r)
                Ps[w][(qd * 4 + r) * 40 + nt * 16 + ln] = bf16rne(pv[nt][r]);
        // same-wave write->read: compiler inserts lgkmcnt wait; no barrier.

        // ---- PV: Of += P * V (V split hi/lo), single k-block of 32 ----
        s8v pf = *(const s8v*)&Ps[w][ln * 40 + qd * 8];
#pragma unroll
        for (int fn = 0; fn < 8; ++fn) {
            int o = (fn * 16 + ln) * 40 + qd * 8;
            s8v vbhf = *(const s8v*)&Vsh[o];
            s8v vblf = *(const s8v*)&Vsl[o];
            Of[fn] = MFMA16(pf, vbhf, Of[fn]);
            Of[fn] = MFMA16(pf, vblf, Of[fn]);
        }
    }

    // ---- epilogue: normalize, split to bf16 hi/lo, store res[token][1024] --
    const int b = bh >> 3, h = bh & 7;
#pragma unroll
    for (int r = 0; r < 4; ++r) {
        float linv = 1.f / lrow[r];
        int qi = q0 + w * 16 + qd * 4 + r;
        size_t off = (size_t)(b * SS + qi) * DM + h * DH + ln;
#pragma unroll
        for (int fn = 0; fn < 8; ++fn) {
            u16 hh, ll;
            bfsplit(Of[fn][r] * linv, hh, ll);
            res_hi[off + fn * 16] = hh;
            res_lo[off + fn * 16] = ll;
        }
    }
}

// ---------------------------------------------------------------------------
extern "C" void kernel_launch(void* const* d_in, const int* in_sizes, int n_in,
                              void* d_out, int out_size, void* d_ws, size_t ws_size,
                              hipStream_t stream) {
    (void)in_sizes; (void)n_in; (void)out_size; (void)ws_size;
    const float* q_src = (const float*)d_in[0];
    const float* k_src = (const float*)d_in[1];
    const float* v_src = (const float*)d_in[2];
    const float* Wq    = (const float*)d_in[3];
    const float* Wk    = (const float*)d_in[4];
    const float* V     = (const float*)d_in[5];
    const float* O     = (const float*)d_in[6];
    const float* sel_v = (const float*)d_in[7];
    const float* sel_o = (const float*)d_in[8];
    float* out = (float*)d_out;

    // workspace layout
    const size_t NELT = (size_t)NTOK * DM;   // 8388608
    u16* wq_h = (u16*)d_ws;                  // q hi/lo [bh][s][f]
    u16* wq_l = wq_h + NELT;
    u16* wk_h = wq_l + NELT;                 // k hi/lo
    u16* wk_l = wk_h + NELT;
    float* wv = (float*)(wk_l + NELT);       // v fp32 [bh][s][f]
    u16* res_hi = (u16*)(wv + NELT);         // attention result hi/lo
    u16* res_lo = res_hi + NELT;
    u16* vs_hi  = res_lo + NELT;             // vsrc split (later: Ot)
    u16* vs_lo  = vs_hi + NELT;
    u16* Vt_hi  = vs_lo + NELT;              // V transposed (later: vT)
    u16* Vt_lo  = Vt_hi + NELT;
    float* gv = (float*)(Vt_lo + NELT);      // dense gates [8192][64]
    float* go = gv + (size_t)NTOK * 64;
    u16* Wq_h = (u16*)(go + (size_t)NTOK * 64);  // W splits (1024x1024 each)
    u16* Wq_l = Wq_h + (size_t)DM * DM;
    u16* Wk_h = Wq_l + (size_t)DM * DM;
    u16* Wk_l = Wk_h + (size_t)DM * DM;
    // aliases (regions dead during the phase they are used)
    u16* qsrc_h = res_hi;                    // dead until attn writes res
    u16* qsrc_l = res_lo;
    u16* ksrc_h = (u16*)wv;                  // dead until v_mfma writes wv
    u16* ksrc_l = ksrc_h + NELT;
    u16* Ot_hi = vs_hi;                      // alias (dead after v_mfma)
    u16* Ot_lo = vs_lo;
    u16* vth   = Vt_hi;                      // alias (dead after v_mfma)
    u16* vtl   = Vt_lo;

    // preprocess: splits
    split_kernel<<<NELT / 1024, 256, 0, stream>>>(v_src, vs_hi, vs_lo);
    split_kernel<<<NELT / 1024, 256, 0, stream>>>(q_src, qsrc_h, qsrc_l);
    split_kernel<<<NELT / 1024, 256, 0, stream>>>(k_src, ksrc_h, ksrc_l);
    split_kernel<<<(DM * DM) / 1024, 256, 0, stream>>>(Wq, Wq_h, Wq_l);
    split_kernel<<<(DM * DM) / 1024, 256, 0, stream>>>(Wk, Wk_h, Wk_l);
    tsplit_kernel<<<dim3(64, 32, 4), 256, 0, stream>>>(V, Vt_hi, Vt_lo, 1024, 128);

    // gates
    gate_kernel<<<NTOK, 64, 0, stream>>>(k_src, sel_v, gv);
    gate_kernel<<<NTOK, 64, 0, stream>>>(q_src, sel_o, go);

    // q/k projections via MFMA (emit bf16 hi/lo)
    proj_mfma_kernel<<<dim3(64, 8), 256, 0, stream>>>(
        qsrc_h, qsrc_l, Wq_h, Wq_l, wq_h, wq_l, SCALE_SQRT);
    proj_mfma_kernel<<<dim3(64, 8), 256, 0, stream>>>(
        ksrc_h, ksrc_l, Wk_h, Wk_l, wk_h, wk_l, SCALE_SQRT);

    // value CVMM (MFMA) -> wv fp32 (overwrites ksrc splits: proj done)
    v_mfma_kernel<<<dim3(64, 8), 256, 0, stream>>>(vs_hi, vs_lo, Vt_hi, Vt_lo, gv, wv);

    // transpose+split O into dead vsrc buffers
    tsplit_kernel<<<dim3(64, 4, 32), 256, 0, stream>>>(O, Ot_hi, Ot_lo, 128, 1024);

    // transpose+split v into dead Vt buffers: vT[bh][f][s]
    tsplit_kernel<<<dim3(32, 64, 4), 256, 0, stream>>>(wv, vth, vtl, 2048, 128);

    // attention (MFMA flash; writes res = overwrites qsrc splits: proj done)
    attn_mfma_kernel<<<BB * NH * (SS / 64), 256, 0, stream>>>(
        wq_h, wq_l, wk_h, wk_l, vth, vtl, res_hi, res_lo);

    // output CVMM (MFMA)
    out_mfma_kernel<<<dim3(8, 64), 256, 0, stream>>>(res_hi, res_lo, Ot_hi, Ot_lo, go, out);
}

// Round 3
// 2068.825 us; speedup vs baseline: 1.5591x; 1.0420x over previous
//
#include <hip/hip_runtime.h>
#include <hip/hip_bf16.h>
#include <math.h>

// Problem constants
#define BB 4
#define SS 2048
#define DM 1024
#define NH 8
#define DH 128
#define NE 8
#define NTOK (BB*SS)          // 8192
#define SCALE_SQRT 0.29730177875068026f

typedef unsigned short u16;
typedef short s8v __attribute__((ext_vector_type(8)));
typedef float f4v __attribute__((ext_vector_type(4)));
#define MFMA16(a,b,c) __builtin_amdgcn_mfma_f32_16x16x32_bf16((a),(b),(c),0,0,0)

// Round-to-nearest-even fp32 -> bf16 split: x ~= hi + lo (each bf16).
__device__ inline void bfsplit(float x, u16& h, u16& l) {
    unsigned u = __float_as_uint(x);
    unsigned hr = (u + 0x7FFFu + ((u >> 16) & 1u)) >> 16;
    h = (u16)hr;
    float hf = __uint_as_float(hr << 16);
    unsigned u2 = __float_as_uint(x - hf);
    l = (u16)((u2 + 0x7FFFu + ((u2 >> 16) & 1u)) >> 16);
}
__device__ inline u16 bf16rne(float x) {
    unsigned u = __float_as_uint(x);
    return (u16)((u + 0x7FFFu + ((u >> 16) & 1u)) >> 16);
}

// Async global->LDS 16B copy. LDS dest = wave-uniform base + lane*16.
__device__ inline void gll16(const u16* g, u16* l) {
    __builtin_amdgcn_global_load_lds(
        (const __attribute__((address_space(1))) unsigned int*)g,
        (__attribute__((address_space(3))) unsigned int*)l,
        16, 0, 0);
}

// Swizzled tile offset (u16 units) for [128][64]-u16 tiles staged linearly:
// row's 16B chunk c stored at chunk index c ^ (row&7). Same XOR on read.
__device__ inline int swzoff(int row, int kchunk) {
    return row * 64 + ((kchunk ^ (row & 7)) << 3);
}

// ---------------------------------------------------------------------------
// Projection GEMM via split-bf16 MFMA (3-term): out = scale * (x @ W^T).
// global_load_lds staging, XOR-swizzled unpadded [128][64] tiles.
// ---------------------------------------------------------------------------
__global__ __launch_bounds__(256, 2) void proj_mfma_kernel(
        const u16* __restrict__ Ah_g, const u16* __restrict__ Al_g,
        const u16* __restrict__ Bh_g, const u16* __restrict__ Bl_g,
        u16* __restrict__ out_h, u16* __restrict__ out_l, float scale) {
    const int i0 = blockIdx.x * 128;
    const int n0 = blockIdx.y * 128;
    __shared__ u16 Ah[128 * 64], Al[128 * 64], Bh[128 * 64], Bl[128 * 64];
    const int t = threadIdx.x;
    const int lane = t & 63, wave = t >> 6;
    const int wm = wave >> 1, wn = wave & 1;
    const int ln = lane & 15, qd = lane >> 4;
    const f4v z4 = {0.f, 0.f, 0.f, 0.f};

    f4v C[4][4];
#pragma unroll
    for (int fm = 0; fm < 4; ++fm)
#pragma unroll
        for (int fn = 0; fn < 4; ++fn) C[fm][fn] = z4;

    for (int kb = 0; kb < 16; ++kb) {
        __syncthreads();
        const int kbase = kb * 64;
#pragma unroll
        for (int p = 0; p < 4; ++p) {
            int chunk = p * 256 + t;
            int row = chunk >> 3;
            int cs  = ((chunk & 7) ^ (row & 7)) * 8;     // swizzled src col (u16)
            int ld  = (p * 256 + (t & 192)) * 8;         // wave-uniform LDS base
            size_t ga = (size_t)(i0 + row) * 1024 + kbase + cs;
            gll16(&Ah_g[ga], &Ah[ld]);
            gll16(&Al_g[ga], &Al[ld]);
            size_t gb = (size_t)(n0 + row) * 1024 + kbase + cs;
            gll16(&Bh_g[gb], &Bh[ld]);
            gll16(&Bl_g[gb], &Bl[ld]);
        }
        __syncthreads();
#pragma unroll
        for (int ks = 0; ks < 2; ++ks) {
            s8v ah[4], alv[4], bh[4], blv[4];
#pragma unroll
            for (int fm = 0; fm < 4; ++fm) {
                int o = swzoff(wm * 64 + fm * 16 + ln, ks * 4 + qd);
                ah[fm]  = *(const s8v*)&Ah[o];
                alv[fm] = *(const s8v*)&Al[o];
            }
#pragma unroll
            for (int fn = 0; fn < 4; ++fn) {
                int o = swzoff(wn * 64 + fn * 16 + ln, ks * 4 + qd);
                bh[fn]  = *(const s8v*)&Bh[o];
                blv[fn] = *(const s8v*)&Bl[o];
            }
#pragma unroll
            for (int fm = 0; fm < 4; ++fm)
#pragma unroll
                for (int fn = 0; fn < 4; ++fn) {
                    C[fm][fn] = MFMA16(ah[fm],  bh[fn],  C[fm][fn]);
                    C[fm][fn] = MFMA16(ah[fm],  blv[fn], C[fm][fn]);
                    C[fm][fn] = MFMA16(alv[fm], bh[fn],  C[fm][fn]);
                }
        }
    }
    const int h = n0 >> 7;
#pragma unroll
    for (int fm = 0; fm < 4; ++fm)
#pragma unroll
        for (int fn = 0; fn < 4; ++fn)
#pragma unroll
            for (int r = 0; r < 4; ++r) {
                int token = i0 + wm * 64 + fm * 16 + qd * 4 + r;
                int f = wn * 64 + fn * 16 + ln;
                int b = token >> 11, s = token & 2047;
                u16 hh, ll;
                bfsplit(C[fm][fn][r] * scale, hh, ll);
                size_t o = ((((size_t)(b * NH + h)) * SS + s) << 7) + f;
                out_h[o] = hh; out_l[o] = ll;
            }
}

// ---------------------------------------------------------------------------
// Gate: dense sparse-valued gate g[token][h][e]
// ---------------------------------------------------------------------------
__global__ void gate_kernel(const float* __restrict__ x,
                            const float* __restrict__ sel,
                            float* __restrict__ gdense) {
    __shared__ float xs[DM];
    __shared__ float logits[64];
    __shared__ int   sbest[NH];
    __shared__ float sg1[NH], sg2[NH];
    const int token = blockIdx.x;
    const int t = threadIdx.x;  // 0..63
    const float* xp = x + (size_t)token * DM;
    for (int i = t; i < DM; i += 64) xs[i] = xp[i];
    __syncthreads();
    const float* sp = sel + (size_t)t * DM;
    float acc = 0.f;
    for (int d = 0; d < DM; ++d) acc += xs[d] * sp[d];
    logits[t] = acc;
    __syncthreads();
    if (t < NH) {
        const float* lp = logits + t * NE;
        int best = 0; float bv = lp[0];
#pragma unroll
        for (int e = 1; e < NE - 1; ++e)
            if (lp[e] > bv) { bv = lp[e]; best = e; }   // strict > == lowest idx tie
        sbest[t] = best;
        sg1[t] = 1.f / (1.f + expf(-bv));
        sg2[t] = 1.f / (1.f + expf(-lp[NE - 1]));
    }
    __syncthreads();
    const int h = t >> 3, e = t & 7;
    float val = (e == sbest[h]) ? sg1[h] : ((e == NE - 1) ? sg2[h] : 0.f);
    gdense[(size_t)token * 64 + t] = val;
}

// ---------------------------------------------------------------------------
// Preprocess: split fp32 -> bf16 hi/lo (no transpose). n divisible by 1024.
// ---------------------------------------------------------------------------
__global__ void split_kernel(const float* __restrict__ src,
                             u16* __restrict__ dh, u16* __restrict__ dl) {
    int i = (blockIdx.x * 256 + threadIdx.x) * 4;
    float4 v = *(const float4*)(src + i);
    u16 h[4], l[4];
    bfsplit(v.x, h[0], l[0]); bfsplit(v.y, h[1], l[1]);
    bfsplit(v.z, h[2], l[2]); bfsplit(v.w, h[3], l[3]);
    uint2 ph = { (unsigned)h[0] | ((unsigned)h[1] << 16),
                 (unsigned)h[2] | ((unsigned)h[3] << 16) };
    uint2 pl = { (unsigned)l[0] | ((unsigned)l[1] << 16),
                 (unsigned)l[2] | ((unsigned)l[3] << 16) };
    *(uint2*)&dh[i] = ph;
    *(uint2*)&dl[i] = pl;
}

// ---------------------------------------------------------------------------
// Preprocess: per-matrix transpose + split. src[mat][R][C] -> dst[mat][C][R].
// ---------------------------------------------------------------------------
__global__ void tsplit_kernel(const float* __restrict__ src,
                              u16* __restrict__ dh, u16* __restrict__ dl,
                              int R, int C) {
    __shared__ float tile[32][33];
    const int mat = blockIdx.x;
    const int r0 = blockIdx.y * 32, c0 = blockIdx.z * 32;
    const size_t base = (size_t)mat * R * C;
    const int tr = threadIdx.x >> 5, tc = threadIdx.x & 31;
#pragma unroll
    for (int p = 0; p < 4; ++p)
        tile[tr + p * 8][tc] = src[base + (size_t)(r0 + tr + p * 8) * C + c0 + tc];
    __syncthreads();
#pragma unroll
    for (int p = 0; p < 4; ++p) {
        int cc = tr + p * 8, rr = tc;
        float x = tile[rr][cc];
        u16 hh, ll; bfsplit(x, hh, ll);
        size_t o = base + (size_t)(c0 + cc) * R + r0 + rr;
        dh[o] = hh; dl[o] = ll;
    }
}

// ---------------------------------------------------------------------------
// Value CVMM, split-bf16 MFMA, dense over experts.
// global_load_lds staging, XOR-swizzled unpadded [128][64] tiles.
// ---------------------------------------------------------------------------
__global__ __launch_bounds__(256, 2) void v_mfma_kernel(
        const u16* __restrict__ Ah_g, const u16* __restrict__ Al_g,
        const u16* __restrict__ Bh_g, const u16* __restrict__ Bl_g,
        const float* __restrict__ gdense,
        float* __restrict__ wv) {
    const int i0 = blockIdx.x * 128;
    const int h  = blockIdx.y;
    __shared__ u16 Ah[128 * 64], Al[128 * 64], Bh[128 * 64], Bl[128 * 64];
    __shared__ float gl[128 * 8];
    const int t = threadIdx.x;
    const int lane = t & 63, wave = t >> 6;
    const int wm = wave >> 1, wn = wave & 1;
    const int ln = lane & 15, qd = lane >> 4;
    const f4v z4 = {0.f, 0.f, 0.f, 0.f};

#pragma unroll
    for (int p = 0; p < 4; ++p) {
        int idx = p * 256 + t;
        gl[idx] = gdense[(size_t)(i0 + (idx >> 3)) * 64 + h * 8 + (idx & 7)];
    }

    f4v C[4][4];
#pragma unroll
    for (int fm = 0; fm < 4; ++fm)
#pragma unroll
        for (int fn = 0; fn < 4; ++fn) C[fm][fn] = z4;

    for (int e = 0; e < 8; ++e) {
        f4v T[4][4];
#pragma unroll
        for (int fm = 0; fm < 4; ++fm)
#pragma unroll
            for (int fn = 0; fn < 4; ++fn) T[fm][fn] = z4;
        const size_t bbase = (size_t)(h * 8 + e) * DH * 1024;
        for (int kb = 0; kb < 16; ++kb) {
            __syncthreads();
            const int kbase = kb * 64;
#pragma unroll
            for (int p = 0; p < 4; ++p) {
                int chunk = p * 256 + t;
                int row = chunk >> 3;
                int cs  = ((chunk & 7) ^ (row & 7)) * 8;
                int ld  = (p * 256 + (t & 192)) * 8;
                size_t ga = (size_t)(i0 + row) * 1024 + kbase + cs;
                gll16(&Ah_g[ga], &Ah[ld]);
                gll16(&Al_g[ga], &Al[ld]);
                size_t gb = bbase + (size_t)row * 1024 + kbase + cs;
                gll16(&Bh_g[gb], &Bh[ld]);
                gll16(&Bl_g[gb], &Bl[ld]);
            }
            __syncthreads();
#pragma unroll
            for (int ks = 0; ks < 2; ++ks) {
                s8v ah[4], alv[4], bh[4], blv[4];
#pragma unroll
                for (int fm = 0; fm < 4; ++fm) {
                    int o = swzoff(wm * 64 + fm * 16 + ln, ks * 4 + qd);
                    ah[fm]  = *(const s8v*)&Ah[o];
                    alv[fm] = *(const s8v*)&Al[o];
                }
#pragma unroll
                for (int fn = 0; fn < 4; ++fn) {
                    int o = swzoff(wn * 64 + fn * 16 + ln, ks * 4 + qd);
                    bh[fn]  = *(const s8v*)&Bh[o];
                    blv[fn] = *(const s8v*)&Bl[o];
                }
#pragma unroll
                for (int fm = 0; fm < 4; ++fm)
#pragma unroll
                    for (int fn = 0; fn < 4; ++fn) {
                        T[fm][fn] = MFMA16(ah[fm],  bh[fn],  T[fm][fn]);
                        T[fm][fn] = MFMA16(ah[fm],  blv[fn], T[fm][fn]);
                        T[fm][fn] = MFMA16(alv[fm], bh[fn],  T[fm][fn]);
                    }
            }
        }
#pragma unroll
        for (int fm = 0; fm < 4; ++fm)
#pragma unroll
            for (int r = 0; r < 4; ++r) {
                float g = gl[(wm * 64 + fm * 16 + qd * 4 + r) * 8 + e];
#pragma unroll
                for (int fn = 0; fn < 4; ++fn)
                    C[fm][fn][r] += g * T[fm][fn][r];
            }
    }
#pragma unroll
    for (int fm = 0; fm < 4; ++fm)
#pragma unroll
        for (int fn = 0; fn < 4; ++fn)
#pragma unroll
            for (int r = 0; r < 4; ++r) {
                int token = i0 + wm * 64 + fm * 16 + qd * 4 + r;
                int f = wn * 64 + fn * 16 + ln;
                int b = token >> 11, s = token & 2047;
                wv[(((size_t)(b * NH + h) * SS + s) << 7) + f] = C[fm][fn][r];
            }
}

// ---------------------------------------------------------------------------
// Output CVMM, split-bf16 MFMA, dense over (h,e).
// global_load_lds staging, XOR-swizzled unpadded [128][64] tiles.
// ---------------------------------------------------------------------------
__global__ __launch_bounds__(256, 2) void out_mfma_kernel(
        const u16* __restrict__ Ah_g, const u16* __restrict__ Al_g,
        const u16* __restrict__ Bh_g, const u16* __restrict__ Bl_g,
        const float* __restrict__ gdense,
        float* __restrict__ out) {
    const int n0 = blockIdx.x * 128;
    const int i0 = blockIdx.y * 128;
    __shared__ u16 Ah[128 * 64], Al[128 * 64], Bh[128 * 64], Bl[128 * 64];
    __shared__ float gl[128 * 8];
    const int t = threadIdx.x;
    const int lane = t & 63, wave = t >> 6;
    const int wm = wave >> 1, wn = wave & 1;
    const int ln = lane & 15, qd = lane >> 4;
    const f4v z4 = {0.f, 0.f, 0.f, 0.f};

    f4v C[4][4];
#pragma unroll
    for (int fm = 0; fm < 4; ++fm)
#pragma unroll
        for (int fn = 0; fn < 4; ++fn) C[fm][fn] = z4;

    for (int h = 0; h < 8; ++h) {
        __syncthreads();
#pragma unroll
        for (int p = 0; p < 4; ++p) {
            int idx = p * 256 + t;
            gl[idx] = gdense[(size_t)(i0 + (idx >> 3)) * 64 + h * 8 + (idx & 7)];
        }
        for (int e = 0; e < 8; ++e) {
            f4v T[4][4];
#pragma unroll
            for (int fm = 0; fm < 4; ++fm)
#pragma unroll
                for (int fn = 0; fn < 4; ++fn) T[fm][fn] = z4;
            const size_t bbase = ((size_t)(h * 8 + e) * 1024 + n0) * DH;
#pragma unroll
            for (int kb = 0; kb < 2; ++kb) {
                __syncthreads();
                const int ka = h * 128 + kb * 64;
                const int kbb = kb * 64;
#pragma unroll
                for (int p = 0; p < 4; ++p) {
                    int chunk = p * 256 + t;
                    int row = chunk >> 3;
                    int cs  = ((chunk & 7) ^ (row & 7)) * 8;
                    int ld  = (p * 256 + (t & 192)) * 8;
                    size_t ga = (size_t)(i0 + row) * 1024 + ka + cs;
                    gll16(&Ah_g[ga], &Ah[ld]);
                    gll16(&Al_g[ga], &Al[ld]);
                    size_t gb = bbase + (size_t)row * DH + kbb + cs;
                    gll16(&Bh_g[gb], &Bh[ld]);
                    gll16(&Bl_g[gb], &Bl[ld]);
                }
                __syncthreads();
#pragma unroll
                for (int ks = 0; ks < 2; ++ks) {
                    s8v ah[4], alv[4], bh[4], blv[4];
#pragma unroll
                    for (int fm = 0; fm < 4; ++fm) {
                        int o = swzoff(wm * 64 + fm * 16 + ln, ks * 4 + qd);
                        ah[fm]  = *(const s8v*)&Ah[o];
                        alv[fm] = *(const s8v*)&Al[o];
                    }
#pragma unroll
                    for (int fn = 0; fn < 4; ++fn) {
                        int o = swzoff(wn * 64 + fn * 16 + ln, ks * 4 + qd);
                        bh[fn]  = *(const s8v*)&Bh[o];
                        blv[fn] = *(const s8v*)&Bl[o];
                    }
#pragma unroll
                    for (int fm = 0; fm < 4; ++fm)
#pragma unroll
                        for (int fn = 0; fn < 4; ++fn) {
                            T[fm][fn] = MFMA16(ah[fm],  bh[fn],  T[fm][fn]);
                            T[fm][fn] = MFMA16(ah[fm],  blv[fn], T[fm][fn]);
                            T[fm][fn] = MFMA16(alv[fm], bh[fn],  T[fm][fn]);
                        }
                }
            }
#pragma unroll
            for (int fm = 0; fm < 4; ++fm)
#pragma unroll
                for (int r = 0; r < 4; ++r) {
                    float g = gl[(wm * 64 + fm * 16 + qd * 4 + r) * 8 + e];
#pragma unroll
                    for (int fn = 0; fn < 4; ++fn)
                        C[fm][fn][r] += g * T[fm][fn][r];
                }
        }
    }
#pragma unroll
    for (int fm = 0; fm < 4; ++fm)
#pragma unroll
        for (int fn = 0; fn < 4; ++fn)
#pragma unroll
            for (int r = 0; r < 4; ++r) {
                int token = i0 + wm * 64 + fm * 16 + qd * 4 + r;
                int d = n0 + wn * 64 + fn * 16 + ln;
                out[(size_t)token * DM + d] = C[fm][fn][r];
            }
}

// ---------------------------------------------------------------------------
// MFMA flash attention (unchanged from round 2).
// ---------------------------------------------------------------------------
__global__ void attn_mfma_kernel(
        const u16* __restrict__ qh, const u16* __restrict__ ql,
        const u16* __restrict__ kh, const u16* __restrict__ kl,
        const u16* __restrict__ vth, const u16* __restrict__ vtl,
        u16* __restrict__ res_hi, u16* __restrict__ res_lo) {
    const int bid = blockIdx.x;          // bh*32 + qtile
    const int bh = bid >> 5;
    const int q0 = (bid & 31) * 64;

    __shared__ u16 Ksh[32 * 136];        // 8704 B
    __shared__ u16 Ksl[32 * 136];
    __shared__ u16 Vsh[128 * 40];        // 10240 B
    __shared__ u16 Vsl[128 * 40];
    __shared__ u16 Ps[4][16 * 40];       // 5120 B   -> total 43008 B

    const int t = threadIdx.x;
    const int lane = t & 63, w = t >> 6;
    const int ln = lane & 15, qd = lane >> 4;

    // Q A-fragments in registers (m = ln, k = ks*32 + qd*8 + 0..7)
    s8v Qh[4], Qlv[4];
    {
        const size_t qoff = ((size_t)bh * SS + q0 + w * 16 + ln) * DH;
        const u16* qhp = qh + qoff;
        const u16* qlp = ql + qoff;
#pragma unroll
        for (int ks = 0; ks < 4; ++ks) {
            Qh[ks]  = *(const s8v*)(qhp + ks * 32 + qd * 8);
            Qlv[ks] = *(const s8v*)(qlp + ks * 32 + qd * 8);
        }
    }

    f4v Of[8];
    const f4v z4 = {0.f, 0.f, 0.f, 0.f};
#pragma unroll
    for (int fn = 0; fn < 8; ++fn) Of[fn] = z4;
    float mrow[4], lrow[4];
#pragma unroll
    for (int r = 0; r < 4; ++r) { mrow[r] = -INFINITY; lrow[r] = 0.f; }

    const u16* kbh = kh + (size_t)bh * SS * DH;
    const u16* kbl = kl + (size_t)bh * SS * DH;
    const u16* vbh = vth + (size_t)bh * DH * SS;   // [f][s]
    const u16* vbl = vtl + (size_t)bh * DH * SS;

    for (int kt = 0; kt < SS / 32; ++kt) {
        __syncthreads();   // all waves done with previous K/V tiles
        // ---- stage K [32 x 128] and V [128 x 32] hi/lo (512 chunks) ----
#pragma unroll
        for (int p = 0; p < 2; ++p) {
            int chunk = p * 256 + t;
            int krow = chunk >> 4, kc = chunk & 15;
            size_t g = (size_t)(kt * 32 + krow) * DH + kc * 8;
            *(uint4*)&Ksh[krow * 136 + kc * 8] = *(const uint4*)&kbh[g];
            *(uint4*)&Ksl[krow * 136 + kc * 8] = *(const uint4*)&kbl[g];
            int vrow = chunk >> 2, vc = chunk & 3;
            size_t gvo = (size_t)vrow * SS + kt * 32 + vc * 8;
            *(uint4*)&Vsh[vrow * 40 + vc * 8] = *(const uint4*)&vbh[gvo];
            *(uint4*)&Vsl[vrow * 40 + vc * 8] = *(const uint4*)&vbl[gvo];
        }
        __syncthreads();

        // ---- QK^T: S[nt] covers cols nt*16+ln (32 cols), rows qd*4+r ----
        f4v S[2];
#pragma unroll
        for (int nt = 0; nt < 2; ++nt) S[nt] = z4;
#pragma unroll
        for (int ks = 0; ks < 4; ++ks) {
#pragma unroll
            for (int nt = 0; nt < 2; ++nt) {
                int o = (nt * 16 + ln) * 136 + ks * 32 + qd * 8;
                s8v kbhf = *(const s8v*)&Ksh[o];
                s8v kblf = *(const s8v*)&Ksl[o];
                S[nt] = MFMA16(Qh[ks],  kbhf, S[nt]);
                S[nt] = MFMA16(Qh[ks],  kblf, S[nt]);
                S[nt] = MFMA16(Qlv[ks], kbhf, S[nt]);
            }
        }

        // ---- online softmax in registers ----
        float mt[4];
#pragma unroll
        for (int r = 0; r < 4; ++r) mt[r] = fmaxf(S[0][r], S[1][r]);
#pragma unroll
        for (int mask = 1; mask < 16; mask <<= 1)
#pragma unroll
            for (int r = 0; r < 4; ++r)
                mt[r] = fmaxf(mt[r], __shfl_xor(mt[r], mask, 64));
        float alpha[4];
#pragma unroll
        for (int r = 0; r < 4; ++r) {
            float mn = fmaxf(mrow[r], mt[r]);
            alpha[r] = __expf(mrow[r] - mn);
            mrow[r] = mn;
        }
        float pv[2][4], lt[4] = {0.f, 0.f, 0.f, 0.f};
#pragma unroll
        for (int nt = 0; nt < 2; ++nt)
#pragma unroll
            for (int r = 0; r < 4; ++r) {
                float p = __expf(S[nt][r] - mrow[r]);
                pv[nt][r] = p;
                lt[r] += p;
            }
#pragma unroll
        for (int mask = 1; mask < 16; mask <<= 1)
#pragma unroll
            for (int r = 0; r < 4; ++r)
                lt[r] += __shfl_xor(lt[r], mask, 64);
#pragma unroll
        for (int r = 0; r < 4; ++r) lrow[r] = alpha[r] * lrow[r] + lt[r];
#pragma unroll
        for (int fn = 0; fn < 8; ++fn)
#pragma unroll
            for (int r = 0; r < 4; ++r) Of[fn][r] *= alpha[r];

        // ---- P (C-layout) -> per-wave LDS (A-layout source) ----
#pragma unroll
        for (int nt = 0; nt < 2; ++nt)
#pragma unroll
            for (int r = 0; r < 4; ++r)
                Ps[w][(qd * 4 + r) * 40 + nt * 16 + ln] = bf16rne(pv[nt][r]);
        // same-wave write->read: compiler inserts lgkmcnt wait; no barrier.

        // ---- PV: Of += P * V (V split hi/lo), single k-block of 32 ----
        s8v pf = *(const s8v*)&Ps[w][ln * 40 + qd * 8];
#pragma unroll
        for (int fn = 0; fn < 8; ++fn) {
            int o = (fn * 16 + ln) * 40 + qd * 8;
            s8v vbhf = *(const s8v*)&Vsh[o];
            s8v vblf = *(const s8v*)&Vsl[o];
            Of[fn] = MFMA16(pf, vbhf, Of[fn]);
            Of[fn] = MFMA16(pf, vblf, Of[fn]);
        }
    }

    // ---- epilogue: normalize, split to bf16 hi/lo, store res[token][1024] --
    const int b = bh >> 3, h = bh & 7;
#pragma unroll
    for (int r = 0; r < 4; ++r) {
        float linv = 1.f / lrow[r];
        int qi = q0 + w * 16 + qd * 4 + r;
        size_t off = (size_t)(b * SS + qi) * DM + h * DH + ln;
#pragma unroll
        for (int fn = 0; fn < 8; ++fn) {
            u16 hh, ll;
            bfsplit(Of[fn][r] * linv, hh, ll);
            res_hi[off + fn * 16] = hh;
            res_lo[off + fn * 16] = ll;
        }
    }
}

// ---------------------------------------------------------------------------
extern "C" void kernel_launch(void* const* d_in, const int* in_sizes, int n_in,
                              void* d_out, int out_size, void* d_ws, size_t ws_size,
                              hipStream_t stream) {
    (void)in_sizes; (void)n_in; (void)out_size; (void)ws_size;
    const float* q_src = (const float*)d_in[0];
    const float* k_src = (const float*)d_in[1];
    const float* v_src = (const float*)d_in[2];
    const float* Wq    = (const float*)d_in[3];
    const float* Wk    = (const float*)d_in[4];
    const float* V     = (const float*)d_in[5];
    const float* O     = (const float*)d_in[6];
    const float* sel_v = (const float*)d_in[7];
    const float* sel_o = (const float*)d_in[8];
    float* out = (float*)d_out;

    // workspace layout
    const size_t NELT = (size_t)NTOK * DM;   // 8388608
    u16* wq_h = (u16*)d_ws;                  // q hi/lo [bh][s][f]
    u16* wq_l = wq_h + NELT;
    u16* wk_h = wq_l + NELT;                 // k hi/lo
    u16* wk_l = wk_h + NELT;
    float* wv = (float*)(wk_l + NELT);       // v fp32 [bh][s][f]
    u16* res_hi = (u16*)(wv + NELT);         // attention result hi/lo
    u16* res_lo = res_hi + NELT;
    u16* vs_hi  = res_lo + NELT;             // vsrc split (later: Ot)
    u16* vs_lo  = vs_hi + NELT;
    u16* Vt_hi  = vs_lo + NELT;              // V transposed (later: vT)
    u16* Vt_lo  = Vt_hi + NELT;
    float* gv = (float*)(Vt_lo + NELT);      // dense gates [8192][64]
    float* go = gv + (size_t)NTOK * 64;
    u16* Wq_h = (u16*)(go + (size_t)NTOK * 64);  // W splits (1024x1024 each)
    u16* Wq_l = Wq_h + (size_t)DM * DM;
    u16* Wk_h = Wq_l + (size_t)DM * DM;
    u16* Wk_l = Wk_h + (size_t)DM * DM;
    // aliases (regions dead during the phase they are used)
    u16* qsrc_h = res_hi;                    // dead until attn writes res
    u16* qsrc_l = res_lo;
    u16* ksrc_h = (u16*)wv;                  // dead until v_mfma writes wv
    u16* ksrc_l = ksrc_h + NELT;
    u16* Ot_hi = vs_hi;                      // alias (dead after v_mfma)
    u16* Ot_lo = vs_lo;
    u16* vth   = Vt_hi;                      // alias (dead after v_mfma)
    u16* vtl   = Vt_lo;

    // preprocess: splits
    split_kernel<<<NELT / 1024, 256, 0, stream>>>(v_src, vs_hi, vs_lo);
    split_kernel<<<NELT / 1024, 256, 0, stream>>>(q_src, qsrc_h, qsrc_l);
    split_kernel<<<NELT / 1024, 256, 0, stream>>>(k_src, ksrc_h, ksrc_l);
    split_kernel<<<(DM * DM) / 1024, 256, 0, stream>>>(Wq, Wq_h, Wq_l);
    split_kernel<<<(DM * DM) / 1024, 256, 0, stream>>>(Wk, Wk_h, Wk_l);
    tsplit_kernel<<<dim3(64, 32, 4), 256, 0, stream>>>(V, Vt_hi, Vt_lo, 1024, 128);

    // gates
    gate_kernel<<<NTOK, 64, 0, stream>>>(k_src, sel_v, gv);
    gate_kernel<<<NTOK, 64, 0, stream>>>(q_src, sel_o, go);

    // q/k projections via MFMA (emit bf16 hi/lo)
    proj_mfma_kernel<<<dim3(64, 8), 256, 0, stream>>>(
        qsrc_h, qsrc_l, Wq_h, Wq_l, wq_h, wq_l, SCALE_SQRT);
    proj_mfma_kernel<<<dim3(64, 8), 256, 0, stream>>>(
        ksrc_h, ksrc_l, Wk_h, Wk_l, wk_h, wk_l, SCALE_SQRT);

    // value CVMM (MFMA) -> wv fp32 (overwrites ksrc splits: proj done)
    v_mfma_kernel<<<dim3(64, 8), 256, 0, stream>>>(vs_hi, vs_lo, Vt_hi, Vt_lo, gv, wv);

    // transpose+split O into dead vsrc buffers
    tsplit_kernel<<<dim3(64, 4, 32), 256, 0, stream>>>(O, Ot_hi, Ot_lo, 128, 1024);

    // transpose+split v into dead Vt buffers: vT[bh][f][s]
    tsplit_kernel<<<dim3(32, 64, 4), 256, 0, stream>>>(wv, vth, vtl, 2048, 128);

    // attention (MFMA flash; writes res = overwrites qsrc splits: proj done)
    attn_mfma_kernel<<<BB * NH * (SS / 64), 256, 0, stream>>>(
        wq_h, wq_l, wk_h, wk_l, vth, vtl, res_hi, res_lo);

    // output CVMM (MFMA)
    out_mfma_kernel<<<dim3(8, 64), 256, 0, stream>>>(res_hi, res_lo, Ot_hi, Ot_lo, go, out);
}

// Round 4
// 1934.468 us; speedup vs baseline: 1.6674x; 1.0695x over previous
//
#include <hip/hip_runtime.h>
#include <hip/hip_bf16.h>
#include <math.h>

// Problem constants
#define BB 4
#define SS 2048
#define DM 1024
#define NH 8
#define DH 128
#define NE 8
#define NTOK (BB*SS)          // 8192
#define SCALE_SQRT 0.29730177875068026f

typedef unsigned short u16;
typedef short s8v __attribute__((ext_vector_type(8)));
typedef float f4v __attribute__((ext_vector_type(4)));
#define MFMA16(a,b,c) __builtin_amdgcn_mfma_f32_16x16x32_bf16((a),(b),(c),0,0,0)

// Round-to-nearest-even fp32 -> bf16 split: x ~= hi + lo (each bf16).
__device__ inline void bfsplit(float x, u16& h, u16& l) {
    unsigned u = __float_as_uint(x);
    unsigned hr = (u + 0x7FFFu + ((u >> 16) & 1u)) >> 16;
    h = (u16)hr;
    float hf = __uint_as_float(hr << 16);
    unsigned u2 = __float_as_uint(x - hf);
    l = (u16)((u2 + 0x7FFFu + ((u2 >> 16) & 1u)) >> 16);
}
__device__ inline u16 bf16rne(float x) {
    unsigned u = __float_as_uint(x);
    return (u16)((u + 0x7FFFu + ((u >> 16) & 1u)) >> 16);
}

// Async global->LDS 16B copy. LDS dest = wave-uniform base + lane*16.
__device__ inline void gll16(const u16* g, u16* l) {
    __builtin_amdgcn_global_load_lds(
        (const __attribute__((address_space(1))) unsigned int*)g,
        (__attribute__((address_space(3))) unsigned int*)l,
        16, 0, 0);
}

// Swizzled tile offset (u16 units) for [128][64]-u16 tiles staged linearly:
// row's 16B chunk c stored at chunk index c ^ (row&7). Same XOR on read.
__device__ inline int swzoff(int row, int kchunk) {
    return row * 64 + ((kchunk ^ (row & 7)) << 3);
}

// ---------------------------------------------------------------------------
// Projection GEMM via split-bf16 MFMA (3-term): out = scale * (x @ W^T).
// global_load_lds staging, XOR-swizzled unpadded [128][64] tiles.
// ---------------------------------------------------------------------------
__global__ __launch_bounds__(256, 2) void proj_mfma_kernel(
        const u16* __restrict__ Ah_g, const u16* __restrict__ Al_g,
        const u16* __restrict__ Bh_g, const u16* __restrict__ Bl_g,
        u16* __restrict__ out_h, u16* __restrict__ out_l, float scale) {
    const int i0 = blockIdx.x * 128;
    const int n0 = blockIdx.y * 128;
    __shared__ u16 Ah[128 * 64], Al[128 * 64], Bh[128 * 64], Bl[128 * 64];
    const int t = threadIdx.x;
    const int lane = t & 63, wave = t >> 6;
    const int wm = wave >> 1, wn = wave & 1;
    const int ln = lane & 15, qd = lane >> 4;
    const f4v z4 = {0.f, 0.f, 0.f, 0.f};

    f4v C[4][4];
#pragma unroll
    for (int fm = 0; fm < 4; ++fm)
#pragma unroll
        for (int fn = 0; fn < 4; ++fn) C[fm][fn] = z4;

    for (int kb = 0; kb < 16; ++kb) {
        __syncthreads();
        const int kbase = kb * 64;
#pragma unroll
        for (int p = 0; p < 4; ++p) {
            int chunk = p * 256 + t;
            int row = chunk >> 3;
            int cs  = ((chunk & 7) ^ (row & 7)) * 8;     // swizzled src col (u16)
            int ld  = (p * 256 + (t & 192)) * 8;         // wave-uniform LDS base
            size_t ga = (size_t)(i0 + row) * 1024 + kbase + cs;
            gll16(&Ah_g[ga], &Ah[ld]);
            gll16(&Al_g[ga], &Al[ld]);
            size_t gb = (size_t)(n0 + row) * 1024 + kbase + cs;
            gll16(&Bh_g[gb], &Bh[ld]);
            gll16(&Bl_g[gb], &Bl[ld]);
        }
        __syncthreads();
#pragma unroll
        for (int ks = 0; ks < 2; ++ks) {
            s8v ah[4], alv[4], bh[4], blv[4];
#pragma unroll
            for (int fm = 0; fm < 4; ++fm) {
                int o = swzoff(wm * 64 + fm * 16 + ln, ks * 4 + qd);
                ah[fm]  = *(const s8v*)&Ah[o];
                alv[fm] = *(const s8v*)&Al[o];
            }
#pragma unroll
            for (int fn = 0; fn < 4; ++fn) {
                int o = swzoff(wn * 64 + fn * 16 + ln, ks * 4 + qd);
                bh[fn]  = *(const s8v*)&Bh[o];
                blv[fn] = *(const s8v*)&Bl[o];
            }
#pragma unroll
            for (int fm = 0; fm < 4; ++fm)
#pragma unroll
                for (int fn = 0; fn < 4; ++fn) {
                    C[fm][fn] = MFMA16(ah[fm],  bh[fn],  C[fm][fn]);
                    C[fm][fn] = MFMA16(ah[fm],  blv[fn], C[fm][fn]);
                    C[fm][fn] = MFMA16(alv[fm], bh[fn],  C[fm][fn]);
                }
        }
    }
    const int h = n0 >> 7;
#pragma unroll
    for (int fm = 0; fm < 4; ++fm)
#pragma unroll
        for (int fn = 0; fn < 4; ++fn)
#pragma unroll
            for (int r = 0; r < 4; ++r) {
                int token = i0 + wm * 64 + fm * 16 + qd * 4 + r;
                int f = wn * 64 + fn * 16 + ln;
                int b = token >> 11, s = token & 2047;
                u16 hh, ll;
                bfsplit(C[fm][fn][r] * scale, hh, ll);
                size_t o = ((((size_t)(b * NH + h)) * SS + s) << 7) + f;
                out_h[o] = hh; out_l[o] = ll;
            }
}

// ---------------------------------------------------------------------------
// Gate: dense sparse-valued gate g[token][h][e]
// ---------------------------------------------------------------------------
__global__ void gate_kernel(const float* __restrict__ x,
                            const float* __restrict__ sel,
                            float* __restrict__ gdense) {
    __shared__ float xs[DM];
    __shared__ float logits[64];
    __shared__ int   sbest[NH];
    __shared__ float sg1[NH], sg2[NH];
    const int token = blockIdx.x;
    const int t = threadIdx.x;  // 0..63
    const float* xp = x + (size_t)token * DM;
    for (int i = t; i < DM; i += 64) xs[i] = xp[i];
    __syncthreads();
    const float* sp = sel + (size_t)t * DM;
    float acc = 0.f;
    for (int d = 0; d < DM; ++d) acc += xs[d] * sp[d];
    logits[t] = acc;
    __syncthreads();
    if (t < NH) {
        const float* lp = logits + t * NE;
        int best = 0; float bv = lp[0];
#pragma unroll
        for (int e = 1; e < NE - 1; ++e)
            if (lp[e] > bv) { bv = lp[e]; best = e; }   // strict > == lowest idx tie
        sbest[t] = best;
        sg1[t] = 1.f / (1.f + expf(-bv));
        sg2[t] = 1.f / (1.f + expf(-lp[NE - 1]));
    }
    __syncthreads();
    const int h = t >> 3, e = t & 7;
    float val = (e == sbest[h]) ? sg1[h] : ((e == NE - 1) ? sg2[h] : 0.f);
    gdense[(size_t)token * 64 + t] = val;
}

// ---------------------------------------------------------------------------
// Preprocess: split fp32 -> bf16 hi/lo (no transpose). n divisible by 1024.
// ---------------------------------------------------------------------------
__global__ void split_kernel(const float* __restrict__ src,
                             u16* __restrict__ dh, u16* __restrict__ dl) {
    int i = (blockIdx.x * 256 + threadIdx.x) * 4;
    float4 v = *(const float4*)(src + i);
    u16 h[4], l[4];
    bfsplit(v.x, h[0], l[0]); bfsplit(v.y, h[1], l[1]);
    bfsplit(v.z, h[2], l[2]); bfsplit(v.w, h[3], l[3]);
    uint2 ph = { (unsigned)h[0] | ((unsigned)h[1] << 16),
                 (unsigned)h[2] | ((unsigned)h[3] << 16) };
    uint2 pl = { (unsigned)l[0] | ((unsigned)l[1] << 16),
                 (unsigned)l[2] | ((unsigned)l[3] << 16) };
    *(uint2*)&dh[i] = ph;
    *(uint2*)&dl[i] = pl;
}

// ---------------------------------------------------------------------------
// Preprocess: per-matrix transpose + split. src[mat][R][C] -> dst[mat][C][R].
// ---------------------------------------------------------------------------
__global__ void tsplit_kernel(const float* __restrict__ src,
                              u16* __restrict__ dh, u16* __restrict__ dl,
                              int R, int C) {
    __shared__ float tile[32][33];
    const int mat = blockIdx.x;
    const int r0 = blockIdx.y * 32, c0 = blockIdx.z * 32;
    const size_t base = (size_t)mat * R * C;
    const int tr = threadIdx.x >> 5, tc = threadIdx.x & 31;
#pragma unroll
    for (int p = 0; p < 4; ++p)
        tile[tr + p * 8][tc] = src[base + (size_t)(r0 + tr + p * 8) * C + c0 + tc];
    __syncthreads();
#pragma unroll
    for (int p = 0; p < 4; ++p) {
        int cc = tr + p * 8, rr = tc;
        float x = tile[rr][cc];
        u16 hh, ll; bfsplit(x, hh, ll);
        size_t o = base + (size_t)(c0 + cc) * R + r0 + rr;
        dh[o] = hh; dl[o] = ll;
    }
}

// ---------------------------------------------------------------------------
// Value CVMM, split-bf16 MFMA, dense over experts.
// global_load_lds staging, XOR-swizzled unpadded [128][64] tiles.
// ---------------------------------------------------------------------------
__global__ __launch_bounds__(256, 2) void v_mfma_kernel(
        const u16* __restrict__ Ah_g, const u16* __restrict__ Al_g,
        const u16* __restrict__ Bh_g, const u16* __restrict__ Bl_g,
        const float* __restrict__ gdense,
        float* __restrict__ wv) {
    const int i0 = blockIdx.x * 128;
    const int h  = blockIdx.y;
    __shared__ u16 Ah[128 * 64], Al[128 * 64], Bh[128 * 64], Bl[128 * 64];
    __shared__ float gl[128 * 8];
    const int t = threadIdx.x;
    const int lane = t & 63, wave = t >> 6;
    const int wm = wave >> 1, wn = wave & 1;
    const int ln = lane & 15, qd = lane >> 4;
    const f4v z4 = {0.f, 0.f, 0.f, 0.f};

#pragma unroll
    for (int p = 0; p < 4; ++p) {
        int idx = p * 256 + t;
        gl[idx] = gdense[(size_t)(i0 + (idx >> 3)) * 64 + h * 8 + (idx & 7)];
    }

    f4v C[4][4];
#pragma unroll
    for (int fm = 0; fm < 4; ++fm)
#pragma unroll
        for (int fn = 0; fn < 4; ++fn) C[fm][fn] = z4;

    for (int e = 0; e < 8; ++e) {
        f4v T[4][4];
#pragma unroll
        for (int fm = 0; fm < 4; ++fm)
#pragma unroll
            for (int fn = 0; fn < 4; ++fn) T[fm][fn] = z4;
        const size_t bbase = (size_t)(h * 8 + e) * DH * 1024;
        for (int kb = 0; kb < 16; ++kb) {
            __syncthreads();
            const int kbase = kb * 64;
#pragma unroll
            for (int p = 0; p < 4; ++p) {
                int chunk = p * 256 + t;
                int row = chunk >> 3;
                int cs  = ((chunk & 7) ^ (row & 7)) * 8;
                int ld  = (p * 256 + (t & 192)) * 8;
                size_t ga = (size_t)(i0 + row) * 1024 + kbase + cs;
                gll16(&Ah_g[ga], &Ah[ld]);
                gll16(&Al_g[ga], &Al[ld]);
                size_t gb = bbase + (size_t)row * 1024 + kbase + cs;
                gll16(&Bh_g[gb], &Bh[ld]);
                gll16(&Bl_g[gb], &Bl[ld]);
            }
            __syncthreads();
#pragma unroll
            for (int ks = 0; ks < 2; ++ks) {
                s8v ah[4], alv[4], bh[4], blv[4];
#pragma unroll
                for (int fm = 0; fm < 4; ++fm) {
                    int o = swzoff(wm * 64 + fm * 16 + ln, ks * 4 + qd);
                    ah[fm]  = *(const s8v*)&Ah[o];
                    alv[fm] = *(const s8v*)&Al[o];
                }
#pragma unroll
                for (int fn = 0; fn < 4; ++fn) {
                    int o = swzoff(wn * 64 + fn * 16 + ln, ks * 4 + qd);
                    bh[fn]  = *(const s8v*)&Bh[o];
                    blv[fn] = *(const s8v*)&Bl[o];
                }
#pragma unroll
                for (int fm = 0; fm < 4; ++fm)
#pragma unroll
                    for (int fn = 0; fn < 4; ++fn) {
                        T[fm][fn] = MFMA16(ah[fm],  bh[fn],  T[fm][fn]);
                        T[fm][fn] = MFMA16(ah[fm],  blv[fn], T[fm][fn]);
                        T[fm][fn] = MFMA16(alv[fm], bh[fn],  T[fm][fn]);
                    }
            }
        }
#pragma unroll
        for (int fm = 0; fm < 4; ++fm)
#pragma unroll
            for (int r = 0; r < 4; ++r) {
                float g = gl[(wm * 64 + fm * 16 + qd * 4 + r) * 8 + e];
#pragma unroll
                for (int fn = 0; fn < 4; ++fn)
                    C[fm][fn][r] += g * T[fm][fn][r];
            }
    }
#pragma unroll
    for (int fm = 0; fm < 4; ++fm)
#pragma unroll
        for (int fn = 0; fn < 4; ++fn)
#pragma unroll
            for (int r = 0; r < 4; ++r) {
                int token = i0 + wm * 64 + fm * 16 + qd * 4 + r;
                int f = wn * 64 + fn * 16 + ln;
                int b = token >> 11, s = token & 2047;
                wv[(((size_t)(b * NH + h) * SS + s) << 7) + f] = C[fm][fn][r];
            }
}

// ---------------------------------------------------------------------------
// Output CVMM, split-bf16 MFMA, dense over (h,e).
// global_load_lds staging, XOR-swizzled unpadded [128][64] tiles.
// ---------------------------------------------------------------------------
__global__ __launch_bounds__(256, 2) void out_mfma_kernel(
        const u16* __restrict__ Ah_g, const u16* __restrict__ Al_g,
        const u16* __restrict__ Bh_g, const u16* __restrict__ Bl_g,
        const float* __restrict__ gdense,
        float* __restrict__ out) {
    const int n0 = blockIdx.x * 128;
    const int i0 = blockIdx.y * 128;
    __shared__ u16 Ah[128 * 64], Al[128 * 64], Bh[128 * 64], Bl[128 * 64];
    __shared__ float gl[128 * 8];
    const int t = threadIdx.x;
    const int lane = t & 63, wave = t >> 6;
    const int wm = wave >> 1, wn = wave & 1;
    const int ln = lane & 15, qd = lane >> 4;
    const f4v z4 = {0.f, 0.f, 0.f, 0.f};

    f4v C[4][4];
#pragma unroll
    for (int fm = 0; fm < 4; ++fm)
#pragma unroll
        for (int fn = 0; fn < 4; ++fn) C[fm][fn] = z4;

    for (int h = 0; h < 8; ++h) {
        __syncthreads();
#pragma unroll
        for (int p = 0; p < 4; ++p) {
            int idx = p * 256 + t;
            gl[idx] = gdense[(size_t)(i0 + (idx >> 3)) * 64 + h * 8 + (idx & 7)];
        }
        for (int e = 0; e < 8; ++e) {
            f4v T[4][4];
#pragma unroll
            for (int fm = 0; fm < 4; ++fm)
#pragma unroll
                for (int fn = 0; fn < 4; ++fn) T[fm][fn] = z4;
            const size_t bbase = ((size_t)(h * 8 + e) * 1024 + n0) * DH;
#pragma unroll
            for (int kb = 0; kb < 2; ++kb) {
                __syncthreads();
                const int ka = h * 128 + kb * 64;
                const int kbb = kb * 64;
#pragma unroll
                for (int p = 0; p < 4; ++p) {
                    int chunk = p * 256 + t;
                    int row = chunk >> 3;
                    int cs  = ((chunk & 7) ^ (row & 7)) * 8;
                    int ld  = (p * 256 + (t & 192)) * 8;
                    size_t ga = (size_t)(i0 + row) * 1024 + ka + cs;
                    gll16(&Ah_g[ga], &Ah[ld]);
                    gll16(&Al_g[ga], &Al[ld]);
                    size_t gb = bbase + (size_t)row * DH + kbb + cs;
                    gll16(&Bh_g[gb], &Bh[ld]);
                    gll16(&Bl_g[gb], &Bl[ld]);
                }
                __syncthreads();
#pragma unroll
                for (int ks = 0; ks < 2; ++ks) {
                    s8v ah[4], alv[4], bh[4], blv[4];
#pragma unroll
                    for (int fm = 0; fm < 4; ++fm) {
                        int o = swzoff(wm * 64 + fm * 16 + ln, ks * 4 + qd);
                        ah[fm]  = *(const s8v*)&Ah[o];
                        alv[fm] = *(const s8v*)&Al[o];
                    }
#pragma unroll
                    for (int fn = 0; fn < 4; ++fn) {
                        int o = swzoff(wn * 64 + fn * 16 + ln, ks * 4 + qd);
                        bh[fn]  = *(const s8v*)&Bh[o];
                        blv[fn] = *(const s8v*)&Bl[o];
                    }
#pragma unroll
                    for (int fm = 0; fm < 4; ++fm)
#pragma unroll
                        for (int fn = 0; fn < 4; ++fn) {
                            T[fm][fn] = MFMA16(ah[fm],  bh[fn],  T[fm][fn]);
                            T[fm][fn] = MFMA16(ah[fm],  blv[fn], T[fm][fn]);
                            T[fm][fn] = MFMA16(alv[fm], bh[fn],  T[fm][fn]);
                        }
                }
            }
#pragma unroll
            for (int fm = 0; fm < 4; ++fm)
#pragma unroll
                for (int r = 0; r < 4; ++r) {
                    float g = gl[(wm * 64 + fm * 16 + qd * 4 + r) * 8 + e];
#pragma unroll
                    for (int fn = 0; fn < 4; ++fn)
                        C[fm][fn][r] += g * T[fm][fn][r];
                }
        }
    }
#pragma unroll
    for (int fm = 0; fm < 4; ++fm)
#pragma unroll
        for (int fn = 0; fn < 4; ++fn)
#pragma unroll
            for (int r = 0; r < 4; ++r) {
                int token = i0 + wm * 64 + fm * 16 + qd * 4 + r;
                int d = n0 + wn * 64 + fn * 16 + ln;
                out[(size_t)token * DM + d] = C[fm][fn][r];
            }
}

// ---------------------------------------------------------------------------
// MFMA flash attention. Block = (b,h) x 128 queries; 4 waves x 32 q-rows.
// KVBLK = 32. T14 async-stage: next K/V tile loaded into regs during compute,
// written to LDS after the post-compute barrier. LDS 48128 B.
// ---------------------------------------------------------------------------
__global__ __launch_bounds__(256, 2) void attn_mfma_kernel(
        const u16* __restrict__ qh, const u16* __restrict__ ql,
        const u16* __restrict__ kh, const u16* __restrict__ kl,
        const u16* __restrict__ vth, const u16* __restrict__ vtl,
        u16* __restrict__ res_hi, u16* __restrict__ res_lo) {
    const int bid = blockIdx.x;          // bh*16 + qtile
    const int bh = bid >> 4;
    const int q0 = (bid & 15) * 128;

    __shared__ u16 Ksh[32 * 136];        // 8704 B
    __shared__ u16 Ksl[32 * 136];
    __shared__ u16 Vsh[128 * 40];        // 10240 B
    __shared__ u16 Vsl[128 * 40];
    __shared__ u16 Ps[4][32 * 40];       // 10240 B  -> total 48128 B

    const int t = threadIdx.x;
    const int lane = t & 63, w = t >> 6;
    const int ln = lane & 15, qd = lane >> 4;

    // Q A-fragments in registers: 2 row-blocks of 16 (m = ln within block)
    s8v Qh[2][4], Qlv[2][4];
#pragma unroll
    for (int fm = 0; fm < 2; ++fm) {
        const size_t qoff = ((size_t)bh * SS + q0 + w * 32 + fm * 16 + ln) * DH;
        const u16* qhp = qh + qoff;
        const u16* qlp = ql + qoff;
#pragma unroll
        for (int ks = 0; ks < 4; ++ks) {
            Qh[fm][ks]  = *(const s8v*)(qhp + ks * 32 + qd * 8);
            Qlv[fm][ks] = *(const s8v*)(qlp + ks * 32 + qd * 8);
        }
    }

    f4v Of[2][8];
    const f4v z4 = {0.f, 0.f, 0.f, 0.f};
#pragma unroll
    for (int fm = 0; fm < 2; ++fm)
#pragma unroll
        for (int fn = 0; fn < 8; ++fn) Of[fm][fn] = z4;
    float mrow[2][4], lrow[2][4];
#pragma unroll
    for (int fm = 0; fm < 2; ++fm)
#pragma unroll
        for (int r = 0; r < 4; ++r) { mrow[fm][r] = -INFINITY; lrow[fm][r] = 0.f; }

    const u16* kbh = kh + (size_t)bh * SS * DH;
    const u16* kbl = kl + (size_t)bh * SS * DH;
    const u16* vbh = vth + (size_t)bh * DH * SS;   // [f][s]
    const u16* vbl = vtl + (size_t)bh * DH * SS;

    // staging registers (next-tile prefetch); chunk = p*256 + t, 512 chunks
    uint4 rKh[2], rKl[2], rVh[2], rVl[2];

#define LOADREGS(KT)                                                         \
    {                                                                        \
        _Pragma("unroll")                                                    \
        for (int p = 0; p < 2; ++p) {                                        \
            int chunk = p * 256 + t;                                         \
            int krow = chunk >> 4, kc = chunk & 15;                          \
            size_t g = (size_t)((KT) * 32 + krow) * DH + kc * 8;             \
            rKh[p] = *(const uint4*)&kbh[g];                                 \
            rKl[p] = *(const uint4*)&kbl[g];                                 \
            int vrow = chunk >> 2, vc = chunk & 3;                           \
            size_t gvo = (size_t)vrow * SS + (KT) * 32 + vc * 8;             \
            rVh[p] = *(const uint4*)&vbh[gvo];                               \
            rVl[p] = *(const uint4*)&vbl[gvo];                               \
        }                                                                    \
    }

#define STORELDS()                                                           \
    {                                                                        \
        _Pragma("unroll")                                                    \
        for (int p = 0; p < 2; ++p) {                                        \
            int chunk = p * 256 + t;                                         \
            int krow = chunk >> 4, kc = chunk & 15;                          \
            *(uint4*)&Ksh[krow * 136 + kc * 8] = rKh[p];                     \
            *(uint4*)&Ksl[krow * 136 + kc * 8] = rKl[p];                     \
            int vrow = chunk >> 2, vc = chunk & 3;                           \
            *(uint4*)&Vsh[vrow * 40 + vc * 8] = rVh[p];                      \
            *(uint4*)&Vsl[vrow * 40 + vc * 8] = rVl[p];                      \
        }                                                                    \
    }

    // prologue: stage tile 0
    LOADREGS(0);
    STORELDS();
    __syncthreads();

    for (int kt = 0; kt < SS / 32; ++kt) {
        const bool more = (kt + 1 < SS / 32);
        if (more) LOADREGS(kt + 1);       // in flight during compute

        // ---- QK^T: S[fm][nt], K frags shared across the 2 row-blocks ----
        f4v S[2][2];
#pragma unroll
        for (int fm = 0; fm < 2; ++fm)
#pragma unroll
            for (int nt = 0; nt < 2; ++nt) S[fm][nt] = z4;
#pragma unroll
        for (int ks = 0; ks < 4; ++ks) {
#pragma unroll
            for (int nt = 0; nt < 2; ++nt) {
                int o = (nt * 16 + ln) * 136 + ks * 32 + qd * 8;
                s8v kbhf = *(const s8v*)&Ksh[o];
                s8v kblf = *(const s8v*)&Ksl[o];
#pragma unroll
                for (int fm = 0; fm < 2; ++fm) {
                    S[fm][nt] = MFMA16(Qh[fm][ks],  kbhf, S[fm][nt]);
                    S[fm][nt] = MFMA16(Qh[fm][ks],  kblf, S[fm][nt]);
                    S[fm][nt] = MFMA16(Qlv[fm][ks], kbhf, S[fm][nt]);
                }
            }
        }

        // ---- online softmax (two independent row-blocks -> ILP) ----
        float pv[2][2][4];
#pragma unroll
        for (int fm = 0; fm < 2; ++fm) {
            float mt[4];
#pragma unroll
            for (int r = 0; r < 4; ++r) mt[r] = fmaxf(S[fm][0][r], S[fm][1][r]);
#pragma unroll
            for (int mask = 1; mask < 16; mask <<= 1)
#pragma unroll
                for (int r = 0; r < 4; ++r)
                    mt[r] = fmaxf(mt[r], __shfl_xor(mt[r], mask, 64));
            float alpha[4];
#pragma unroll
            for (int r = 0; r < 4; ++r) {
                float mn = fmaxf(mrow[fm][r], mt[r]);
                alpha[r] = __expf(mrow[fm][r] - mn);
                mrow[fm][r] = mn;
            }
            float lt[4] = {0.f, 0.f, 0.f, 0.f};
#pragma unroll
            for (int nt = 0; nt < 2; ++nt)
#pragma unroll
                for (int r = 0; r < 4; ++r) {
                    float p = __expf(S[fm][nt][r] - mrow[fm][r]);
                    pv[fm][nt][r] = p;
                    lt[r] += p;
                }
#pragma unroll
            for (int mask = 1; mask < 16; mask <<= 1)
#pragma unroll
                for (int r = 0; r < 4; ++r)
                    lt[r] += __shfl_xor(lt[r], mask, 64);
#pragma unroll
            for (int r = 0; r < 4; ++r)
                lrow[fm][r] = alpha[r] * lrow[fm][r] + lt[r];
#pragma unroll
            for (int fn = 0; fn < 8; ++fn)
#pragma unroll
                for (int r = 0; r < 4; ++r) Of[fm][fn][r] *= alpha[r];
        }

        // ---- P (C-layout) -> per-wave LDS (A-layout source) ----
#pragma unroll
        for (int fm = 0; fm < 2; ++fm)
#pragma unroll
            for (int nt = 0; nt < 2; ++nt)
#pragma unroll
                for (int r = 0; r < 4; ++r)
                    Ps[w][(fm * 16 + qd * 4 + r) * 40 + nt * 16 + ln] =
                        bf16rne(pv[fm][nt][r]);
        // same-wave write->read: compiler inserts lgkmcnt wait; no barrier.

        // ---- PV: Of += P * V, V frags shared across the 2 row-blocks ----
        s8v pf[2];
#pragma unroll
        for (int fm = 0; fm < 2; ++fm)
            pf[fm] = *(const s8v*)&Ps[w][(fm * 16 + ln) * 40 + qd * 8];
#pragma unroll
        for (int fn = 0; fn < 8; ++fn) {
            int o = (fn * 16 + ln) * 40 + qd * 8;
            s8v vbhf = *(const s8v*)&Vsh[o];
            s8v vblf = *(const s8v*)&Vsl[o];
#pragma unroll
            for (int fm = 0; fm < 2; ++fm) {
                Of[fm][fn] = MFMA16(pf[fm], vbhf, Of[fm][fn]);
                Of[fm][fn] = MFMA16(pf[fm], vblf, Of[fm][fn]);
            }
        }

        __syncthreads();                  // all waves done reading K/V LDS
        if (more) {
            STORELDS();                   // waits vmcnt for rK/rV arrival
            __syncthreads();              // next tile staged
        }
    }

    // ---- epilogue: normalize, split to bf16 hi/lo, store res[token][1024] --
    const int b = bh >> 3, h = bh & 7;
#pragma unroll
    for (int fm = 0; fm < 2; ++fm)
#pragma unroll
        for (int r = 0; r < 4; ++r) {
            float linv = 1.f / lrow[fm][r];
            int qi = q0 + w * 32 + fm * 16 + qd * 4 + r;
            size_t off = (size_t)(b * SS + qi) * DM + h * DH + ln;
#pragma unroll
            for (int fn = 0; fn < 8; ++fn) {
                u16 hh, ll;
                bfsplit(Of[fm][fn][r] * linv, hh, ll);
                res_hi[off + fn * 16] = hh;
                res_lo[off + fn * 16] = ll;
            }
        }
#undef LOADREGS
#undef STORELDS
}

// ---------------------------------------------------------------------------
extern "C" void kernel_launch(void* const* d_in, const int* in_sizes, int n_in,
                              void* d_out, int out_size, void* d_ws, size_t ws_size,
                              hipStream_t stream) {
    (void)in_sizes; (void)n_in; (void)out_size; (void)ws_size;
    const float* q_src = (const float*)d_in[0];
    const float* k_src = (const float*)d_in[1];
    const float* v_src = (const float*)d_in[2];
    const float* Wq    = (const float*)d_in[3];
    const float* Wk    = (const float*)d_in[4];
    const float* V     = (const float*)d_in[5];
    const float* O     = (const float*)d_in[6];
    const float* sel_v = (const float*)d_in[7];
    const float* sel_o = (const float*)d_in[8];
    float* out = (float*)d_out;

    // workspace layout
    const size_t NELT = (size_t)NTOK * DM;   // 8388608
    u16* wq_h = (u16*)d_ws;                  // q hi/lo [bh][s][f]
    u16* wq_l = wq_h + NELT;
    u16* wk_h = wq_l + NELT;                 // k hi/lo
    u16* wk_l = wk_h + NELT;
    float* wv = (float*)(wk_l + NELT);       // v fp32 [bh][s][f]
    u16* res_hi = (u16*)(wv + NELT);         // attention result hi/lo
    u16* res_lo = res_hi + NELT;
    u16* vs_hi  = res_lo + NELT;             // vsrc split (later: Ot)
    u16* vs_lo  = vs_hi + NELT;
    u16* Vt_hi  = vs_lo + NELT;              // V transposed (later: vT)
    u16* Vt_lo  = Vt_hi + NELT;
    float* gv = (float*)(Vt_lo + NELT);      // dense gates [8192][64]
    float* go = gv + (size_t)NTOK * 64;
    u16* Wq_h = (u16*)(go + (size_t)NTOK * 64);  // W splits (1024x1024 each)
    u16* Wq_l = Wq_h + (size_t)DM * DM;
    u16* Wk_h = Wq_l + (size_t)DM * DM;
    u16* Wk_l = Wk_h + (size_t)DM * DM;
    // aliases (regions dead during the phase they are used)
    u16* qsrc_h = res_hi;                    // dead until attn writes res
    u16* qsrc_l = res_lo;
    u16* ksrc_h = (u16*)wv;                  // dead until v_mfma writes wv
    u16* ksrc_l = ksrc_h + NELT;
    u16* Ot_hi = vs_hi;                      // alias (dead after v_mfma)
    u16* Ot_lo = vs_lo;
    u16* vth   = Vt_hi;                      // alias (dead after v_mfma)
    u16* vtl   = Vt_lo;

    // preprocess: splits
    split_kernel<<<NELT / 1024, 256, 0, stream>>>(v_src, vs_hi, vs_lo);
    split_kernel<<<NELT / 1024, 256, 0, stream>>>(q_src, qsrc_h, qsrc_l);
    split_kernel<<<NELT / 1024, 256, 0, stream>>>(k_src, ksrc_h, ksrc_l);
    split_kernel<<<(DM * DM) / 1024, 256, 0, stream>>>(Wq, Wq_h, Wq_l);
    split_kernel<<<(DM * DM) / 1024, 256, 0, stream>>>(Wk, Wk_h, Wk_l);
    tsplit_kernel<<<dim3(64, 32, 4), 256, 0, stream>>>(V, Vt_hi, Vt_lo, 1024, 128);

    // gates
    gate_kernel<<<NTOK, 64, 0, stream>>>(k_src, sel_v, gv);
    gate_kernel<<<NTOK, 64, 0, stream>>>(q_src, sel_o, go);

    // q/k projections via MFMA (emit bf16 hi/lo)
    proj_mfma_kernel<<<dim3(64, 8), 256, 0, stream>>>(
        qsrc_h, qsrc_l, Wq_h, Wq_l, wq_h, wq_l, SCALE_SQRT);
    proj_mfma_kernel<<<dim3(64, 8), 256, 0, stream>>>(
        ksrc_h, ksrc_l, Wk_h, Wk_l, wk_h, wk_l, SCALE_SQRT);

    // value CVMM (MFMA) -> wv fp32 (overwrites ksrc splits: proj done)
    v_mfma_kernel<<<dim3(64, 8), 256, 0, stream>>>(vs_hi, vs_lo, Vt_hi, Vt_lo, gv, wv);

    // transpose+split O into dead vsrc buffers
    tsplit_kernel<<<dim3(64, 4, 32), 256, 0, stream>>>(O, Ot_hi, Ot_lo, 128, 1024);

    // transpose+split v into dead Vt buffers: vT[bh][f][s]
    tsplit_kernel<<<dim3(32, 64, 4), 256, 0, stream>>>(wv, vth, vtl, 2048, 128);

    // attention (MFMA flash; 128-query tiles; writes res = overwrites qsrc)
    attn_mfma_kernel<<<BB * NH * (SS / 128), 256, 0, stream>>>(
        wq_h, wq_l, wk_h, wk_l, vth, vtl, res_hi, res_lo);

    // output CVMM (MFMA)
    out_mfma_kernel<<<dim3(8, 64), 256, 0, stream>>>(res_hi, res_lo, Ot_hi, Ot_lo, go, out);
}

// Round 5
// 1701.628 us; speedup vs baseline: 1.8956x; 1.1368x over previous
//
#include <hip/hip_runtime.h>
#include <hip/hip_bf16.h>
#include <math.h>

// Problem constants
#define BB 4
#define SS 2048
#define DM 1024
#define NH 8
#define DH 128
#define NE 8
#define NTOK (BB*SS)          // 8192
#define SCALE_SQRT 0.29730177875068026f

typedef unsigned short u16;
typedef short s8v __attribute__((ext_vector_type(8)));
typedef float f4v __attribute__((ext_vector_type(4)));
#define MFMA16(a,b,c) __builtin_amdgcn_mfma_f32_16x16x32_bf16((a),(b),(c),0,0,0)

// Round-to-nearest-even fp32 -> bf16 split: x ~= hi + lo (each bf16).
__device__ inline void bfsplit(float x, u16& h, u16& l) {
    unsigned u = __float_as_uint(x);
    unsigned hr = (u + 0x7FFFu + ((u >> 16) & 1u)) >> 16;
    h = (u16)hr;
    float hf = __uint_as_float(hr << 16);
    unsigned u2 = __float_as_uint(x - hf);
    l = (u16)((u2 + 0x7FFFu + ((u2 >> 16) & 1u)) >> 16);
}
__device__ inline u16 bf16rne(float x) {
    unsigned u = __float_as_uint(x);
    return (u16)((u + 0x7FFFu + ((u >> 16) & 1u)) >> 16);
}

// Async global->LDS 16B copy. LDS dest = wave-uniform base + lane*16.
__device__ inline void gll16(const u16* g, u16* l) {
    __builtin_amdgcn_global_load_lds(
        (const __attribute__((address_space(1))) unsigned int*)g,
        (__attribute__((address_space(3))) unsigned int*)l,
        16, 0, 0);
}

// Swizzled tile offset (u16 units) for [128][64]-u16 tiles staged linearly:
// row's 16B chunk c stored at chunk index c ^ (row&7). Same XOR on read.
__device__ inline int swzoff(int row, int kchunk) {
    return row * 64 + ((kchunk ^ (row & 7)) << 3);
}

// ---------------------------------------------------------------------------
// Projection GEMM via split-bf16 MFMA (3-term): out = scale * (x @ W^T).
// global_load_lds staging, XOR-swizzled unpadded [128][64] tiles.
// ---------------------------------------------------------------------------
__global__ __launch_bounds__(256, 2) void proj_mfma_kernel(
        const u16* __restrict__ Ah_g, const u16* __restrict__ Al_g,
        const u16* __restrict__ Bh_g, const u16* __restrict__ Bl_g,
        u16* __restrict__ out_h, u16* __restrict__ out_l, float scale) {
    const int i0 = blockIdx.x * 128;
    const int n0 = blockIdx.y * 128;
    __shared__ u16 Ah[128 * 64], Al[128 * 64], Bh[128 * 64], Bl[128 * 64];
    const int t = threadIdx.x;
    const int lane = t & 63, wave = t >> 6;
    const int wm = wave >> 1, wn = wave & 1;
    const int ln = lane & 15, qd = lane >> 4;
    const f4v z4 = {0.f, 0.f, 0.f, 0.f};

    f4v C[4][4];
#pragma unroll
    for (int fm = 0; fm < 4; ++fm)
#pragma unroll
        for (int fn = 0; fn < 4; ++fn) C[fm][fn] = z4;

    for (int kb = 0; kb < 16; ++kb) {
        __syncthreads();
        const int kbase = kb * 64;
#pragma unroll
        for (int p = 0; p < 4; ++p) {
            int chunk = p * 256 + t;
            int row = chunk >> 3;
            int cs  = ((chunk & 7) ^ (row & 7)) * 8;     // swizzled src col (u16)
            int ld  = (p * 256 + (t & 192)) * 8;         // wave-uniform LDS base
            size_t ga = (size_t)(i0 + row) * 1024 + kbase + cs;
            gll16(&Ah_g[ga], &Ah[ld]);
            gll16(&Al_g[ga], &Al[ld]);
            size_t gb = (size_t)(n0 + row) * 1024 + kbase + cs;
            gll16(&Bh_g[gb], &Bh[ld]);
            gll16(&Bl_g[gb], &Bl[ld]);
        }
        __syncthreads();
#pragma unroll
        for (int ks = 0; ks < 2; ++ks) {
            s8v ah[4], alv[4], bh[4], blv[4];
#pragma unroll
            for (int fm = 0; fm < 4; ++fm) {
                int o = swzoff(wm * 64 + fm * 16 + ln, ks * 4 + qd);
                ah[fm]  = *(const s8v*)&Ah[o];
                alv[fm] = *(const s8v*)&Al[o];
            }
#pragma unroll
            for (int fn = 0; fn < 4; ++fn) {
                int o = swzoff(wn * 64 + fn * 16 + ln, ks * 4 + qd);
                bh[fn]  = *(const s8v*)&Bh[o];
                blv[fn] = *(const s8v*)&Bl[o];
            }
#pragma unroll
            for (int fm = 0; fm < 4; ++fm)
#pragma unroll
                for (int fn = 0; fn < 4; ++fn) {
                    C[fm][fn] = MFMA16(ah[fm],  bh[fn],  C[fm][fn]);
                    C[fm][fn] = MFMA16(ah[fm],  blv[fn], C[fm][fn]);
                    C[fm][fn] = MFMA16(alv[fm], bh[fn],  C[fm][fn]);
                }
        }
    }
    const int h = n0 >> 7;
#pragma unroll
    for (int fm = 0; fm < 4; ++fm)
#pragma unroll
        for (int fn = 0; fn < 4; ++fn)
#pragma unroll
            for (int r = 0; r < 4; ++r) {
                int token = i0 + wm * 64 + fm * 16 + qd * 4 + r;
                int f = wn * 64 + fn * 16 + ln;
                int b = token >> 11, s = token & 2047;
                u16 hh, ll;
                bfsplit(C[fm][fn][r] * scale, hh, ll);
                size_t o = ((((size_t)(b * NH + h)) * SS + s) << 7) + f;
                out_h[o] = hh; out_l[o] = ll;
            }
}

// ---------------------------------------------------------------------------
// Gate: dense sparse-valued gate g[token][h][e]
// ---------------------------------------------------------------------------
__global__ void gate_kernel(const float* __restrict__ x,
                            const float* __restrict__ sel,
                            float* __restrict__ gdense) {
    __shared__ float xs[DM];
    __shared__ float logits[64];
    __shared__ int   sbest[NH];
    __shared__ float sg1[NH], sg2[NH];
    const int token = blockIdx.x;
    const int t = threadIdx.x;  // 0..63
    const float* xp = x + (size_t)token * DM;
    for (int i = t; i < DM; i += 64) xs[i] = xp[i];
    __syncthreads();
    const float* sp = sel + (size_t)t * DM;
    float acc = 0.f;
    for (int d = 0; d < DM; ++d) acc += xs[d] * sp[d];
    logits[t] = acc;
    __syncthreads();
    if (t < NH) {
        const float* lp = logits + t * NE;
        int best = 0; float bv = lp[0];
#pragma unroll
        for (int e = 1; e < NE - 1; ++e)
            if (lp[e] > bv) { bv = lp[e]; best = e; }   // strict > == lowest idx tie
        sbest[t] = best;
        sg1[t] = 1.f / (1.f + expf(-bv));
        sg2[t] = 1.f / (1.f + expf(-lp[NE - 1]));
    }
    __syncthreads();
    const int h = t >> 3, e = t & 7;
    float val = (e == sbest[h]) ? sg1[h] : ((e == NE - 1) ? sg2[h] : 0.f);
    gdense[(size_t)token * 64 + t] = val;
}

// ---------------------------------------------------------------------------
// Preprocess: split fp32 -> bf16 hi/lo (no transpose). n divisible by 1024.
// ---------------------------------------------------------------------------
__global__ void split_kernel(const float* __restrict__ src,
                             u16* __restrict__ dh, u16* __restrict__ dl) {
    int i = (blockIdx.x * 256 + threadIdx.x) * 4;
    float4 v = *(const float4*)(src + i);
    u16 h[4], l[4];
    bfsplit(v.x, h[0], l[0]); bfsplit(v.y, h[1], l[1]);
    bfsplit(v.z, h[2], l[2]); bfsplit(v.w, h[3], l[3]);
    uint2 ph = { (unsigned)h[0] | ((unsigned)h[1] << 16),
                 (unsigned)h[2] | ((unsigned)h[3] << 16) };
    uint2 pl = { (unsigned)l[0] | ((unsigned)l[1] << 16),
                 (unsigned)l[2] | ((unsigned)l[3] << 16) };
    *(uint2*)&dh[i] = ph;
    *(uint2*)&dl[i] = pl;
}

// ---------------------------------------------------------------------------
// Preprocess: per-matrix transpose + split. src[mat][R][C] -> dst[mat][C][R].
// ---------------------------------------------------------------------------
__global__ void tsplit_kernel(const float* __restrict__ src,
                              u16* __restrict__ dh, u16* __restrict__ dl,
                              int R, int C) {
    __shared__ float tile[32][33];
    const int mat = blockIdx.x;
    const int r0 = blockIdx.y * 32, c0 = blockIdx.z * 32;
    const size_t base = (size_t)mat * R * C;
    const int tr = threadIdx.x >> 5, tc = threadIdx.x & 31;
#pragma unroll
    for (int p = 0; p < 4; ++p)
        tile[tr + p * 8][tc] = src[base + (size_t)(r0 + tr + p * 8) * C + c0 + tc];
    __syncthreads();
#pragma unroll
    for (int p = 0; p < 4; ++p) {
        int cc = tr + p * 8, rr = tc;
        float x = tile[rr][cc];
        u16 hh, ll; bfsplit(x, hh, ll);
        size_t o = base + (size_t)(c0 + cc) * R + r0 + rr;
        dh[o] = hh; dl[o] = ll;
    }
}

// ---------------------------------------------------------------------------
// Value CVMM, split-bf16 MFMA, dense over experts.
// global_load_lds staging, XOR-swizzled unpadded [128][64] tiles.
// ---------------------------------------------------------------------------
__global__ __launch_bounds__(256, 2) void v_mfma_kernel(
        const u16* __restrict__ Ah_g, const u16* __restrict__ Al_g,
        const u16* __restrict__ Bh_g, const u16* __restrict__ Bl_g,
        const float* __restrict__ gdense,
        float* __restrict__ wv) {
    const int i0 = blockIdx.x * 128;
    const int h  = blockIdx.y;
    __shared__ u16 Ah[128 * 64], Al[128 * 64], Bh[128 * 64], Bl[128 * 64];
    __shared__ float gl[128 * 8];
    const int t = threadIdx.x;
    const int lane = t & 63, wave = t >> 6;
    const int wm = wave >> 1, wn = wave & 1;
    const int ln = lane & 15, qd = lane >> 4;
    const f4v z4 = {0.f, 0.f, 0.f, 0.f};

#pragma unroll
    for (int p = 0; p < 4; ++p) {
        int idx = p * 256 + t;
        gl[idx] = gdense[(size_t)(i0 + (idx >> 3)) * 64 + h * 8 + (idx & 7)];
    }

    f4v C[4][4];
#pragma unroll
    for (int fm = 0; fm < 4; ++fm)
#pragma unroll
        for (int fn = 0; fn < 4; ++fn) C[fm][fn] = z4;

    for (int e = 0; e < 8; ++e) {
        f4v T[4][4];
#pragma unroll
        for (int fm = 0; fm < 4; ++fm)
#pragma unroll
            for (int fn = 0; fn < 4; ++fn) T[fm][fn] = z4;
        const size_t bbase = (size_t)(h * 8 + e) * DH * 1024;
        for (int kb = 0; kb < 16; ++kb) {
            __syncthreads();
            const int kbase = kb * 64;
#pragma unroll
            for (int p = 0; p < 4; ++p) {
                int chunk = p * 256 + t;
                int row = chunk >> 3;
                int cs  = ((chunk & 7) ^ (row & 7)) * 8;
                int ld  = (p * 256 + (t & 192)) * 8;
                size_t ga = (size_t)(i0 + row) * 1024 + kbase + cs;
                gll16(&Ah_g[ga], &Ah[ld]);
                gll16(&Al_g[ga], &Al[ld]);
                size_t gb = bbase + (size_t)row * 1024 + kbase + cs;
                gll16(&Bh_g[gb], &Bh[ld]);
                gll16(&Bl_g[gb], &Bl[ld]);
            }
            __syncthreads();
#pragma unroll
            for (int ks = 0; ks < 2; ++ks) {
                s8v ah[4], alv[4], bh[4], blv[4];
#pragma unroll
                for (int fm = 0; fm < 4; ++fm) {
                    int o = swzoff(wm * 64 + fm * 16 + ln, ks * 4 + qd);
                    ah[fm]  = *(const s8v*)&Ah[o];
                    alv[fm] = *(const s8v*)&Al[o];
                }
#pragma unroll
                for (int fn = 0; fn < 4; ++fn) {
                    int o = swzoff(wn * 64 + fn * 16 + ln, ks * 4 + qd);
                    bh[fn]  = *(const s8v*)&Bh[o];
                    blv[fn] = *(const s8v*)&Bl[o];
                }
#pragma unroll
                for (int fm = 0; fm < 4; ++fm)
#pragma unroll
                    for (int fn = 0; fn < 4; ++fn) {
                        T[fm][fn] = MFMA16(ah[fm],  bh[fn],  T[fm][fn]);
                        T[fm][fn] = MFMA16(ah[fm],  blv[fn], T[fm][fn]);
                        T[fm][fn] = MFMA16(alv[fm], bh[fn],  T[fm][fn]);
                    }
            }
        }
#pragma unroll
        for (int fm = 0; fm < 4; ++fm)
#pragma unroll
            for (int r = 0; r < 4; ++r) {
                float g = gl[(wm * 64 + fm * 16 + qd * 4 + r) * 8 + e];
#pragma unroll
                for (int fn = 0; fn < 4; ++fn)
                    C[fm][fn][r] += g * T[fm][fn][r];
            }
    }
#pragma unroll
    for (int fm = 0; fm < 4; ++fm)
#pragma unroll
        for (int fn = 0; fn < 4; ++fn)
#pragma unroll
            for (int r = 0; r < 4; ++r) {
                int token = i0 + wm * 64 + fm * 16 + qd * 4 + r;
                int f = wn * 64 + fn * 16 + ln;
                int b = token >> 11, s = token & 2047;
                wv[(((size_t)(b * NH + h) * SS + s) << 7) + f] = C[fm][fn][r];
            }
}

// ---------------------------------------------------------------------------
// Output CVMM, split-bf16 MFMA, dense over (h,e).
// global_load_lds staging, XOR-swizzled unpadded [128][64] tiles.
// ---------------------------------------------------------------------------
__global__ __launch_bounds__(256, 2) void out_mfma_kernel(
        const u16* __restrict__ Ah_g, const u16* __restrict__ Al_g,
        const u16* __restrict__ Bh_g, const u16* __restrict__ Bl_g,
        const float* __restrict__ gdense,
        float* __restrict__ out) {
    const int n0 = blockIdx.x * 128;
    const int i0 = blockIdx.y * 128;
    __shared__ u16 Ah[128 * 64], Al[128 * 64], Bh[128 * 64], Bl[128 * 64];
    __shared__ float gl[128 * 8];
    const int t = threadIdx.x;
    const int lane = t & 63, wave = t >> 6;
    const int wm = wave >> 1, wn = wave & 1;
    const int ln = lane & 15, qd = lane >> 4;
    const f4v z4 = {0.f, 0.f, 0.f, 0.f};

    f4v C[4][4];
#pragma unroll
    for (int fm = 0; fm < 4; ++fm)
#pragma unroll
        for (int fn = 0; fn < 4; ++fn) C[fm][fn] = z4;

    for (int h = 0; h < 8; ++h) {
        __syncthreads();
#pragma unroll
        for (int p = 0; p < 4; ++p) {
            int idx = p * 256 + t;
            gl[idx] = gdense[(size_t)(i0 + (idx >> 3)) * 64 + h * 8 + (idx & 7)];
        }
        for (int e = 0; e < 8; ++e) {
            f4v T[4][4];
#pragma unroll
            for (int fm = 0; fm < 4; ++fm)
#pragma unroll
                for (int fn = 0; fn < 4; ++fn) T[fm][fn] = z4;
            const size_t bbase = ((size_t)(h * 8 + e) * 1024 + n0) * DH;
#pragma unroll
            for (int kb = 0; kb < 2; ++kb) {
                __syncthreads();
                const int ka = h * 128 + kb * 64;
                const int kbb = kb * 64;
#pragma unroll
                for (int p = 0; p < 4; ++p) {
                    int chunk = p * 256 + t;
                    int row = chunk >> 3;
                    int cs  = ((chunk & 7) ^ (row & 7)) * 8;
                    int ld  = (p * 256 + (t & 192)) * 8;
                    size_t ga = (size_t)(i0 + row) * 1024 + ka + cs;
                    gll16(&Ah_g[ga], &Ah[ld]);
                    gll16(&Al_g[ga], &Al[ld]);
                    size_t gb = bbase + (size_t)row * DH + kbb + cs;
                    gll16(&Bh_g[gb], &Bh[ld]);
                    gll16(&Bl_g[gb], &Bl[ld]);
                }
                __syncthreads();
#pragma unroll
                for (int ks = 0; ks < 2; ++ks) {
                    s8v ah[4], alv[4], bh[4], blv[4];
#pragma unroll
                    for (int fm = 0; fm < 4; ++fm) {
                        int o = swzoff(wm * 64 + fm * 16 + ln, ks * 4 + qd);
                        ah[fm]  = *(const s8v*)&Ah[o];
                        alv[fm] = *(const s8v*)&Al[o];
                    }
#pragma unroll
                    for (int fn = 0; fn < 4; ++fn) {
                        int o = swzoff(wn * 64 + fn * 16 + ln, ks * 4 + qd);
                        bh[fn]  = *(const s8v*)&Bh[o];
                        blv[fn] = *(const s8v*)&Bl[o];
                    }
#pragma unroll
                    for (int fm = 0; fm < 4; ++fm)
#pragma unroll
                        for (int fn = 0; fn < 4; ++fn) {
                            T[fm][fn] = MFMA16(ah[fm],  bh[fn],  T[fm][fn]);
                            T[fm][fn] = MFMA16(ah[fm],  blv[fn], T[fm][fn]);
                            T[fm][fn] = MFMA16(alv[fm], bh[fn],  T[fm][fn]);
                        }
                }
            }
#pragma unroll
            for (int fm = 0; fm < 4; ++fm)
#pragma unroll
                for (int r = 0; r < 4; ++r) {
                    float g = gl[(wm * 64 + fm * 16 + qd * 4 + r) * 8 + e];
#pragma unroll
                    for (int fn = 0; fn < 4; ++fn)
                        C[fm][fn][r] += g * T[fm][fn][r];
                }
        }
    }
#pragma unroll
    for (int fm = 0; fm < 4; ++fm)
#pragma unroll
        for (int fn = 0; fn < 4; ++fn)
#pragma unroll
            for (int r = 0; r < 4; ++r) {
                int token = i0 + wm * 64 + fm * 16 + qd * 4 + r;
                int d = n0 + wn * 64 + fn * 16 + ln;
                out[(size_t)token * DM + d] = C[fm][fn][r];
            }
}

// ---------------------------------------------------------------------------
// MFMA flash attention. Block = (b,h) x 128 queries; 4 waves x 32 q-rows.
// KVBLK = 32. T14 async-stage with NAMED registers (rule #20: no arrays,
// no runtime indexing -> stays in VGPRs, no scratch). LDS 48128 B.
// ---------------------------------------------------------------------------
__global__ __launch_bounds__(256, 2) void attn_mfma_kernel(
        const u16* __restrict__ qh, const u16* __restrict__ ql,
        const u16* __restrict__ kh, const u16* __restrict__ kl,
        const u16* __restrict__ vth, const u16* __restrict__ vtl,
        u16* __restrict__ res_hi, u16* __restrict__ res_lo) {
    const int bid = blockIdx.x;          // bh*16 + qtile
    const int bh = bid >> 4;
    const int q0 = (bid & 15) * 128;

    __shared__ u16 Ksh[32 * 136];        // 8704 B
    __shared__ u16 Ksl[32 * 136];
    __shared__ u16 Vsh[128 * 40];        // 10240 B
    __shared__ u16 Vsl[128 * 40];
    __shared__ u16 Ps[4][32 * 40];       // 10240 B  -> total 48128 B

    const int t = threadIdx.x;
    const int lane = t & 63, w = t >> 6;
    const int ln = lane & 15, qd = lane >> 4;

    // Q A-fragments in registers: 2 row-blocks of 16 (m = ln within block)
    s8v Qh[2][4], Qlv[2][4];
#pragma unroll
    for (int fm = 0; fm < 2; ++fm) {
        const size_t qoff = ((size_t)bh * SS + q0 + w * 32 + fm * 16 + ln) * DH;
        const u16* qhp = qh + qoff;
        const u16* qlp = ql + qoff;
#pragma unroll
        for (int ks = 0; ks < 4; ++ks) {
            Qh[fm][ks]  = *(const s8v*)(qhp + ks * 32 + qd * 8);
            Qlv[fm][ks] = *(const s8v*)(qlp + ks * 32 + qd * 8);
        }
    }

    f4v Of[2][8];
    const f4v z4 = {0.f, 0.f, 0.f, 0.f};
#pragma unroll
    for (int fm = 0; fm < 2; ++fm)
#pragma unroll
        for (int fn = 0; fn < 8; ++fn) Of[fm][fn] = z4;
    float mrow[2][4], lrow[2][4];
#pragma unroll
    for (int fm = 0; fm < 2; ++fm)
#pragma unroll
        for (int r = 0; r < 4; ++r) { mrow[fm][r] = -INFINITY; lrow[fm][r] = 0.f; }

    const u16* kbh = kh + (size_t)bh * SS * DH;
    const u16* kbl = kl + (size_t)bh * SS * DH;
    const u16* vbh = vth + (size_t)bh * DH * SS;   // [f][s]
    const u16* vbl = vtl + (size_t)bh * DH * SS;

    // per-thread staging addresses (chunk = t and chunk = 256+t)
    const int krow0 = t >> 4,        kc0 = t & 15;
    const int krow1 = (256 + t) >> 4, kc1 = (256 + t) & 15;
    const int vrow0 = t >> 2,        vc0 = t & 3;
    const int vrow1 = (256 + t) >> 2, vc1 = (256 + t) & 3;
    const int kld0 = krow0 * 136 + kc0 * 8, kld1 = krow1 * 136 + kc1 * 8;
    const int vld0 = vrow0 * 40 + vc0 * 8,  vld1 = vrow1 * 40 + vc1 * 8;

    // staging registers — NAMED scalars, straight-line code (no arrays)
    uint4 rKh0, rKh1, rKl0, rKl1, rVh0, rVh1, rVl0, rVl1;

#define LOADREGS(KT)                                                         \
    {                                                                        \
        size_t g0 = (size_t)((KT) * 32 + krow0) * DH + kc0 * 8;              \
        size_t g1 = (size_t)((KT) * 32 + krow1) * DH + kc1 * 8;              \
        rKh0 = *(const uint4*)&kbh[g0];  rKl0 = *(const uint4*)&kbl[g0];     \
        rKh1 = *(const uint4*)&kbh[g1];  rKl1 = *(const uint4*)&kbl[g1];     \
        size_t v0 = (size_t)vrow0 * SS + (KT) * 32 + vc0 * 8;                \
        size_t v1 = (size_t)vrow1 * SS + (KT) * 32 + vc1 * 8;                \
        rVh0 = *(const uint4*)&vbh[v0];  rVl0 = *(const uint4*)&vbl[v0];     \
        rVh1 = *(const uint4*)&vbh[v1];  rVl1 = *(const uint4*)&vbl[v1];     \
    }

#define STORELDS()                                                           \
    {                                                                        \
        *(uint4*)&Ksh[kld0] = rKh0;  *(uint4*)&Ksl[kld0] = rKl0;             \
        *(uint4*)&Ksh[kld1] = rKh1;  *(uint4*)&Ksl[kld1] = rKl1;             \
        *(uint4*)&Vsh[vld0] = rVh0;  *(uint4*)&Vsl[vld0] = rVl0;             \
        *(uint4*)&Vsh[vld1] = rVh1;  *(uint4*)&Vsl[vld1] = rVl1;             \
    }

    // prologue: stage tile 0
    LOADREGS(0);
    STORELDS();
    __syncthreads();

    for (int kt = 0; kt < SS / 32; ++kt) {
        const bool more = (kt + 1 < SS / 32);
        if (more) LOADREGS(kt + 1);       // in flight during compute

        // ---- QK^T: S[fm][nt], K frags shared across the 2 row-blocks ----
        f4v S[2][2];
#pragma unroll
        for (int fm = 0; fm < 2; ++fm)
#pragma unroll
            for (int nt = 0; nt < 2; ++nt) S[fm][nt] = z4;
#pragma unroll
        for (int ks = 0; ks < 4; ++ks) {
#pragma unroll
            for (int nt = 0; nt < 2; ++nt) {
                int o = (nt * 16 + ln) * 136 + ks * 32 + qd * 8;
                s8v kbhf = *(const s8v*)&Ksh[o];
                s8v kblf = *(const s8v*)&Ksl[o];
#pragma unroll
                for (int fm = 0; fm < 2; ++fm) {
                    S[fm][nt] = MFMA16(Qh[fm][ks],  kbhf, S[fm][nt]);
                    S[fm][nt] = MFMA16(Qh[fm][ks],  kblf, S[fm][nt]);
                    S[fm][nt] = MFMA16(Qlv[fm][ks], kbhf, S[fm][nt]);
                }
            }
        }

        // ---- online softmax (two independent row-blocks -> ILP) ----
        float pv[2][2][4];
#pragma unroll
        for (int fm = 0; fm < 2; ++fm) {
            float mt[4];
#pragma unroll
            for (int r = 0; r < 4; ++r) mt[r] = fmaxf(S[fm][0][r], S[fm][1][r]);
#pragma unroll
            for (int mask = 1; mask < 16; mask <<= 1)
#pragma unroll
                for (int r = 0; r < 4; ++r)
                    mt[r] = fmaxf(mt[r], __shfl_xor(mt[r], mask, 64));
            float alpha[4];
#pragma unroll
            for (int r = 0; r < 4; ++r) {
                float mn = fmaxf(mrow[fm][r], mt[r]);
                alpha[r] = __expf(mrow[fm][r] - mn);
                mrow[fm][r] = mn;
            }
            float lt[4] = {0.f, 0.f, 0.f, 0.f};
#pragma unroll
            for (int nt = 0; nt < 2; ++nt)
#pragma unroll
                for (int r = 0; r < 4; ++r) {
                    float p = __expf(S[fm][nt][r] - mrow[fm][r]);
                    pv[fm][nt][r] = p;
                    lt[r] += p;
                }
#pragma unroll
            for (int mask = 1; mask < 16; mask <<= 1)
#pragma unroll
                for (int r = 0; r < 4; ++r)
                    lt[r] += __shfl_xor(lt[r], mask, 64);
#pragma unroll
            for (int r = 0; r < 4; ++r)
                lrow[fm][r] = alpha[r] * lrow[fm][r] + lt[r];
#pragma unroll
            for (int fn = 0; fn < 8; ++fn)
#pragma unroll
                for (int r = 0; r < 4; ++r) Of[fm][fn][r] *= alpha[r];
        }

        // ---- P (C-layout) -> per-wave LDS (A-layout source) ----
#pragma unroll
        for (int fm = 0; fm < 2; ++fm)
#pragma unroll
            for (int nt = 0; nt < 2; ++nt)
#pragma unroll
                for (int r = 0; r < 4; ++r)
                    Ps[w][(fm * 16 + qd * 4 + r) * 40 + nt * 16 + ln] =
                        bf16rne(pv[fm][nt][r]);
        // same-wave write->read: compiler inserts lgkmcnt wait; no barrier.

        // ---- PV: Of += P * V, V frags shared across the 2 row-blocks ----
        s8v pf[2];
#pragma unroll
        for (int fm = 0; fm < 2; ++fm)
            pf[fm] = *(const s8v*)&Ps[w][(fm * 16 + ln) * 40 + qd * 8];
#pragma unroll
        for (int fn = 0; fn < 8; ++fn) {
            int o = (fn * 16 + ln) * 40 + qd * 8;
            s8v vbhf = *(const s8v*)&Vsh[o];
            s8v vblf = *(const s8v*)&Vsl[o];
#pragma unroll
            for (int fm = 0; fm < 2; ++fm) {
                Of[fm][fn] = MFMA16(pf[fm], vbhf, Of[fm][fn]);
                Of[fm][fn] = MFMA16(pf[fm], vblf, Of[fm][fn]);
            }
        }

        __syncthreads();                  // all waves done reading K/V LDS
        if (more) {
            STORELDS();                   // waits vmcnt for rK/rV arrival
            __syncthreads();              // next tile staged
        }
    }

    // ---- epilogue: normalize, split to bf16 hi/lo, store res[token][1024] --
    const int b = bh >> 3, h = bh & 7;
#pragma unroll
    for (int fm = 0; fm < 2; ++fm)
#pragma unroll
        for (int r = 0; r < 4; ++r) {
            float linv = 1.f / lrow[fm][r];
            int qi = q0 + w * 32 + fm * 16 + qd * 4 + r;
            size_t off = (size_t)(b * SS + qi) * DM + h * DH + ln;
#pragma unroll
            for (int fn = 0; fn < 8; ++fn) {
                u16 hh, ll;
                bfsplit(Of[fm][fn][r] * linv, hh, ll);
                res_hi[off + fn * 16] = hh;
                res_lo[off + fn * 16] = ll;
            }
        }
#undef LOADREGS
#undef STORELDS
}

// ---------------------------------------------------------------------------
extern "C" void kernel_launch(void* const* d_in, const int* in_sizes, int n_in,
                              void* d_out, int out_size, void* d_ws, size_t ws_size,
                              hipStream_t stream) {
    (void)in_sizes; (void)n_in; (void)out_size; (void)ws_size;
    const float* q_src = (const float*)d_in[0];
    const float* k_src = (const float*)d_in[1];
    const float* v_src = (const float*)d_in[2];
    const float* Wq    = (const float*)d_in[3];
    const float* Wk    = (const float*)d_in[4];
    const float* V     = (const float*)d_in[5];
    const float* O     = (const float*)d_in[6];
    const float* sel_v = (const float*)d_in[7];
    const float* sel_o = (const float*)d_in[8];
    float* out = (float*)d_out;

    // workspace layout
    const size_t NELT = (size_t)NTOK * DM;   // 8388608
    u16* wq_h = (u16*)d_ws;                  // q hi/lo [bh][s][f]
    u16* wq_l = wq_h + NELT;
    u16* wk_h = wq_l + NELT;                 // k hi/lo
    u16* wk_l = wk_h + NELT;
    float* wv = (float*)(wk_l + NELT);       // v fp32 [bh][s][f]
    u16* res_hi = (u16*)(wv + NELT);         // attention result hi/lo
    u16* res_lo = res_hi + NELT;
    u16* vs_hi  = res_lo + NELT;             // vsrc split (later: Ot)
    u16* vs_lo  = vs_hi + NELT;
    u16* Vt_hi  = vs_lo + NELT;              // V transposed (later: vT)
    u16* Vt_lo  = Vt_hi + NELT;
    float* gv = (float*)(Vt_lo + NELT);      // dense gates [8192][64]
    float* go = gv + (size_t)NTOK * 64;
    u16* Wq_h = (u16*)(go + (size_t)NTOK * 64);  // W splits (1024x1024 each)
    u16* Wq_l = Wq_h + (size_t)DM * DM;
    u16* Wk_h = Wq_l + (size_t)DM * DM;
    u16* Wk_l = Wk_h + (size_t)DM * DM;
    // aliases (regions dead during the phase they are used)
    u16* qsrc_h = res_hi;                    // dead until attn writes res
    u16* qsrc_l = res_lo;
    u16* ksrc_h = (u16*)wv;                  // dead until v_mfma writes wv
    u16* ksrc_l = ksrc_h + NELT;
    u16* Ot_hi = vs_hi;                      // alias (dead after v_mfma)
    u16* Ot_lo = vs_lo;
    u16* vth   = Vt_hi;                      // alias (dead after v_mfma)
    u16* vtl   = Vt_lo;

    // preprocess: splits
    split_kernel<<<NELT / 1024, 256, 0, stream>>>(v_src, vs_hi, vs_lo);
    split_kernel<<<NELT / 1024, 256, 0, stream>>>(q_src, qsrc_h, qsrc_l);
    split_kernel<<<NELT / 1024, 256, 0, stream>>>(k_src, ksrc_h, ksrc_l);
    split_kernel<<<(DM * DM) / 1024, 256, 0, stream>>>(Wq, Wq_h, Wq_l);
    split_kernel<<<(DM * DM) / 1024, 256, 0, stream>>>(Wk, Wk_h, Wk_l);
    tsplit_kernel<<<dim3(64, 32, 4), 256, 0, stream>>>(V, Vt_hi, Vt_lo, 1024, 128);

    // gates
    gate_kernel<<<NTOK, 64, 0, stream>>>(k_src, sel_v, gv);
    gate_kernel<<<NTOK, 64, 0, stream>>>(q_src, sel_o, go);

    // q/k projections via MFMA (emit bf16 hi/lo)
    proj_mfma_kernel<<<dim3(64, 8), 256, 0, stream>>>(
        qsrc_h, qsrc_l, Wq_h, Wq_l, wq_h, wq_l, SCALE_SQRT);
    proj_mfma_kernel<<<dim3(64, 8), 256, 0, stream>>>(
        ksrc_h, ksrc_l, Wk_h, Wk_l, wk_h, wk_l, SCALE_SQRT);

    // value CVMM (MFMA) -> wv fp32 (overwrites ksrc splits: proj done)
    v_mfma_kernel<<<dim3(64, 8), 256, 0, stream>>>(vs_hi, vs_lo, Vt_hi, Vt_lo, gv, wv);

    // transpose+split O into dead vsrc buffers
    tsplit_kernel<<<dim3(64, 4, 32), 256, 0, stream>>>(O, Ot_hi, Ot_lo, 128, 1024);

    // transpose+split v into dead Vt buffers: vT[bh][f][s]
    tsplit_kernel<<<dim3(32, 64, 4), 256, 0, stream>>>(wv, vth, vtl, 2048, 128);

    // attention (MFMA flash; 128-query tiles; writes res = overwrites qsrc)
    attn_mfma_kernel<<<BB * NH * (SS / 128), 256, 0, stream>>>(
        wq_h, wq_l, wk_h, wk_l, vth, vtl, res_hi, res_lo);

    // output CVMM (MFMA)
    out_mfma_kernel<<<dim3(8, 64), 256, 0, stream>>>(res_hi, res_lo, Ot_hi, Ot_lo, go, out);
}

// Round 6
// 1692.824 us; speedup vs baseline: 1.9054x; 1.0052x over previous
//
#include <hip/hip_runtime.h>
#include <hip/hip_bf16.h>
#include <math.h>

// Problem constants
#define BB 4
#define SS 2048
#define DM 1024
#define NH 8
#define DH 128
#define NE 8
#define NTOK (BB*SS)          // 8192
#define SCALE_SQRT 0.29730177875068026f

typedef unsigned short u16;
typedef short s8v __attribute__((ext_vector_type(8)));
typedef float f4v __attribute__((ext_vector_type(4)));
#define MFMA16(a,b,c) __builtin_amdgcn_mfma_f32_16x16x32_bf16((a),(b),(c),0,0,0)

// Round-to-nearest-even fp32 -> bf16 split: x ~= hi + lo (each bf16).
__device__ inline void bfsplit(float x, u16& h, u16& l) {
    unsigned u = __float_as_uint(x);
    unsigned hr = (u + 0x7FFFu + ((u >> 16) & 1u)) >> 16;
    h = (u16)hr;
    float hf = __uint_as_float(hr << 16);
    unsigned u2 = __float_as_uint(x - hf);
    l = (u16)((u2 + 0x7FFFu + ((u2 >> 16) & 1u)) >> 16);
}
__device__ inline u16 bf16rne(float x) {
    unsigned u = __float_as_uint(x);
    return (u16)((u + 0x7FFFu + ((u >> 16) & 1u)) >> 16);
}

// Async global->LDS 16B copy. LDS dest = wave-uniform base + lane*16;
// global source address is PER-LANE (supports gather).
__device__ inline void gll16(const u16* g, u16* l) {
    __builtin_amdgcn_global_load_lds(
        (const __attribute__((address_space(1))) unsigned int*)g,
        (__attribute__((address_space(3))) unsigned int*)l,
        16, 0, 0);
}

// Swizzled tile offset (u16 units) for [128][64]-u16 tiles staged linearly:
// row's 16B chunk c stored at chunk index c ^ (row&7). Same XOR on read.
__device__ inline int swzoff(int row, int kchunk) {
    return row * 64 + ((kchunk ^ (row & 7)) << 3);
}

// ---------------------------------------------------------------------------
// Projection GEMM via split-bf16 MFMA (3-term): out = scale * (x @ W^T).
// ---------------------------------------------------------------------------
__global__ __launch_bounds__(256, 2) void proj_mfma_kernel(
        const u16* __restrict__ Ah_g, const u16* __restrict__ Al_g,
        const u16* __restrict__ Bh_g, const u16* __restrict__ Bl_g,
        u16* __restrict__ out_h, u16* __restrict__ out_l, float scale) {
    const int i0 = blockIdx.x * 128;
    const int n0 = blockIdx.y * 128;
    __shared__ u16 Ah[128 * 64], Al[128 * 64], Bh[128 * 64], Bl[128 * 64];
    const int t = threadIdx.x;
    const int lane = t & 63, wave = t >> 6;
    const int wm = wave >> 1, wn = wave & 1;
    const int ln = lane & 15, qd = lane >> 4;
    const f4v z4 = {0.f, 0.f, 0.f, 0.f};

    f4v C[4][4];
#pragma unroll
    for (int fm = 0; fm < 4; ++fm)
#pragma unroll
        for (int fn = 0; fn < 4; ++fn) C[fm][fn] = z4;

    for (int kb = 0; kb < 16; ++kb) {
        __syncthreads();
        const int kbase = kb * 64;
#pragma unroll
        for (int p = 0; p < 4; ++p) {
            int chunk = p * 256 + t;
            int row = chunk >> 3;
            int cs  = ((chunk & 7) ^ (row & 7)) * 8;     // swizzled src col (u16)
            int ld  = (p * 256 + (t & 192)) * 8;         // wave-uniform LDS base
            size_t ga = (size_t)(i0 + row) * 1024 + kbase + cs;
            gll16(&Ah_g[ga], &Ah[ld]);
            gll16(&Al_g[ga], &Al[ld]);
            size_t gb = (size_t)(n0 + row) * 1024 + kbase + cs;
            gll16(&Bh_g[gb], &Bh[ld]);
            gll16(&Bl_g[gb], &Bl[ld]);
        }
        __syncthreads();
#pragma unroll
        for (int ks = 0; ks < 2; ++ks) {
            s8v ah[4], alv[4], bh[4], blv[4];
#pragma unroll
            for (int fm = 0; fm < 4; ++fm) {
                int o = swzoff(wm * 64 + fm * 16 + ln, ks * 4 + qd);
                ah[fm]  = *(const s8v*)&Ah[o];
                alv[fm] = *(const s8v*)&Al[o];
            }
#pragma unroll
            for (int fn = 0; fn < 4; ++fn) {
                int o = swzoff(wn * 64 + fn * 16 + ln, ks * 4 + qd);
                bh[fn]  = *(const s8v*)&Bh[o];
                blv[fn] = *(const s8v*)&Bl[o];
            }
#pragma unroll
            for (int fm = 0; fm < 4; ++fm)
#pragma unroll
                for (int fn = 0; fn < 4; ++fn) {
                    C[fm][fn] = MFMA16(ah[fm],  bh[fn],  C[fm][fn]);
                    C[fm][fn] = MFMA16(ah[fm],  blv[fn], C[fm][fn]);
                    C[fm][fn] = MFMA16(alv[fm], bh[fn],  C[fm][fn]);
                }
        }
    }
    const int h = n0 >> 7;
#pragma unroll
    for (int fm = 0; fm < 4; ++fm)
#pragma unroll
        for (int fn = 0; fn < 4; ++fn)
#pragma unroll
            for (int r = 0; r < 4; ++r) {
                int token = i0 + wm * 64 + fm * 16 + qd * 4 + r;
                int f = wn * 64 + fn * 16 + ln;
                int b = token >> 11, s = token & 2047;
                u16 hh, ll;
                bfsplit(C[fm][fn][r] * scale, hh, ll);
                size_t o = ((((size_t)(b * NH + h)) * SS + s) << 7) + f;
                out_h[o] = hh; out_l[o] = ll;
            }
}

// ---------------------------------------------------------------------------
// Zero helper for bucket counters.
// ---------------------------------------------------------------------------
__global__ void zero_kernel(int* __restrict__ p, int n) {
    int i = blockIdx.x * 128 + threadIdx.x;
    if (i < n) p[i] = 0;
}

// ---------------------------------------------------------------------------
// Gate: dense sparse-valued gate g[token][h][e]; float4 dot (same fma order
// as scalar loop -> identical results). Optionally builds (h,best) buckets.
// ---------------------------------------------------------------------------
__global__ void gate_kernel(const float* __restrict__ x,
                            const float* __restrict__ sel,
                            float* __restrict__ gdense,
                            int* __restrict__ bcnt,
                            int* __restrict__ bidx,
                            float* __restrict__ bgv) {
    __shared__ float xs[DM];
    __shared__ float logits[64];
    __shared__ int   sbest[NH];
    __shared__ float sg1[NH], sg2[NH];
    const int token = blockIdx.x;
    const int t = threadIdx.x;  // 0..63
    const float4* xp4 = (const float4*)(x + (size_t)token * DM);
    float4* xs4 = (float4*)xs;
    for (int i = t; i < DM / 4; i += 64) xs4[i] = xp4[i];
    __syncthreads();
    const float4* sp4 = (const float4*)(sel + (size_t)t * DM);
    float acc = 0.f;
    for (int d = 0; d < DM / 4; ++d) {
        float4 a = xs4[d], b = sp4[d];
        acc += a.x * b.x; acc += a.y * b.y;
        acc += a.z * b.z; acc += a.w * b.w;
    }
    logits[t] = acc;
    __syncthreads();
    if (t < NH) {
        const float* lp = logits + t * NE;
        int best = 0; float bv = lp[0];
#pragma unroll
        for (int e = 1; e < NE - 1; ++e)
            if (lp[e] > bv) { bv = lp[e]; best = e; }   // strict > == lowest idx tie
        float g1 = 1.f / (1.f + expf(-bv));
        sbest[t] = best;
        sg1[t] = g1;
        sg2[t] = 1.f / (1.f + expf(-lp[NE - 1]));
        if (bidx != nullptr) {
            int bk = t * 7 + best;
            int slot = atomicAdd(&bcnt[bk], 1);
            bidx[(size_t)bk * NTOK + slot] = token;
            bgv [(size_t)bk * NTOK + slot] = g1;
        }
    }
    __syncthreads();
    const int h = t >> 3, e = t & 7;
    float val = (e == sbest[h]) ? sg1[h] : ((e == NE - 1) ? sg2[h] : 0.f);
    gdense[(size_t)token * 64 + t] = val;
}

// ---------------------------------------------------------------------------
// Preprocess: split fp32 -> bf16 hi/lo (no transpose). n divisible by 1024.
// ---------------------------------------------------------------------------
__global__ void split_kernel(const float* __restrict__ src,
                             u16* __restrict__ dh, u16* __restrict__ dl) {
    int i = (blockIdx.x * 256 + threadIdx.x) * 4;
    float4 v = *(const float4*)(src + i);
    u16 h[4], l[4];
    bfsplit(v.x, h[0], l[0]); bfsplit(v.y, h[1], l[1]);
    bfsplit(v.z, h[2], l[2]); bfsplit(v.w, h[3], l[3]);
    uint2 ph = { (unsigned)h[0] | ((unsigned)h[1] << 16),
                 (unsigned)h[2] | ((unsigned)h[3] << 16) };
    uint2 pl = { (unsigned)l[0] | ((unsigned)l[1] << 16),
                 (unsigned)l[2] | ((unsigned)l[3] << 16) };
    *(uint2*)&dh[i] = ph;
    *(uint2*)&dl[i] = pl;
}

// ---------------------------------------------------------------------------
// Preprocess: per-matrix transpose + split. src[mat][R][C] -> dst[mat][C][R].
// ---------------------------------------------------------------------------
__global__ void tsplit_kernel(const float* __restrict__ src,
                              u16* __restrict__ dh, u16* __restrict__ dl,
                              int R, int C) {
    __shared__ float tile[32][33];
    const int mat = blockIdx.x;
    const int r0 = blockIdx.y * 32, c0 = blockIdx.z * 32;
    const size_t base = (size_t)mat * R * C;
    const int tr = threadIdx.x >> 5, tc = threadIdx.x & 31;
#pragma unroll
    for (int p = 0; p < 4; ++p)
        tile[tr + p * 8][tc] = src[base + (size_t)(r0 + tr + p * 8) * C + c0 + tc];
    __syncthreads();
#pragma unroll
    for (int p = 0; p < 4; ++p) {
        int cc = tr + p * 8, rr = tc;
        float x = tile[rr][cc];
        u16 hh, ll; bfsplit(x, hh, ll);
        size_t o = base + (size_t)(c0 + cc) * R + r0 + rr;
        dh[o] = hh; dl[o] = ll;
    }
}

// ---------------------------------------------------------------------------
// Value CVMM, SHARED expert (e=7), dense over tokens. Writes wv = g*C.
// ---------------------------------------------------------------------------
__global__ __launch_bounds__(256, 2) void v_shared_kernel(
        const u16* __restrict__ Ah_g, const u16* __restrict__ Al_g,
        const u16* __restrict__ Bh_g, const u16* __restrict__ Bl_g,
        const float* __restrict__ gdense,
        float* __restrict__ wv) {
    const int i0 = blockIdx.x * 128;
    const int h  = blockIdx.y;
    __shared__ u16 Ah[128 * 64], Al[128 * 64], Bh[128 * 64], Bl[128 * 64];
    __shared__ float gl[128];
    const int t = threadIdx.x;
    const int lane = t & 63, wave = t >> 6;
    const int wm = wave >> 1, wn = wave & 1;
    const int ln = lane & 15, qd = lane >> 4;
    const f4v z4 = {0.f, 0.f, 0.f, 0.f};

    if (t < 128) gl[t] = gdense[(size_t)(i0 + t) * 64 + h * 8 + 7];

    f4v C[4][4];
#pragma unroll
    for (int fm = 0; fm < 4; ++fm)
#pragma unroll
        for (int fn = 0; fn < 4; ++fn) C[fm][fn] = z4;

    const size_t bbase = (size_t)(h * 8 + 7) * DH * 1024;
    for (int kb = 0; kb < 16; ++kb) {
        __syncthreads();
        const int kbase = kb * 64;
#pragma unroll
        for (int p = 0; p < 4; ++p) {
            int chunk = p * 256 + t;
            int row = chunk >> 3;
            int cs  = ((chunk & 7) ^ (row & 7)) * 8;
            int ld  = (p * 256 + (t & 192)) * 8;
            size_t ga = (size_t)(i0 + row) * 1024 + kbase + cs;
            gll16(&Ah_g[ga], &Ah[ld]);
            gll16(&Al_g[ga], &Al[ld]);
            size_t gb = bbase + (size_t)row * 1024 + kbase + cs;
            gll16(&Bh_g[gb], &Bh[ld]);
            gll16(&Bl_g[gb], &Bl[ld]);
        }
        __syncthreads();
#pragma unroll
        for (int ks = 0; ks < 2; ++ks) {
            s8v ah[4], alv[4], bh[4], blv[4];
#pragma unroll
            for (int fm = 0; fm < 4; ++fm) {
                int o = swzoff(wm * 64 + fm * 16 + ln, ks * 4 + qd);
                ah[fm]  = *(const s8v*)&Ah[o];
                alv[fm] = *(const s8v*)&Al[o];
            }
#pragma unroll
            for (int fn = 0; fn < 4; ++fn) {
                int o = swzoff(wn * 64 + fn * 16 + ln, ks * 4 + qd);
                bh[fn]  = *(const s8v*)&Bh[o];
                blv[fn] = *(const s8v*)&Bl[o];
            }
#pragma unroll
            for (int fm = 0; fm < 4; ++fm)
#pragma unroll
                for (int fn = 0; fn < 4; ++fn) {
                    C[fm][fn] = MFMA16(ah[fm],  bh[fn],  C[fm][fn]);
                    C[fm][fn] = MFMA16(ah[fm],  blv[fn], C[fm][fn]);
                    C[fm][fn] = MFMA16(alv[fm], bh[fn],  C[fm][fn]);
                }
        }
    }
#pragma unroll
    for (int fm = 0; fm < 4; ++fm)
#pragma unroll
        for (int fn = 0; fn < 4; ++fn)
#pragma unroll
            for (int r = 0; r < 4; ++r) {
                int row = wm * 64 + fm * 16 + qd * 4 + r;
                int token = i0 + row;
                int f = wn * 64 + fn * 16 + ln;
                int b = token >> 11, s = token & 2047;
                wv[(((size_t)(b * NH + h) * SS + s) << 7) + f] = gl[row] * C[fm][fn][r];
            }
}

// ---------------------------------------------------------------------------
// Value CVMM, ROUTED experts via (h,best) buckets; single launch, race-free
// (+= safe: each (token,h) in exactly one bucket). Gathered-A via gll16
// (per-lane global source address). grid (64 tiles, 56 buckets).
// ---------------------------------------------------------------------------
__global__ __launch_bounds__(256, 2) void v_routed_kernel(
        const u16* __restrict__ Ah_g, const u16* __restrict__ Al_g,
        const u16* __restrict__ Bh_g, const u16* __restrict__ Bl_g,
        const int* __restrict__ bcnt, const int* __restrict__ bidx,
        const float* __restrict__ bgv,
        float* __restrict__ wv) {
    const int bucket = blockIdx.y;           // h*7 + e
    const int cnt = bcnt[bucket];
    const int tile0 = blockIdx.x * 128;
    if (tile0 >= cnt) return;
    const int h = bucket / 7, e = bucket % 7;
    const int rows = min(128, cnt - tile0);
    __shared__ u16 Ah[128 * 64], Al[128 * 64], Bh[128 * 64], Bl[128 * 64];
    __shared__ int   toks[128];
    __shared__ float gvals[128];
    const int t = threadIdx.x;
    const int lane = t & 63, wave = t >> 6;
    const int wm = wave >> 1, wn = wave & 1;
    const int ln = lane & 15, qd = lane >> 4;
    const f4v z4 = {0.f, 0.f, 0.f, 0.f};

    if (t < 128) {
        int slot = tile0 + min(t, rows - 1);   // clamp: padding rows duplicate
        toks[t]  = bidx[(size_t)bucket * NTOK + slot];
        gvals[t] = bgv [(size_t)bucket * NTOK + slot];
    }
    __syncthreads();
    // per-thread gathered token ids for A staging (rows t>>3 + 32p) — named
    const int rb = t >> 3;
    const int tok0 = toks[rb], tok1 = toks[32 + rb];
    const int tok2 = toks[64 + rb], tok3 = toks[96 + rb];

    f4v C[4][4];
#pragma unroll
    for (int fm = 0; fm < 4; ++fm)
#pragma unroll
        for (int fn = 0; fn < 4; ++fn) C[fm][fn] = z4;

    const size_t bbase = (size_t)(h * 8 + e) * DH * 1024;
    for (int kb = 0; kb < 16; ++kb) {
        __syncthreads();
        const int kbase = kb * 64;
#pragma unroll
        for (int p = 0; p < 4; ++p) {
            int chunk = p * 256 + t;
            int row = chunk >> 3;                    // 32p + rb
            int cs  = ((chunk & 7) ^ (row & 7)) * 8;
            int ld  = (p * 256 + (t & 192)) * 8;
            int tok = (p == 0) ? tok0 : (p == 1) ? tok1 : (p == 2) ? tok2 : tok3;
            size_t ga = (size_t)tok * 1024 + kbase + cs;
            gll16(&Ah_g[ga], &Ah[ld]);
            gll16(&Al_g[ga], &Al[ld]);
            size_t gb = bbase + (size_t)row * 1024 + kbase + cs;
            gll16(&Bh_g[gb], &Bh[ld]);
            gll16(&Bl_g[gb], &Bl[ld]);
        }
        __syncthreads();
#pragma unroll
        for (int ks = 0; ks < 2; ++ks) {
            s8v ah[4], alv[4], bh[4], blv[4];
#pragma unroll
            for (int fm = 0; fm < 4; ++fm) {
                int o = swzoff(wm * 64 + fm * 16 + ln, ks * 4 + qd);
                ah[fm]  = *(const s8v*)&Ah[o];
                alv[fm] = *(const s8v*)&Al[o];
            }
#pragma unroll
            for (int fn = 0; fn < 4; ++fn) {
                int o = swzoff(wn * 64 + fn * 16 + ln, ks * 4 + qd);
                bh[fn]  = *(const s8v*)&Bh[o];
                blv[fn] = *(const s8v*)&Bl[o];
            }
#pragma unroll
            for (int fm = 0; fm < 4; ++fm)
#pragma unroll
                for (int fn = 0; fn < 4; ++fn) {
                    C[fm][fn] = MFMA16(ah[fm],  bh[fn],  C[fm][fn]);
                    C[fm][fn] = MFMA16(ah[fm],  blv[fn], C[fm][fn]);
                    C[fm][fn] = MFMA16(alv[fm], bh[fn],  C[fm][fn]);
                }
        }
    }
#pragma unroll
    for (int fm = 0; fm < 4; ++fm)
#pragma unroll
        for (int fn = 0; fn < 4; ++fn)
#pragma unroll
            for (int r = 0; r < 4; ++r) {
                int row = wm * 64 + fm * 16 + qd * 4 + r;
                if (row >= rows) continue;     // guard padding rows
                int token = toks[row];
                int f = wn * 64 + fn * 16 + ln;
                int b = token >> 11, s = token & 2047;
                wv[(((size_t)(b * NH + h) * SS + s) << 7) + f] += gvals[row] * C[fm][fn][r];
            }
}

// ---------------------------------------------------------------------------
// Output CVMM, split-bf16 MFMA, dense over (h,e). (unchanged)
// ---------------------------------------------------------------------------
__global__ __launch_bounds__(256, 2) void out_mfma_kernel(
        const u16* __restrict__ Ah_g, const u16* __restrict__ Al_g,
        const u16* __restrict__ Bh_g, const u16* __restrict__ Bl_g,
        const float* __restrict__ gdense,
        float* __restrict__ out) {
    const int n0 = blockIdx.x * 128;
    const int i0 = blockIdx.y * 128;
    __shared__ u16 Ah[128 * 64], Al[128 * 64], Bh[128 * 64], Bl[128 * 64];
    __shared__ float gl[128 * 8];
    const int t = threadIdx.x;
    const int lane = t & 63, wave = t >> 6;
    const int wm = wave >> 1, wn = wave & 1;
    const int ln = lane & 15, qd = lane >> 4;
    const f4v z4 = {0.f, 0.f, 0.f, 0.f};

    f4v C[4][4];
#pragma unroll
    for (int fm = 0; fm < 4; ++fm)
#pragma unroll
        for (int fn = 0; fn < 4; ++fn) C[fm][fn] = z4;

    for (int h = 0; h < 8; ++h) {
        __syncthreads();
#pragma unroll
        for (int p = 0; p < 4; ++p) {
            int idx = p * 256 + t;
            gl[idx] = gdense[(size_t)(i0 + (idx >> 3)) * 64 + h * 8 + (idx & 7)];
        }
        for (int e = 0; e < 8; ++e) {
            f4v T[4][4];
#pragma unroll
            for (int fm = 0; fm < 4; ++fm)
#pragma unroll
                for (int fn = 0; fn < 4; ++fn) T[fm][fn] = z4;
            const size_t bbase = ((size_t)(h * 8 + e) * 1024 + n0) * DH;
#pragma unroll
            for (int kb = 0; kb < 2; ++kb) {
                __syncthreads();
                const int ka = h * 128 + kb * 64;
                const int kbb = kb * 64;
#pragma unroll
                for (int p = 0; p < 4; ++p) {
                    int chunk = p * 256 + t;
                    int row = chunk >> 3;
                    int cs  = ((chunk & 7) ^ (row & 7)) * 8;
                    int ld  = (p * 256 + (t & 192)) * 8;
                    size_t ga = (size_t)(i0 + row) * 1024 + ka + cs;
                    gll16(&Ah_g[ga], &Ah[ld]);
                    gll16(&Al_g[ga], &Al[ld]);
                    size_t gb = bbase + (size_t)row * DH + kbb + cs;
                    gll16(&Bh_g[gb], &Bh[ld]);
                    gll16(&Bl_g[gb], &Bl[ld]);
                }
                __syncthreads();
#pragma unroll
                for (int ks = 0; ks < 2; ++ks) {
                    s8v ah[4], alv[4], bh[4], blv[4];
#pragma unroll
                    for (int fm = 0; fm < 4; ++fm) {
                        int o = swzoff(wm * 64 + fm * 16 + ln, ks * 4 + qd);
                        ah[fm]  = *(const s8v*)&Ah[o];
                        alv[fm] = *(const s8v*)&Al[o];
                    }
#pragma unroll
                    for (int fn = 0; fn < 4; ++fn) {
                        int o = swzoff(wn * 64 + fn * 16 + ln, ks * 4 + qd);
                        bh[fn]  = *(const s8v*)&Bh[o];
                        blv[fn] = *(const s8v*)&Bl[o];
                    }
#pragma unroll
                    for (int fm = 0; fm < 4; ++fm)
#pragma unroll
                        for (int fn = 0; fn < 4; ++fn) {
                            T[fm][fn] = MFMA16(ah[fm],  bh[fn],  T[fm][fn]);
                            T[fm][fn] = MFMA16(ah[fm],  blv[fn], T[fm][fn]);
                            T[fm][fn] = MFMA16(alv[fm], bh[fn],  T[fm][fn]);
                        }
                }
            }
#pragma unroll
            for (int fm = 0; fm < 4; ++fm)
#pragma unroll
                for (int r = 0; r < 4; ++r) {
                    float g = gl[(wm * 64 + fm * 16 + qd * 4 + r) * 8 + e];
#pragma unroll
                    for (int fn = 0; fn < 4; ++fn)
                        C[fm][fn][r] += g * T[fm][fn][r];
                }
        }
    }
#pragma unroll
    for (int fm = 0; fm < 4; ++fm)
#pragma unroll
        for (int fn = 0; fn < 4; ++fn)
#pragma unroll
            for (int r = 0; r < 4; ++r) {
                int token = i0 + wm * 64 + fm * 16 + qd * 4 + r;
                int d = n0 + wn * 64 + fn * 16 + ln;
                out[(size_t)token * DM + d] = C[fm][fn][r];
            }
}

// ---------------------------------------------------------------------------
// MFMA flash attention (unchanged from round 5).
// ---------------------------------------------------------------------------
__global__ __launch_bounds__(256, 2) void attn_mfma_kernel(
        const u16* __restrict__ qh, const u16* __restrict__ ql,
        const u16* __restrict__ kh, const u16* __restrict__ kl,
        const u16* __restrict__ vth, const u16* __restrict__ vtl,
        u16* __restrict__ res_hi, u16* __restrict__ res_lo) {
    const int bid = blockIdx.x;          // bh*16 + qtile
    const int bh = bid >> 4;
    const int q0 = (bid & 15) * 128;

    __shared__ u16 Ksh[32 * 136];        // 8704 B
    __shared__ u16 Ksl[32 * 136];
    __shared__ u16 Vsh[128 * 40];        // 10240 B
    __shared__ u16 Vsl[128 * 40];
    __shared__ u16 Ps[4][32 * 40];       // 10240 B  -> total 48128 B

    const int t = threadIdx.x;
    const int lane = t & 63, w = t >> 6;
    const int ln = lane & 15, qd = lane >> 4;

    // Q A-fragments in registers: 2 row-blocks of 16 (m = ln within block)
    s8v Qh[2][4], Qlv[2][4];
#pragma unroll
    for (int fm = 0; fm < 2; ++fm) {
        const size_t qoff = ((size_t)bh * SS + q0 + w * 32 + fm * 16 + ln) * DH;
        const u16* qhp = qh + qoff;
        const u16* qlp = ql + qoff;
#pragma unroll
        for (int ks = 0; ks < 4; ++ks) {
            Qh[fm][ks]  = *(const s8v*)(qhp + ks * 32 + qd * 8);
            Qlv[fm][ks] = *(const s8v*)(qlp + ks * 32 + qd * 8);
        }
    }

    f4v Of[2][8];
    const f4v z4 = {0.f, 0.f, 0.f, 0.f};
#pragma unroll
    for (int fm = 0; fm < 2; ++fm)
#pragma unroll
        for (int fn = 0; fn < 8; ++fn) Of[fm][fn] = z4;
    float mrow[2][4], lrow[2][4];
#pragma unroll
    for (int fm = 0; fm < 2; ++fm)
#pragma unroll
        for (int r = 0; r < 4; ++r) { mrow[fm][r] = -INFINITY; lrow[fm][r] = 0.f; }

    const u16* kbh = kh + (size_t)bh * SS * DH;
    const u16* kbl = kl + (size_t)bh * SS * DH;
    const u16* vbh = vth + (size_t)bh * DH * SS;   // [f][s]
    const u16* vbl = vtl + (size_t)bh * DH * SS;

    // per-thread staging addresses (chunk = t and chunk = 256+t)
    const int krow0 = t >> 4,        kc0 = t & 15;
    const int krow1 = (256 + t) >> 4, kc1 = (256 + t) & 15;
    const int vrow0 = t >> 2,        vc0 = t & 3;
    const int vrow1 = (256 + t) >> 2, vc1 = (256 + t) & 3;
    const int kld0 = krow0 * 136 + kc0 * 8, kld1 = krow1 * 136 + kc1 * 8;
    const int vld0 = vrow0 * 40 + vc0 * 8,  vld1 = vrow1 * 40 + vc1 * 8;

    // staging registers — NAMED scalars, straight-line code (no arrays)
    uint4 rKh0, rKh1, rKl0, rKl1, rVh0, rVh1, rVl0, rVl1;

#define LOADREGS(KT)                                                         \
    {                                                                        \
        size_t g0 = (size_t)((KT) * 32 + krow0) * DH + kc0 * 8;              \
        size_t g1 = (size_t)((KT) * 32 + krow1) * DH + kc1 * 8;              \
        rKh0 = *(const uint4*)&kbh[g0];  rKl0 = *(const uint4*)&kbl[g0];     \
        rKh1 = *(const uint4*)&kbh[g1];  rKl1 = *(const uint4*)&kbl[g1];     \
        size_t v0 = (size_t)vrow0 * SS + (KT) * 32 + vc0 * 8;                \
        size_t v1 = (size_t)vrow1 * SS + (KT) * 32 + vc1 * 8;                \
        rVh0 = *(const uint4*)&vbh[v0];  rVl0 = *(const uint4*)&vbl[v0];     \
        rVh1 = *(const uint4*)&vbh[v1];  rVl1 = *(const uint4*)&vbl[v1];     \
    }

#define STORELDS()                                                           \
    {                                                                        \
        *(uint4*)&Ksh[kld0] = rKh0;  *(uint4*)&Ksl[kld0] = rKl0;             \
        *(uint4*)&Ksh[kld1] = rKh1;  *(uint4*)&Ksl[kld1] = rKl1;             \
        *(uint4*)&Vsh[vld0] = rVh0;  *(uint4*)&Vsl[vld0] = rVl0;             \
        *(uint4*)&Vsh[vld1] = rVh1;  *(uint4*)&Vsl[vld1] = rVl1;             \
    }

    // prologue: stage tile 0
    LOADREGS(0);
    STORELDS();
    __syncthreads();

    for (int kt = 0; kt < SS / 32; ++kt) {
        const bool more = (kt + 1 < SS / 32);
        if (more) LOADREGS(kt + 1);       // in flight during compute

        // ---- QK^T: S[fm][nt], K frags shared across the 2 row-blocks ----
        f4v S[2][2];
#pragma unroll
        for (int fm = 0; fm < 2; ++fm)
#pragma unroll
            for (int nt = 0; nt < 2; ++nt) S[fm][nt] = z4;
#pragma unroll
        for (int ks = 0; ks < 4; ++ks) {
#pragma unroll
            for (int nt = 0; nt < 2; ++nt) {
                int o = (nt * 16 + ln) * 136 + ks * 32 + qd * 8;
                s8v kbhf = *(const s8v*)&Ksh[o];
                s8v kblf = *(const s8v*)&Ksl[o];
#pragma unroll
                for (int fm = 0; fm < 2; ++fm) {
                    S[fm][nt] = MFMA16(Qh[fm][ks],  kbhf, S[fm][nt]);
                    S[fm][nt] = MFMA16(Qh[fm][ks],  kblf, S[fm][nt]);
                    S[fm][nt] = MFMA16(Qlv[fm][ks], kbhf, S[fm][nt]);
                }
            }
        }

        // ---- online softmax (two independent row-blocks -> ILP) ----
        float pv[2][2][4];
#pragma unroll
        for (int fm = 0; fm < 2; ++fm) {
            float mt[4];
#pragma unroll
            for (int r = 0; r < 4; ++r) mt[r] = fmaxf(S[fm][0][r], S[fm][1][r]);
#pragma unroll
            for (int mask = 1; mask < 16; mask <<= 1)
#pragma unroll
                for (int r = 0; r < 4; ++r)
                    mt[r] = fmaxf(mt[r], __shfl_xor(mt[r], mask, 64));
            float alpha[4];
#pragma unroll
            for (int r = 0; r < 4; ++r) {
                float mn = fmaxf(mrow[fm][r], mt[r]);
                alpha[r] = __expf(mrow[fm][r] - mn);
                mrow[fm][r] = mn;
            }
            float lt[4] = {0.f, 0.f, 0.f, 0.f};
#pragma unroll
            for (int nt = 0; nt < 2; ++nt)
#pragma unroll
                for (int r = 0; r < 4; ++r) {
                    float p = __expf(S[fm][nt][r] - mrow[fm][r]);
                    pv[fm][nt][r] = p;
                    lt[r] += p;
                }
#pragma unroll
            for (int mask = 1; mask < 16; mask <<= 1)
#pragma unroll
                for (int r = 0; r < 4; ++r)
                    lt[r] += __shfl_xor(lt[r], mask, 64);
#pragma unroll
            for (int r = 0; r < 4; ++r)
                lrow[fm][r] = alpha[r] * lrow[fm][r] + lt[r];
#pragma unroll
            for (int fn = 0; fn < 8; ++fn)
#pragma unroll
                for (int r = 0; r < 4; ++r) Of[fm][fn][r] *= alpha[r];
        }

        // ---- P (C-layout) -> per-wave LDS (A-layout source) ----
#pragma unroll
        for (int fm = 0; fm < 2; ++fm)
#pragma unroll
            for (int nt = 0; nt < 2; ++nt)
#pragma unroll
                for (int r = 0; r < 4; ++r)
                    Ps[w][(fm * 16 + qd * 4 + r) * 40 + nt * 16 + ln] =
                        bf16rne(pv[fm][nt][r]);
        // same-wave write->read: compiler inserts lgkmcnt wait; no barrier.

        // ---- PV: Of += P * V, V frags shared across the 2 row-blocks ----
        s8v pf[2];
#pragma unroll
        for (int fm = 0; fm < 2; ++fm)
            pf[fm] = *(const s8v*)&Ps[w][(fm * 16 + ln) * 40 + qd * 8];
#pragma unroll
        for (int fn = 0; fn < 8; ++fn) {
            int o = (fn * 16 + ln) * 40 + qd * 8;
            s8v vbhf = *(const s8v*)&Vsh[o];
            s8v vblf = *(const s8v*)&Vsl[o];
#pragma unroll
            for (int fm = 0; fm < 2; ++fm) {
                Of[fm][fn] = MFMA16(pf[fm], vbhf, Of[fm][fn]);
                Of[fm][fn] = MFMA16(pf[fm], vblf, Of[fm][fn]);
            }
        }

        __syncthreads();                  // all waves done reading K/V LDS
        if (more) {
            STORELDS();                   // waits vmcnt for rK/rV arrival
            __syncthreads();              // next tile staged
        }
    }

    // ---- epilogue: normalize, split to bf16 hi/lo, store res[token][1024] --
    const int b = bh >> 3, h = bh & 7;
#pragma unroll
    for (int fm = 0; fm < 2; ++fm)
#pragma unroll
        for (int r = 0; r < 4; ++r) {
            float linv = 1.f / lrow[fm][r];
            int qi = q0 + w * 32 + fm * 16 + qd * 4 + r;
            size_t off = (size_t)(b * SS + qi) * DM + h * DH + ln;
#pragma unroll
            for (int fn = 0; fn < 8; ++fn) {
                u16 hh, ll;
                bfsplit(Of[fm][fn][r] * linv, hh, ll);
                res_hi[off + fn * 16] = hh;
                res_lo[off + fn * 16] = ll;
            }
        }
#undef LOADREGS
#undef STORELDS
}

// ---------------------------------------------------------------------------
extern "C" void kernel_launch(void* const* d_in, const int* in_sizes, int n_in,
                              void* d_out, int out_size, void* d_ws, size_t ws_size,
                              hipStream_t stream) {
    (void)in_sizes; (void)n_in; (void)out_size; (void)ws_size;
    const float* q_src = (const float*)d_in[0];
    const float* k_src = (const float*)d_in[1];
    const float* v_src = (const float*)d_in[2];
    const float* Wq    = (const float*)d_in[3];
    const float* Wk    = (const float*)d_in[4];
    const float* V     = (const float*)d_in[5];
    const float* O     = (const float*)d_in[6];
    const float* sel_v = (const float*)d_in[7];
    const float* sel_o = (const float*)d_in[8];
    float* out = (float*)d_out;

    // workspace layout
    const size_t NELT = (size_t)NTOK * DM;   // 8388608
    u16* wq_h = (u16*)d_ws;                  // q hi/lo [bh][s][f]
    u16* wq_l = wq_h + NELT;
    u16* wk_h = wq_l + NELT;                 // k hi/lo
    u16* wk_l = wk_h + NELT;
    float* wv = (float*)(wk_l + NELT);       // v fp32 [bh][s][f]
    u16* res_hi = (u16*)(wv + NELT);         // attention result hi/lo
    u16* res_lo = res_hi + NELT;
    u16* vs_hi  = res_lo + NELT;             // vsrc split (later: Ot)
    u16* vs_lo  = vs_hi + NELT;
    u16* Vt_hi  = vs_lo + NELT;              // V transposed (later: vT)
    u16* Vt_lo  = Vt_hi + NELT;
    float* gv = (float*)(Vt_lo + NELT);      // dense gates [8192][64]
    float* go = gv + (size_t)NTOK * 64;
    u16* Wq_h = (u16*)(go + (size_t)NTOK * 64);  // W splits (1024x1024 each)
    u16* Wq_l = Wq_h + (size_t)DM * DM;
    u16* Wk_h = Wq_l + (size_t)DM * DM;
    u16* Wk_l = Wk_h + (size_t)DM * DM;
    int* bcnt_v = (int*)(Wk_l + (size_t)DM * DM);  // 56 counters (v-gate)
    int* bidx_v = bcnt_v + 64;                     // 56*NTOK token ids
    float* bgv_v = (float*)(bidx_v + (size_t)56 * NTOK);
    // aliases (regions dead during the phase they are used)
    u16* qsrc_h = res_hi;                    // dead until attn writes res
    u16* qsrc_l = res_lo;
    u16* ksrc_h = (u16*)wv;                  // dead until v CVMM writes wv
    u16* ksrc_l = ksrc_h + NELT;
    u16* Ot_hi = vs_hi;                      // alias (dead after v CVMM)
    u16* Ot_lo = vs_lo;
    u16* vth   = Vt_hi;                      // alias (dead after v CVMM)
    u16* vtl   = Vt_lo;

    // preprocess: splits
    split_kernel<<<NELT / 1024, 256, 0, stream>>>(v_src, vs_hi, vs_lo);
    split_kernel<<<NELT / 1024, 256, 0, stream>>>(q_src, qsrc_h, qsrc_l);
    split_kernel<<<NELT / 1024, 256, 0, stream>>>(k_src, ksrc_h, ksrc_l);
    split_kernel<<<(DM * DM) / 1024, 256, 0, stream>>>(Wq, Wq_h, Wq_l);
    split_kernel<<<(DM * DM) / 1024, 256, 0, stream>>>(Wk, Wk_h, Wk_l);
    tsplit_kernel<<<dim3(64, 32, 4), 256, 0, stream>>>(V, Vt_hi, Vt_lo, 1024, 128);

    // gates (+ v-side expert buckets)
    zero_kernel<<<1, 128, 0, stream>>>(bcnt_v, 56);
    gate_kernel<<<NTOK, 64, 0, stream>>>(k_src, sel_v, gv, bcnt_v, bidx_v, bgv_v);
    gate_kernel<<<NTOK, 64, 0, stream>>>(q_src, sel_o, go, nullptr, nullptr, nullptr);

    // q/k projections via MFMA (emit bf16 hi/lo)
    proj_mfma_kernel<<<dim3(64, 8), 256, 0, stream>>>(
        qsrc_h, qsrc_l, Wq_h, Wq_l, wq_h, wq_l, SCALE_SQRT);
    proj_mfma_kernel<<<dim3(64, 8), 256, 0, stream>>>(
        ksrc_h, ksrc_l, Wk_h, Wk_l, wk_h, wk_l, SCALE_SQRT);

    // value CVMM: shared expert (dense, writes wv) then routed (bucketed, +=)
    // (overwrites ksrc splits: proj done)
    v_shared_kernel<<<dim3(64, 8), 256, 0, stream>>>(vs_hi, vs_lo, Vt_hi, Vt_lo, gv, wv);
    v_routed_kernel<<<dim3(64, 56), 256, 0, stream>>>(vs_hi, vs_lo, Vt_hi, Vt_lo,
                                                      bcnt_v, bidx_v, bgv_v, wv);

    // transpose+split O into dead vsrc buffers
    tsplit_kernel<<<dim3(64, 4, 32), 256, 0, stream>>>(O, Ot_hi, Ot_lo, 128, 1024);

    // transpose+split v into dead Vt buffers: vT[bh][f][s]
    tsplit_kernel<<<dim3(32, 64, 4), 256, 0, stream>>>(wv, vth, vtl, 2048, 128);

    // attention (MFMA flash; 128-query tiles; writes res = overwrites qsrc)
    attn_mfma_kernel<<<BB * NH * (SS / 128), 256, 0, stream>>>(
        wq_h, wq_l, wk_h, wk_l, vth, vtl, res_hi, res_lo);

    // output CVMM (MFMA, dense)
    out_mfma_kernel<<<dim3(8, 64), 256, 0, stream>>>(res_hi, res_lo, Ot_hi, Ot_lo, go, out);
}